// Round 1
// baseline (3389.038 us; speedup 1.0000x reference)
//
#include <hip/hip_runtime.h>
#include <math.h>

#define NP 15360
#define NTOK 15130
#define NFEAT 15129
#define HG 123

// ---------------- generic fp32 GEMM: C = cS*(A@B) + eS*E + bias, relu/accum flags, batched via blockIdx.z
__global__ __launch_bounds__(256)
void gemm_f32(const float* __restrict__ A, int lda, long sA,
              const float* __restrict__ B, int ldb, long sB,
              float* __restrict__ C, int ldc, long sC,
              int M, int N, int K,
              const float* __restrict__ bias,
              const float* __restrict__ E, int ldE, long sE, float eS,
              float cS, int relu, int accum)
{
    A += (long)blockIdx.z * sA;
    B += (long)blockIdx.z * sB;
    C += (long)blockIdx.z * sC;
    if (E) E += (long)blockIdx.z * sE;
    const int m0 = blockIdx.y * 64, n0 = blockIdx.x * 64;
    const int t = threadIdx.x;
    const int tx = t & 15, ty = t >> 4;
    __shared__ float As[16][64];
    __shared__ float Bs[16][64];
    float acc[4][4] = {};
    const int arow = t >> 2, akc = (t & 3) * 4;
    const int brow = t >> 4, bnc = (t & 15) * 4;
    for (int k0 = 0; k0 < K; k0 += 16) {
        float4 av = make_float4(0.f, 0.f, 0.f, 0.f);
        if (m0 + arow < M) av = *(const float4*)(A + (long)(m0 + arow) * lda + k0 + akc);
        As[akc + 0][arow] = av.x; As[akc + 1][arow] = av.y;
        As[akc + 2][arow] = av.z; As[akc + 3][arow] = av.w;
        float4 bv = *(const float4*)(B + (long)(k0 + brow) * ldb + n0 + bnc);
        *(float4*)&Bs[brow][bnc] = bv;
        __syncthreads();
#pragma unroll
        for (int kk = 0; kk < 16; ++kk) {
            float4 a4 = *(const float4*)&As[kk][ty * 4];
            float4 b4 = *(const float4*)&Bs[kk][tx * 4];
            float a[4] = {a4.x, a4.y, a4.z, a4.w};
            float b[4] = {b4.x, b4.y, b4.z, b4.w};
#pragma unroll
            for (int i = 0; i < 4; i++)
#pragma unroll
                for (int j = 0; j < 4; j++) acc[i][j] = fmaf(a[i], b[j], acc[i][j]);
        }
        __syncthreads();
    }
#pragma unroll
    for (int i = 0; i < 4; i++) {
        int m = m0 + ty * 4 + i;
        if (m < M) {
#pragma unroll
            for (int j = 0; j < 4; j++) {
                int n = n0 + tx * 4 + j;
                float v = cS * acc[i][j];
                if (E) v = fmaf(eS, E[(long)m * ldE + n], v);
                if (bias) v += bias[n];
                if (relu) v = fmaxf(v, 0.f);
                if (accum) C[(long)m * ldc + n] += v;
                else C[(long)m * ldc + n] = v;
            }
        }
    }
}

// ---------------- qkv GEMM with scatter epilogue into q/k/v [head][token][64], q scaled 1/8
__global__ __launch_bounds__(256)
void gemm_qkv(const float* __restrict__ A, const float* __restrict__ B,
              float* __restrict__ qo, float* __restrict__ ko, float* __restrict__ vo)
{
    const int m0 = blockIdx.y * 64, n0 = blockIdx.x * 64;
    const int t = threadIdx.x;
    const int tx = t & 15, ty = t >> 4;
    __shared__ float As[16][64];
    __shared__ float Bs[16][64];
    float acc[4][4] = {};
    const int arow = t >> 2, akc = (t & 3) * 4;
    const int brow = t >> 4, bnc = (t & 15) * 4;
    for (int k0 = 0; k0 < 512; k0 += 16) {
        float4 av = *(const float4*)(A + (long)(m0 + arow) * 512 + k0 + akc);
        As[akc + 0][arow] = av.x; As[akc + 1][arow] = av.y;
        As[akc + 2][arow] = av.z; As[akc + 3][arow] = av.w;
        float4 bv = *(const float4*)(B + (long)(k0 + brow) * 1536 + n0 + bnc);
        *(float4*)&Bs[brow][bnc] = bv;
        __syncthreads();
#pragma unroll
        for (int kk = 0; kk < 16; ++kk) {
            float4 a4 = *(const float4*)&As[kk][ty * 4];
            float4 b4 = *(const float4*)&Bs[kk][tx * 4];
            float a[4] = {a4.x, a4.y, a4.z, a4.w};
            float b[4] = {b4.x, b4.y, b4.z, b4.w};
#pragma unroll
            for (int i = 0; i < 4; i++)
#pragma unroll
                for (int j = 0; j < 4; j++) acc[i][j] = fmaf(a[i], b[j], acc[i][j]);
        }
        __syncthreads();
    }
#pragma unroll
    for (int i = 0; i < 4; i++) {
        int m = m0 + ty * 4 + i;
#pragma unroll
        for (int j = 0; j < 4; j++) {
            int col = n0 + tx * 4 + j;
            int which = col >> 9, h = (col >> 6) & 7, d = col & 63;
            float* dst = which == 0 ? qo : (which == 1 ? ko : vo);
            float s = which == 0 ? 0.125f : 1.0f;
            dst[((long)h * NP + m) * 64 + d] = s * acc[i][j];
        }
    }
}

// ---------------- layernorm over 512, writes padded xln (first `pad` rows zero)
__global__ __launch_bounds__(256)
void k_layernorm(const float* __restrict__ h, float* __restrict__ xln,
                 const float* __restrict__ g, const float* __restrict__ b, int pad)
{
    int row = blockIdx.x, t = threadIdx.x;
    if (row < pad) {
        xln[(long)row * 512 + t] = 0.f;
        xln[(long)row * 512 + t + 256] = 0.f;
        return;
    }
    const float* src = h + (long)(row - pad) * 512;
    float x1 = src[t], x2 = src[t + 256];
    float s = x1 + x2, q = x1 * x1 + x2 * x2;
    __shared__ float rs[4], rq[4], st[2];
    int wid = t >> 6, lane = t & 63;
#pragma unroll
    for (int o = 32; o > 0; o >>= 1) { s += __shfl_down(s, o); q += __shfl_down(q, o); }
    if (lane == 0) { rs[wid] = s; rq[wid] = q; }
    __syncthreads();
    if (t == 0) {
        float S = rs[0] + rs[1] + rs[2] + rs[3];
        float Q = rq[0] + rq[1] + rq[2] + rq[3];
        float mean = S / 512.f;
        float var = Q / 512.f - mean * mean;
        st[0] = mean; st[1] = rsqrtf(var + 1e-5f);
    }
    __syncthreads();
    float mean = st[0], rstd = st[1];
    xln[(long)row * 512 + t] = (x1 - mean) * rstd * g[t] + b[t];
    xln[(long)row * 512 + t + 256] = (x2 - mean) * rstd * g[t + 256] + b[t + 256];
}

// ---------------- write cls row + wrap-pad rows 15001..15129
__global__ __launch_bounds__(256)
void k_padcls(float* __restrict__ hbuf, const float* __restrict__ cls)
{
    int i = blockIdx.x, t = threadIdx.x;
    if (i == 0) { hbuf[t] = cls[t]; hbuf[t + 256] = cls[t + 256]; }
    else {
        hbuf[(long)(15000 + i) * 512 + t] = hbuf[(long)i * 512 + t];
        hbuf[(long)(15000 + i) * 512 + t + 256] = hbuf[(long)i * 512 + t + 256];
    }
}

// ---------------- landmarks: ql[h][i][d], klT[h][d][i] (transposed), and zero scal
__global__ __launch_bounds__(64)
void k_landmarks(const float* __restrict__ q, const float* __restrict__ k,
                 float* __restrict__ ql, float* __restrict__ klT, unsigned* __restrict__ scal)
{
    int i = blockIdx.x, h = blockIdx.y, d = threadIdx.x;
    if (i == 0 && h == 0 && d == 0) { scal[0] = 0u; scal[1] = 0u; }
    long base = ((long)h * NP + (long)i * 60) * 64 + d;
    float sq = 0.f, sk = 0.f;
    for (int j = 0; j < 60; j++) { sq += q[base + j * 64]; sk += k[base + j * 64]; }
    ql[((long)h * 256 + i) * 64 + d] = sq / 60.f;
    klT[((long)h * 64 + d) * 256 + i] = sk / 60.f;
}

// ---------------- in-place row softmax (row length 256)
__global__ __launch_bounds__(256)
void k_softmax256(float* __restrict__ X, long headStride)
{
    float* row = X + (long)blockIdx.y * headStride + (long)blockIdx.x * 256;
    int t = threadIdx.x, wid = t >> 6, lane = t & 63;
    float x = row[t];
    __shared__ float rm[4], rsum[4], fin[2];
    float m = x;
#pragma unroll
    for (int o = 32; o > 0; o >>= 1) m = fmaxf(m, __shfl_down(m, o));
    if (lane == 0) rm[wid] = m;
    __syncthreads();
    if (t == 0) fin[0] = fmaxf(fmaxf(rm[0], rm[1]), fmaxf(rm[2], rm[3]));
    __syncthreads();
    float e = __expf(x - fin[0]);
    float s = e;
#pragma unroll
    for (int o = 32; o > 0; o >>= 1) s += __shfl_down(s, o);
    if (lane == 0) rsum[wid] = s;
    __syncthreads();
    if (t == 0) fin[1] = rsum[0] + rsum[1] + rsum[2] + rsum[3];
    __syncthreads();
    row[t] = e / fin[1];
}

// ---------------- global max of col-sums (scal[0]) and row-sums (scal[1]) of a2
__global__ __launch_bounds__(256)
void k_colmax(const float* __restrict__ a2, unsigned* __restrict__ scal)
{
    int h = blockIdx.x, t = threadIdx.x, wid = t >> 6, lane = t & 63;
    const float* A = a2 + (long)h * 65536;
    float cs = 0.f, rs = 0.f;
    for (int i = 0; i < 256; i++) cs += A[(long)i * 256 + t];
    for (int j = 0; j < 256; j++) rs += A[(long)t * 256 + j];
    __shared__ float r1[4], r2[4];
    float m1v = cs, m2v = rs;
#pragma unroll
    for (int o = 32; o > 0; o >>= 1) {
        m1v = fmaxf(m1v, __shfl_down(m1v, o));
        m2v = fmaxf(m2v, __shfl_down(m2v, o));
    }
    if (lane == 0) { r1[wid] = m1v; r2[wid] = m2v; }
    __syncthreads();
    if (t == 0) {
        float a = fmaxf(fmaxf(r1[0], r1[1]), fmaxf(r1[2], r1[3]));
        float b = fmaxf(fmaxf(r2[0], r2[1]), fmaxf(r2[2], r2[3]));
        atomicMax(scal + 0, __float_as_uint(a));
        atomicMax(scal + 1, __float_as_uint(b));
    }
}

// ---------------- z0 = a2^T * 1/(scal0*scal1)   (batched 32x32 tiled transpose)
__global__ __launch_bounds__(256)
void k_zinit(const float* __restrict__ a2, float* __restrict__ z, const unsigned* __restrict__ scal)
{
    float s = 1.f / (__uint_as_float(scal[0]) * __uint_as_float(scal[1]));
    const float* A = a2 + (long)blockIdx.z * 65536;
    float* Z = z + (long)blockIdx.z * 65536;
    __shared__ float tile[32][33];
    int tx = threadIdx.x & 31, ty = threadIdx.x >> 5;
    int i0 = blockIdx.x * 32, j0 = blockIdx.y * 32;
#pragma unroll
    for (int u = 0; u < 4; u++) tile[ty + u * 8][tx] = A[(long)(j0 + ty + u * 8) * 256 + i0 + tx];
    __syncthreads();
#pragma unroll
    for (int u = 0; u < 4; u++) Z[(long)(i0 + ty + u * 8) * 256 + j0 + tx] = tile[tx][ty + u * 8] * s;
}

// ---------------- a3 @ v, split-K partials with online softmax. thread = landmark row.
__global__ __launch_bounds__(256)
void k_a3v_partial(const float* __restrict__ ql, const float* __restrict__ k,
                   const float* __restrict__ v,
                   float* __restrict__ pacc, float* __restrict__ pml)
{
    int c = blockIdx.x, h = blockIdx.y, i = threadIdx.x;
    __shared__ float kt[16][64], vt[16][64];
    float qr[64], acc[64];
#pragma unroll
    for (int d = 0; d < 64; d++) { qr[d] = ql[((long)h * 256 + i) * 64 + d]; acc[d] = 0.f; }
    float m = -INFINITY, l = 0.f;
    const float* kb = k + (long)h * NP * 64;
    const float* vb = v + (long)h * NP * 64;
    int base = c * 256;
    for (int t0 = 0; t0 < 256; t0 += 16) {
        __syncthreads();
        int idx = threadIdx.x * 4;
        int r = idx >> 6, col = idx & 63;
        *(float4*)&kt[r][col] = *(const float4*)(kb + (long)(base + t0 + r) * 64 + col);
        *(float4*)&vt[r][col] = *(const float4*)(vb + (long)(base + t0 + r) * 64 + col);
        __syncthreads();
        for (int jj = 0; jj < 16; jj++) {
            float s = 0.f;
#pragma unroll
            for (int d = 0; d < 64; d++) s = fmaf(qr[d], kt[jj][d], s);
            if (s > m) {
                float f = __expf(m - s);
                l = l * f + 1.f;
#pragma unroll
                for (int d = 0; d < 64; d++) acc[d] = acc[d] * f + vt[jj][d];
                m = s;
            } else {
                float p = __expf(s - m);
                l += p;
#pragma unroll
                for (int d = 0; d < 64; d++) acc[d] = fmaf(p, vt[jj][d], acc[d]);
            }
        }
    }
    long pb = (long)(h * 60 + c) * 64 * 256;
#pragma unroll
    for (int d = 0; d < 64; d++) pacc[pb + (long)d * 256 + i] = acc[d];
    pml[(long)(h * 60 + c) * 2 * 256 + i] = m;
    pml[((long)(h * 60 + c) * 2 + 1) * 256 + i] = l;
}

// ---------------- merge 60 chunk-partials → t1[h][i][d]
__global__ __launch_bounds__(256)
void k_a3v_merge(const float* __restrict__ pacc, const float* __restrict__ pml,
                 float* __restrict__ t1)
{
    int d = blockIdx.x, h = blockIdx.y, i = threadIdx.x;
    float M = -INFINITY, L = 0.f, num = 0.f;
    for (int c = 0; c < 60; c++) {
        float mc = pml[(long)(h * 60 + c) * 2 * 256 + i];
        float lc = pml[((long)(h * 60 + c) * 2 + 1) * 256 + i];
        float ac = pacc[((long)(h * 60 + c) * 64 + d) * 256 + i];
        if (mc > M) {
            float f = __expf(M - mc);
            num = num * f + ac; L = L * f + lc; M = mc;
        } else {
            float p = __expf(mc - M);
            num = fmaf(p, ac, num); L = fmaf(p, lc, L);
        }
    }
    t1[((long)h * 256 + i) * 64 + d] = num / L;
}

// ---------------- depthwise 1D conv (k=33) on v, += into oh
__global__ __launch_bounds__(256)
void k_resconv(float* __restrict__ oh, const float* __restrict__ v,
               const float* __restrict__ rw, int Mrows)
{
    int h = blockIdx.y;
    int d = threadIdx.x & 63, r = threadIdx.x >> 6;
    int tk = blockIdx.x * 4 + r;
    if (tk >= Mrows) return;
    const float* vb = v + (long)h * NP * 64 + d;
    float acc = 0.f;
    int center = 230 + tk;
#pragma unroll
    for (int kk = 0; kk < 33; kk++) {
        int src = center + kk - 16;
        if (src >= 0 && src < NP) acc = fmaf(rw[h * 33 + kk], vb[(long)src * 64], acc);
    }
    oh[(long)tk * 512 + h * 64 + d] += acc;
}

// ---------------- plain float4 copy
__global__ __launch_bounds__(256)
void k_copy4(const float4* __restrict__ src, float4* __restrict__ dst, long n4)
{
    long i = (long)blockIdx.x * 256 + threadIdx.x;
    if (i < n4) dst[i] = src[i];
}

// ---------------- PPEG: 7x7 + 5x5 + 3x3 depthwise + identity, writes hbuf rows 1..
__global__ __launch_bounds__(256)
void k_ppeg(const float* __restrict__ cnn, float* __restrict__ hbuf,
            const float* __restrict__ w7, const float* __restrict__ b7,
            const float* __restrict__ w5, const float* __restrict__ b5,
            const float* __restrict__ w3, const float* __restrict__ b3)
{
    __shared__ float tile[14 * 14 * 64];
    int lc = threadIdx.x & 63, sp0 = threadIdx.x >> 6;
    int c0 = blockIdx.x * 8, r0 = blockIdx.y * 8, cb = blockIdx.z * 64;
    for (int p = sp0; p < 196; p += 4) {
        int pr = p / 14, pc = p % 14;
        int gr = r0 + pr - 3, gc = c0 + pc - 3;
        float val = 0.f;
        if (gr >= 0 && gr < HG && gc >= 0 && gc < HG)
            val = cnn[(long)(gr * HG + gc) * 512 + cb + lc];
        tile[p * 64 + lc] = val;
    }
    __syncthreads();
    int c = cb + lc;
    float bb = b7[c] + b5[c] + b3[c];
    float acc[16];
    int bidx[16];
#pragma unroll
    for (int u = 0; u < 16; u++) {
        int sp = sp0 + 4 * u;
        int orr = sp >> 3, occ = sp & 7;
        bidx[u] = (orr * 14 + occ) * 64 + lc;
        acc[u] = bb + tile[((orr + 3) * 14 + (occ + 3)) * 64 + lc];
    }
    for (int kr = 0; kr < 7; kr++)
        for (int kc = 0; kc < 7; kc++) {
            float w = w7[c * 49 + kr * 7 + kc];
            int koff = (kr * 14 + kc) * 64;
#pragma unroll
            for (int u = 0; u < 16; u++) acc[u] = fmaf(w, tile[bidx[u] + koff], acc[u]);
        }
    for (int kr = 0; kr < 5; kr++)
        for (int kc = 0; kc < 5; kc++) {
            float w = w5[c * 25 + kr * 5 + kc];
            int koff = ((kr + 1) * 14 + kc + 1) * 64;
#pragma unroll
            for (int u = 0; u < 16; u++) acc[u] = fmaf(w, tile[bidx[u] + koff], acc[u]);
        }
    for (int kr = 0; kr < 3; kr++)
        for (int kc = 0; kc < 3; kc++) {
            float w = w3[c * 9 + kr * 3 + kc];
            int koff = ((kr + 2) * 14 + kc + 2) * 64;
#pragma unroll
            for (int u = 0; u < 16; u++) acc[u] = fmaf(w, tile[bidx[u] + koff], acc[u]);
        }
#pragma unroll
    for (int u = 0; u < 16; u++) {
        int sp = sp0 + 4 * u;
        int orr = sp >> 3, occ = sp & 7;
        int gr = r0 + orr, gc = c0 + occ;
        if (gr < HG && gc < HG)
            hbuf[(long)(1 + gr * HG + gc) * 512 + c] = acc[u];
    }
}

// ---------------- final: LN(row0) -> fc2 -> softmax/argmax -> out[11]
__global__ __launch_bounds__(256)
void k_final(const float* __restrict__ hbuf, const float* __restrict__ g,
             const float* __restrict__ b, const float* __restrict__ W2,
             const float* __restrict__ b2, float* __restrict__ out)
{
    __shared__ float y[512];
    __shared__ float rs[4], rq[4], st[2], lg[8];
    int t = threadIdx.x, wid = t >> 6, lane = t & 63;
    float x1 = hbuf[t], x2 = hbuf[t + 256];
    float s = x1 + x2, q = x1 * x1 + x2 * x2;
#pragma unroll
    for (int o = 32; o > 0; o >>= 1) { s += __shfl_down(s, o); q += __shfl_down(q, o); }
    if (lane == 0) { rs[wid] = s; rq[wid] = q; }
    __syncthreads();
    if (t == 0) {
        float S = rs[0] + rs[1] + rs[2] + rs[3];
        float Q = rq[0] + rq[1] + rq[2] + rq[3];
        float mean = S / 512.f;
        float var = Q / 512.f - mean * mean;
        st[0] = mean; st[1] = rsqrtf(var + 1e-5f);
    }
    __syncthreads();
    float mean = st[0], rstd = st[1];
    y[t] = (x1 - mean) * rstd * g[t] + b[t];
    y[t + 256] = (x2 - mean) * rstd * g[t + 256] + b[t + 256];
    __syncthreads();
    if (t < 5) {
        float acc = b2[t];
        for (int kx = 0; kx < 512; kx++) acc = fmaf(y[kx], W2[kx * 5 + t], acc);
        lg[t] = acc;
    }
    __syncthreads();
    if (t == 0) {
        float mx = lg[0]; int am = 0;
        for (int j = 1; j < 5; j++) if (lg[j] > mx) { mx = lg[j]; am = j; }
        float e[5], se = 0.f;
        for (int j = 0; j < 5; j++) { e[j] = __expf(lg[j] - mx); se += e[j]; }
        for (int j = 0; j < 5; j++) { out[j] = lg[j]; out[5 + j] = e[j] / se; }
        out[10] = (float)am;
    }
}

extern "C" void kernel_launch(void* const* d_in, const int* in_sizes, int n_in,
                              void* d_out, int out_size, void* d_ws, size_t ws_size,
                              hipStream_t stream)
{
    const float* data  = (const float*)d_in[0];
    const float* Wfc1  = (const float*)d_in[1];
    const float* bfc1  = (const float*)d_in[2];
    const float* cls   = (const float*)d_in[3];
    const float* ln1g  = (const float*)d_in[4];
    const float* ln1b  = (const float*)d_in[5];
    const float* qkv1  = (const float*)d_in[6];
    const float* out1w = (const float*)d_in[7];
    const float* out1b = (const float*)d_in[8];
    const float* res1  = (const float*)d_in[9];
    const float* w7    = (const float*)d_in[10];
    const float* b7    = (const float*)d_in[11];
    const float* w5    = (const float*)d_in[12];
    const float* b5    = (const float*)d_in[13];
    const float* w3    = (const float*)d_in[14];
    const float* b3    = (const float*)d_in[15];
    const float* ln2g  = (const float*)d_in[16];
    const float* ln2b  = (const float*)d_in[17];
    const float* qkv2  = (const float*)d_in[18];
    const float* out2w = (const float*)d_in[19];
    const float* out2b = (const float*)d_in[20];
    const float* res2  = (const float*)d_in[21];
    const float* normg = (const float*)d_in[22];
    const float* normb = (const float*)d_in[23];
    const float* Wfc2  = (const float*)d_in[24];
    const float* bfc2  = (const float*)d_in[25];
    float* out = (float*)d_out;

    float* W = (float*)d_ws;
    size_t off = 0;
    auto alloc = [&](size_t n) { size_t o = off; off += (n + 255) & ~(size_t)255; return o; };
    float* hbuf = W + alloc((size_t)NTOK * 512);
    float* xln  = W + alloc((size_t)NP * 512);     // aliased as oh after qkv
    float* oh   = xln;
    float* qb   = W + alloc((size_t)8 * NP * 64);
    float* kb   = W + alloc((size_t)8 * NP * 64);
    float* vb   = W + alloc((size_t)8 * NP * 64);
    float* ql   = W + alloc(8 * 256 * 64);
    float* klT  = W + alloc(8 * 64 * 256);
    float* a2   = W + alloc(8 * 65536);
    float* z0   = W + alloc(8 * 65536);
    float* z1   = W + alloc(8 * 65536);
    float* m1   = W + alloc(8 * 65536);
    float* ma   = W + alloc(8 * 65536);
    float* mb   = W + alloc(8 * 65536);
    float* t1   = W + alloc(8 * 256 * 64);
    float* Bm   = W + alloc(8 * 256 * 64);
    float* scal = W + alloc(64);
    float* big  = W + alloc(8110080);   // pacc+pml | sim1 slabs | ppeg cnn
    float* pacc = big;
    float* pml  = big + 7864320;
    float* simbuf = big;
    float* cnn  = big;
    if (ws_size < off * sizeof(float)) return;   // insufficient workspace: bail

    // fc1 + relu -> hbuf rows 1..15000
    gemm_f32<<<dim3(8, 235, 1), 256, 0, stream>>>(data, 1024, 0, Wfc1, 512, 0,
        hbuf + 512, 512, 0, 15000, 512, 1024, bfc1, nullptr, 0, 0, 0.f, 1.f, 1, 0);
    k_padcls<<<130, 256, 0, stream>>>(hbuf, cls);

    auto layer = [&](const float* lng, const float* lnb, const float* qkvW,
                     const float* outW, const float* outB, const float* resW, bool full) {
        k_layernorm<<<NP, 256, 0, stream>>>(hbuf, xln, lng, lnb, 230);
        gemm_qkv<<<dim3(24, 240, 1), 256, 0, stream>>>(xln, qkvW, qb, kb, vb);
        k_landmarks<<<dim3(256, 8), 64, 0, stream>>>(qb, kb, ql, klT, (unsigned*)scal);
        // sim2 = ql @ kl^T  -> a2 (softmax)
        gemm_f32<<<dim3(4, 4, 8), 256, 0, stream>>>(ql, 64, 16384, klT, 256, 16384,
            a2, 256, 65536, 256, 256, 64, nullptr, nullptr, 0, 0, 0.f, 1.f, 0, 0);
        k_softmax256<<<dim3(256, 8), 256, 0, stream>>>(a2, 65536);
        k_colmax<<<8, 256, 0, stream>>>(a2, (unsigned*)scal);
        k_zinit<<<dim3(8, 8, 8), 256, 0, stream>>>(a2, z0, (const unsigned*)scal);
        float* zi = z0; float* zo = z1;
        for (int it = 0; it < 6; ++it) {
            gemm_f32<<<dim3(4, 4, 8), 256, 0, stream>>>(a2, 256, 65536, zi, 256, 65536,
                m1, 256, 65536, 256, 256, 256, nullptr, nullptr, 0, 0, 0.f, 1.f, 0, 0);
            gemm_f32<<<dim3(4, 4, 8), 256, 0, stream>>>(m1, 256, 65536, m1, 256, 65536,
                ma, 256, 65536, 256, 256, 256, nullptr, m1, 256, 65536, 7.f, -1.f, 0, 0);
            gemm_f32<<<dim3(4, 4, 8), 256, 0, stream>>>(m1, 256, 65536, ma, 256, 65536,
                mb, 256, 65536, 256, 256, 256, nullptr, m1, 256, 65536, 15.f, -1.f, 0, 0);
            gemm_f32<<<dim3(4, 4, 8), 256, 0, stream>>>(zi, 256, 65536, mb, 256, 65536,
                zo, 256, 65536, 256, 256, 256, nullptr, zi, 256, 65536, 3.25f, -0.25f, 0, 0);
            float* tmp = zi; zi = zo; zo = tmp;
        }
        // t1 = a3 @ v (flash-style)
        k_a3v_partial<<<dim3(60, 8), 256, 0, stream>>>(ql, kb, vb, pacc, pml);
        k_a3v_merge<<<dim3(64, 8), 256, 0, stream>>>(pacc, pml, t1);
        // B = z @ t1
        gemm_f32<<<dim3(1, 4, 8), 256, 0, stream>>>(zi, 256, 65536, t1, 64, 16384,
            Bm, 64, 16384, 256, 64, 256, nullptr, nullptr, 0, 0, 0.f, 1.f, 0, 0);
        int Mtot = full ? NTOK : 1;
        for (int s0 = 0; s0 < Mtot; s0 += 3840) {
            int ms = Mtot - s0 < 3840 ? Mtot - s0 : 3840;
            gemm_f32<<<dim3(4, (ms + 63) / 64, 8), 256, 0, stream>>>(
                qb + (long)(230 + s0) * 64, 64, (long)NP * 64, klT, 256, 16384,
                simbuf, 256, (long)3840 * 256, ms, 256, 64,
                nullptr, nullptr, 0, 0, 0.f, 1.f, 0, 0);
            k_softmax256<<<dim3(ms, 8), 256, 0, stream>>>(simbuf, (long)3840 * 256);
            gemm_f32<<<dim3(1, (ms + 63) / 64, 8), 256, 0, stream>>>(
                simbuf, 256, (long)3840 * 256, Bm, 64, 16384,
                oh + (long)s0 * 512, 512, 64, ms, 64, 256,
                nullptr, nullptr, 0, 0, 0.f, 1.f, 0, 0);
        }
        k_resconv<<<dim3((Mtot + 3) / 4, 8), 256, 0, stream>>>(oh, vb, resW, Mtot);
        // h += oh @ Wout + bout
        gemm_f32<<<dim3(8, (Mtot + 63) / 64, 1), 256, 0, stream>>>(oh, 512, 0, outW, 512, 0,
            hbuf, 512, 0, Mtot, 512, 512, outB, nullptr, 0, 0, 0.f, 1.f, 0, 1);
    };

    layer(ln1g, ln1b, qkv1, out1w, out1b, res1, true);
    k_copy4<<<(1936512 + 255) / 256, 256, 0, stream>>>((const float4*)(hbuf + 512), (float4*)cnn, 1936512);
    k_ppeg<<<dim3(16, 16, 8), 256, 0, stream>>>(cnn, hbuf, w7, b7, w5, b5, w3, b3);
    layer(ln2g, ln2b, qkv2, out2w, out2b, res2, false);
    k_final<<<1, 256, 0, stream>>>(hbuf, normg, normb, Wfc2, bfc2, out);
}

// Round 2
// 2470.846 us; speedup vs baseline: 1.3716x; 1.3716x over previous
//
#include <hip/hip_runtime.h>
#include <math.h>

#define NP 15360
#define NPQ 15488
#define NTOK 15130
#define HG 123

typedef __attribute__((ext_vector_type(8))) short s8b;
typedef __attribute__((ext_vector_type(4))) float f4;

__device__ inline float bf2f(ushort u) { return __uint_as_float(((unsigned)u) << 16); }
__device__ inline ushort f2bf(float f) {
    unsigned u = __float_as_uint(f);
    unsigned r = (u + 0x7fffu + ((u >> 16) & 1u)) >> 16;
    return (ushort)r;
}

// ---------------- generic fp32 GEMM (kept for small/sensitive ops): C = cS*(A@B) + eS*E + bias
__global__ __launch_bounds__(256)
void gemm_f32(const float* __restrict__ A, int lda, long sA,
              const float* __restrict__ B, int ldb, long sB,
              float* __restrict__ C, int ldc, long sC,
              int M, int N, int K,
              const float* __restrict__ bias,
              const float* __restrict__ E, int ldE, long sE, float eS,
              float cS, int relu, int accum)
{
    A += (long)blockIdx.z * sA;
    B += (long)blockIdx.z * sB;
    C += (long)blockIdx.z * sC;
    if (E) E += (long)blockIdx.z * sE;
    const int m0 = blockIdx.y * 64, n0 = blockIdx.x * 64;
    const int t = threadIdx.x;
    const int tx = t & 15, ty = t >> 4;
    __shared__ float As[16][64];
    __shared__ float Bs[16][64];
    float acc[4][4] = {};
    const int arow = t >> 2, akc = (t & 3) * 4;
    const int brow = t >> 4, bnc = (t & 15) * 4;
    for (int k0 = 0; k0 < K; k0 += 16) {
        float4 av = make_float4(0.f, 0.f, 0.f, 0.f);
        if (m0 + arow < M) av = *(const float4*)(A + (long)(m0 + arow) * lda + k0 + akc);
        As[akc + 0][arow] = av.x; As[akc + 1][arow] = av.y;
        As[akc + 2][arow] = av.z; As[akc + 3][arow] = av.w;
        float4 bv = *(const float4*)(B + (long)(k0 + brow) * ldb + n0 + bnc);
        *(float4*)&Bs[brow][bnc] = bv;
        __syncthreads();
#pragma unroll
        for (int kk = 0; kk < 16; ++kk) {
            float4 a4 = *(const float4*)&As[kk][ty * 4];
            float4 b4 = *(const float4*)&Bs[kk][tx * 4];
            float a[4] = {a4.x, a4.y, a4.z, a4.w};
            float b[4] = {b4.x, b4.y, b4.z, b4.w};
#pragma unroll
            for (int i = 0; i < 4; i++)
#pragma unroll
                for (int j = 0; j < 4; j++) acc[i][j] = fmaf(a[i], b[j], acc[i][j]);
        }
        __syncthreads();
    }
#pragma unroll
    for (int i = 0; i < 4; i++) {
        int m = m0 + ty * 4 + i;
        if (m < M) {
#pragma unroll
            for (int j = 0; j < 4; j++) {
                int n = n0 + tx * 4 + j;
                float v = cS * acc[i][j];
                if (E) v = fmaf(eS, E[(long)m * ldE + n], v);
                if (bias) v += bias[n];
                if (relu) v = fmaxf(v, 0.f);
                if (accum) C[(long)m * ldc + n] += v;
                else C[(long)m * ldc + n] = v;
            }
        }
    }
}

// ---------------- bf16 MFMA GEMM: C(fp32) = A(bf16,[M][K]) @ Bt(bf16,[N][K])^T (+bias, relu, accum)
// wave tile = (MT*16) x (NT*16); waves arranged WROWS x WCOLS; block tile = 128 x (NT*16*WCOLS)
template<int MT, int NT, int WROWS, int WCOLS>
__global__ __launch_bounds__(256)
void gemm_mfma(const ushort* __restrict__ A, int lda, long sA,
               const ushort* __restrict__ Bt, int ldb, long sB,
               float* __restrict__ C, int ldc, long sC,
               int M, int K,
               const float* __restrict__ bias, int relu, int accum)
{
    constexpr int TM = MT * 16 * WROWS;
    constexpr int TN = NT * 16 * WCOLS;
    constexpr int BKP = 40;   // 32 + 8 pad (80B rows: 16B-aligned, conflict-light)
    __shared__ ushort As[TM * BKP];
    __shared__ ushort Bs[TN * BKP];
    A  += (long)blockIdx.z * sA;
    Bt += (long)blockIdx.z * sB;
    C  += (long)blockIdx.z * sC;
    const int t = threadIdx.x;
    const int m0 = blockIdx.y * TM, n0 = blockIdx.x * TN;
    const int w = t >> 6, l = t & 63;
    const int wm = (w / WCOLS) * (MT * 16), wn = (w % WCOLS) * (NT * 16);
    const int lr = l & 15;
    const int lk = (l >> 4) * 8;
    f4 acc[MT][NT] = {};
    for (int k0 = 0; k0 < K; k0 += 32) {
        for (int c = t; c < TM * 4; c += 256) {
            int row = c >> 2, kc = (c & 3) * 8;
            s8b v = *(const s8b*)(A + (long)(m0 + row) * lda + k0 + kc);
            *(s8b*)(&As[row * BKP + kc]) = v;
        }
        for (int c = t; c < TN * 4; c += 256) {
            int row = c >> 2, kc = (c & 3) * 8;
            s8b v = *(const s8b*)(Bt + (long)(n0 + row) * ldb + k0 + kc);
            *(s8b*)(&Bs[row * BKP + kc]) = v;
        }
        __syncthreads();
        s8b af[MT], bf[NT];
#pragma unroll
        for (int i = 0; i < MT; i++) af[i] = *(const s8b*)(&As[(wm + i * 16 + lr) * BKP + lk]);
#pragma unroll
        for (int j = 0; j < NT; j++) bf[j] = *(const s8b*)(&Bs[(wn + j * 16 + lr) * BKP + lk]);
#pragma unroll
        for (int i = 0; i < MT; i++)
#pragma unroll
            for (int j = 0; j < NT; j++)
                acc[i][j] = __builtin_amdgcn_mfma_f32_16x16x32_bf16(af[i], bf[j], acc[i][j], 0, 0, 0);
        __syncthreads();
    }
    const int orow = (l >> 4) * 4;
#pragma unroll
    for (int i = 0; i < MT; i++) {
#pragma unroll
        for (int r = 0; r < 4; r++) {
            int m = m0 + wm + i * 16 + orow + r;
            if (m < M) {
#pragma unroll
                for (int j = 0; j < NT; j++) {
                    int n = n0 + wn + j * 16 + lr;
                    float vv = acc[i][j][r];
                    if (bias) vv += bias[n];
                    if (relu) vv = fmaxf(vv, 0.f);
                    if (accum) C[(long)m * ldc + n] += vv;
                    else C[(long)m * ldc + n] = vv;
                }
            }
        }
    }
}

// ---------------- qkv MFMA GEMM, scatter epilogue into bf16 q/k/v [head][NPQ][64], q scaled 1/8
__global__ __launch_bounds__(256)
void gemm_qkv_mfma(const ushort* __restrict__ A, const ushort* __restrict__ Bt,
                   ushort* __restrict__ qo, ushort* __restrict__ ko, ushort* __restrict__ vo)
{
    constexpr int BKP = 40;
    __shared__ ushort As[128 * BKP];
    __shared__ ushort Bs[128 * BKP];
    const int t = threadIdx.x;
    const int m0 = blockIdx.y * 128, n0 = blockIdx.x * 128;
    const int w = t >> 6, l = t & 63;
    const int wm = (w >> 1) * 64, wn = (w & 1) * 64;
    const int lr = l & 15;
    const int lk = (l >> 4) * 8;
    f4 acc[4][4] = {};
    for (int k0 = 0; k0 < 512; k0 += 32) {
        for (int c = t; c < 512; c += 256) {
            int row = c >> 2, kc = (c & 3) * 8;
            s8b va = *(const s8b*)(A + (long)(m0 + row) * 512 + k0 + kc);
            *(s8b*)(&As[row * BKP + kc]) = va;
            s8b vb = *(const s8b*)(Bt + (long)(n0 + row) * 512 + k0 + kc);
            *(s8b*)(&Bs[row * BKP + kc]) = vb;
        }
        __syncthreads();
        s8b af[4], bf[4];
#pragma unroll
        for (int i = 0; i < 4; i++) af[i] = *(const s8b*)(&As[(wm + i * 16 + lr) * BKP + lk]);
#pragma unroll
        for (int j = 0; j < 4; j++) bf[j] = *(const s8b*)(&Bs[(wn + j * 16 + lr) * BKP + lk]);
#pragma unroll
        for (int i = 0; i < 4; i++)
#pragma unroll
            for (int j = 0; j < 4; j++)
                acc[i][j] = __builtin_amdgcn_mfma_f32_16x16x32_bf16(af[i], bf[j], acc[i][j], 0, 0, 0);
        __syncthreads();
    }
    const int orow = (l >> 4) * 4;
#pragma unroll
    for (int i = 0; i < 4; i++) {
#pragma unroll
        for (int r = 0; r < 4; r++) {
            int m = m0 + wm + i * 16 + orow + r;
#pragma unroll
            for (int j = 0; j < 4; j++) {
                int col = n0 + wn + j * 16 + lr;
                int which = col >> 9, h = (col >> 6) & 7, d = col & 63;
                float vv = acc[i][j][r];
                if (which == 0) vv *= 0.125f;
                ushort* dst = which == 0 ? qo : (which == 1 ? ko : vo);
                dst[((long)h * NPQ + m) * 64 + d] = f2bf(vv);
            }
        }
    }
}

// ---------------- layernorm over 512, writes bf16 xln (first `pad` rows zero)
__global__ __launch_bounds__(256)
void k_layernorm(const float* __restrict__ h, ushort* __restrict__ xln,
                 const float* __restrict__ g, const float* __restrict__ b, int pad)
{
    int row = blockIdx.x, t = threadIdx.x;
    if (row < pad) {
        xln[(long)row * 512 + t] = 0;
        xln[(long)row * 512 + t + 256] = 0;
        return;
    }
    const float* src = h + (long)(row - pad) * 512;
    float x1 = src[t], x2 = src[t + 256];
    float s = x1 + x2, q = x1 * x1 + x2 * x2;
    __shared__ float rs[4], rq[4], st[2];
    int wid = t >> 6, lane = t & 63;
#pragma unroll
    for (int o = 32; o > 0; o >>= 1) { s += __shfl_down(s, o); q += __shfl_down(q, o); }
    if (lane == 0) { rs[wid] = s; rq[wid] = q; }
    __syncthreads();
    if (t == 0) {
        float S = rs[0] + rs[1] + rs[2] + rs[3];
        float Q = rq[0] + rq[1] + rq[2] + rq[3];
        float mean = S / 512.f;
        float var = Q / 512.f - mean * mean;
        st[0] = mean; st[1] = rsqrtf(var + 1e-5f);
    }
    __syncthreads();
    float mean = st[0], rstd = st[1];
    xln[(long)row * 512 + t] = f2bf((x1 - mean) * rstd * g[t] + b[t]);
    xln[(long)row * 512 + t + 256] = f2bf((x2 - mean) * rstd * g[t + 256] + b[t + 256]);
}

// ---------------- write cls row + wrap-pad rows 15001..15129 (fp32 hbuf)
__global__ __launch_bounds__(256)
void k_padcls(float* __restrict__ hbuf, const float* __restrict__ cls)
{
    int i = blockIdx.x, t = threadIdx.x;
    if (i == 0) { hbuf[t] = cls[t]; hbuf[t + 256] = cls[t + 256]; }
    else {
        hbuf[(long)(15000 + i) * 512 + t] = hbuf[(long)i * 512 + t];
        hbuf[(long)(15000 + i) * 512 + t + 256] = hbuf[(long)i * 512 + t + 256];
    }
}

// ---------------- fp32 [K][N] -> bf16 [N][K] transpose-convert (batched)
__global__ __launch_bounds__(256)
void k_wT(const float* __restrict__ Wm, ushort* __restrict__ Wt, int K, int N, long sW, long sWt)
{
    Wm += (long)blockIdx.z * sW; Wt += (long)blockIdx.z * sWt;
    __shared__ float tile[32][33];
    int tx = threadIdx.x & 31, ty = threadIdx.x >> 5;
    int n0 = blockIdx.x * 32, k0 = blockIdx.y * 32;
#pragma unroll
    for (int u = 0; u < 4; u++) tile[ty + u * 8][tx] = Wm[(long)(k0 + ty + u * 8) * N + n0 + tx];
    __syncthreads();
#pragma unroll
    for (int u = 0; u < 4; u++) Wt[(long)(n0 + ty + u * 8) * K + k0 + tx] = f2bf(tile[tx][ty + u * 8]);
}

// ---------------- fp32 -> bf16 elementwise (vector4)
__global__ __launch_bounds__(256)
void k_cvt(const float4* __restrict__ src, ushort4* __restrict__ dst, long n4)
{
    long i = (long)blockIdx.x * 256 + threadIdx.x;
    if (i < n4) {
        float4 v = src[i];
        ushort4 o;
        o.x = f2bf(v.x); o.y = f2bf(v.y); o.z = f2bf(v.z); o.w = f2bf(v.w);
        dst[i] = o;
    }
}

// ---------------- landmarks from bf16 q,k: ql f32, klT f32 [h][d][i], klb bf16 [h][i][d]; zero scal
__global__ __launch_bounds__(64)
void k_landmarks(const ushort* __restrict__ q, const ushort* __restrict__ k,
                 float* __restrict__ ql, float* __restrict__ klT, ushort* __restrict__ klb,
                 unsigned* __restrict__ scal)
{
    int i = blockIdx.x, h = blockIdx.y, d = threadIdx.x;
    if (i == 0 && h == 0 && d == 0) { scal[0] = 0u; scal[1] = 0u; }
    long base = ((long)h * NPQ + (long)i * 60) * 64 + d;
    float sq = 0.f, sk = 0.f;
    for (int j = 0; j < 60; j++) { sq += bf2f(q[base + j * 64]); sk += bf2f(k[base + j * 64]); }
    float qv = sq / 60.f, kv = sk / 60.f;
    ql[((long)h * 256 + i) * 64 + d] = qv;
    klT[((long)h * 64 + d) * 256 + i] = kv;
    klb[((long)h * 256 + i) * 64 + d] = f2bf(kv);
}

// ---------------- in-place fp32 row softmax (row length 256)
__global__ __launch_bounds__(256)
void k_softmax256(float* __restrict__ X, long headStride)
{
    float* row = X + (long)blockIdx.y * headStride + (long)blockIdx.x * 256;
    int t = threadIdx.x, wid = t >> 6, lane = t & 63;
    float x = row[t];
    __shared__ float rm[4], rsum[4], fin[2];
    float m = x;
#pragma unroll
    for (int o = 32; o > 0; o >>= 1) m = fmaxf(m, __shfl_down(m, o));
    if (lane == 0) rm[wid] = m;
    __syncthreads();
    if (t == 0) fin[0] = fmaxf(fmaxf(rm[0], rm[1]), fmaxf(rm[2], rm[3]));
    __syncthreads();
    float e = __expf(x - fin[0]);
    float s = e;
#pragma unroll
    for (int o = 32; o > 0; o >>= 1) s += __shfl_down(s, o);
    if (lane == 0) rsum[wid] = s;
    __syncthreads();
    if (t == 0) fin[1] = rsum[0] + rsum[1] + rsum[2] + rsum[3];
    __syncthreads();
    row[t] = e / fin[1];
}

// ---------------- fp32 row softmax -> bf16 out (row length 256)
__global__ __launch_bounds__(256)
void k_softmax256b(const float* __restrict__ X, ushort* __restrict__ O, long hsX, long hsO)
{
    const float* row = X + (long)blockIdx.y * hsX + (long)blockIdx.x * 256;
    ushort* orow = O + (long)blockIdx.y * hsO + (long)blockIdx.x * 256;
    int t = threadIdx.x, wid = t >> 6, lane = t & 63;
    float x = row[t];
    __shared__ float rm[4], rsum[4], fin[2];
    float m = x;
#pragma unroll
    for (int o = 32; o > 0; o >>= 1) m = fmaxf(m, __shfl_down(m, o));
    if (lane == 0) rm[wid] = m;
    __syncthreads();
    if (t == 0) fin[0] = fmaxf(fmaxf(rm[0], rm[1]), fmaxf(rm[2], rm[3]));
    __syncthreads();
    float e = __expf(x - fin[0]);
    float s = e;
#pragma unroll
    for (int o = 32; o > 0; o >>= 1) s += __shfl_down(s, o);
    if (lane == 0) rsum[wid] = s;
    __syncthreads();
    if (t == 0) fin[1] = rsum[0] + rsum[1] + rsum[2] + rsum[3];
    __syncthreads();
    orow[t] = f2bf(e / fin[1]);
}

// ---------------- global max of col-sums / row-sums of a2
__global__ __launch_bounds__(256)
void k_colmax(const float* __restrict__ a2, unsigned* __restrict__ scal)
{
    int h = blockIdx.x, t = threadIdx.x, wid = t >> 6, lane = t & 63;
    const float* A = a2 + (long)h * 65536;
    float cs = 0.f, rs = 0.f;
    for (int i = 0; i < 256; i++) cs += A[(long)i * 256 + t];
    for (int j = 0; j < 256; j++) rs += A[(long)t * 256 + j];
    __shared__ float r1[4], r2[4];
    float m1v = cs, m2v = rs;
#pragma unroll
    for (int o = 32; o > 0; o >>= 1) {
        m1v = fmaxf(m1v, __shfl_down(m1v, o));
        m2v = fmaxf(m2v, __shfl_down(m2v, o));
    }
    if (lane == 0) { r1[wid] = m1v; r2[wid] = m2v; }
    __syncthreads();
    if (t == 0) {
        float a = fmaxf(fmaxf(r1[0], r1[1]), fmaxf(r1[2], r1[3]));
        float b = fmaxf(fmaxf(r2[0], r2[1]), fmaxf(r2[2], r2[3]));
        atomicMax(scal + 0, __float_as_uint(a));
        atomicMax(scal + 1, __float_as_uint(b));
    }
}

// ---------------- z0 = a2^T / (scal0*scal1)
__global__ __launch_bounds__(256)
void k_zinit(const float* __restrict__ a2, float* __restrict__ z, const unsigned* __restrict__ scal)
{
    float s = 1.f / (__uint_as_float(scal[0]) * __uint_as_float(scal[1]));
    const float* A = a2 + (long)blockIdx.z * 65536;
    float* Z = z + (long)blockIdx.z * 65536;
    __shared__ float tile[32][33];
    int tx = threadIdx.x & 31, ty = threadIdx.x >> 5;
    int i0 = blockIdx.x * 32, j0 = blockIdx.y * 32;
#pragma unroll
    for (int u = 0; u < 4; u++) tile[ty + u * 8][tx] = A[(long)(j0 + ty + u * 8) * 256 + i0 + tx];
    __syncthreads();
#pragma unroll
    for (int u = 0; u < 4; u++) Z[(long)(i0 + ty + u * 8) * 256 + j0 + tx] = tile[tx][ty + u * 8] * s;
}

// ---------------- a3 @ v, split-K partials with online softmax (bf16 k,v)
__global__ __launch_bounds__(256)
void k_a3v_partial(const float* __restrict__ ql, const ushort* __restrict__ k,
                   const ushort* __restrict__ v,
                   float* __restrict__ pacc, float* __restrict__ pml)
{
    int c = blockIdx.x, h = blockIdx.y, i = threadIdx.x;
    __shared__ float kt[16][64], vt[16][64];
    float qr[64], acc[64];
#pragma unroll
    for (int d = 0; d < 64; d++) { qr[d] = ql[((long)h * 256 + i) * 64 + d]; acc[d] = 0.f; }
    float m = -INFINITY, l = 0.f;
    const ushort* kb = k + (long)h * NPQ * 64;
    const ushort* vb = v + (long)h * NPQ * 64;
    int base = c * 256;
    for (int t0 = 0; t0 < 256; t0 += 16) {
        __syncthreads();
        int idx = threadIdx.x * 4;
        int r = idx >> 6, col = idx & 63;
        ushort4 kr4 = *(const ushort4*)(kb + (long)(base + t0 + r) * 64 + col);
        ushort4 vr4 = *(const ushort4*)(vb + (long)(base + t0 + r) * 64 + col);
        kt[r][col + 0] = bf2f(kr4.x); kt[r][col + 1] = bf2f(kr4.y);
        kt[r][col + 2] = bf2f(kr4.z); kt[r][col + 3] = bf2f(kr4.w);
        vt[r][col + 0] = bf2f(vr4.x); vt[r][col + 1] = bf2f(vr4.y);
        vt[r][col + 2] = bf2f(vr4.z); vt[r][col + 3] = bf2f(vr4.w);
        __syncthreads();
        for (int jj = 0; jj < 16; jj++) {
            float s = 0.f;
#pragma unroll
            for (int d = 0; d < 64; d++) s = fmaf(qr[d], kt[jj][d], s);
            if (s > m) {
                float f = __expf(m - s);
                l = l * f + 1.f;
#pragma unroll
                for (int d = 0; d < 64; d++) acc[d] = acc[d] * f + vt[jj][d];
                m = s;
            } else {
                float p = __expf(s - m);
                l += p;
#pragma unroll
                for (int d = 0; d < 64; d++) acc[d] = fmaf(p, vt[jj][d], acc[d]);
            }
        }
    }
    long pb = (long)(h * 60 + c) * 64 * 256;
#pragma unroll
    for (int d = 0; d < 64; d++) pacc[pb + (long)d * 256 + i] = acc[d];
    pml[(long)(h * 60 + c) * 2 * 256 + i] = m;
    pml[((long)(h * 60 + c) * 2 + 1) * 256 + i] = l;
}

__global__ __launch_bounds__(256)
void k_a3v_merge(const float* __restrict__ pacc, const float* __restrict__ pml,
                 float* __restrict__ t1)
{
    int d = blockIdx.x, h = blockIdx.y, i = threadIdx.x;
    float M = -INFINITY, L = 0.f, num = 0.f;
    for (int c = 0; c < 60; c++) {
        float mc = pml[(long)(h * 60 + c) * 2 * 256 + i];
        float lc = pml[((long)(h * 60 + c) * 2 + 1) * 256 + i];
        float ac = pacc[((long)(h * 60 + c) * 64 + d) * 256 + i];
        if (mc > M) {
            float f = __expf(M - mc);
            num = num * f + ac; L = L * f + lc; M = mc;
        } else {
            float p = __expf(mc - M);
            num = fmaf(p, ac, num); L = fmaf(p, lc, L);
        }
    }
    t1[((long)h * 256 + i) * 64 + d] = num / L;
}

// ---------------- depthwise 1D conv (k=33) on bf16 v, += into fp32 oh
__global__ __launch_bounds__(256)
void k_resconv(float* __restrict__ oh, const ushort* __restrict__ v,
               const float* __restrict__ rw, int Mrows)
{
    int h = blockIdx.y;
    int d = threadIdx.x & 63, r = threadIdx.x >> 6;
    int tk = blockIdx.x * 4 + r;
    if (tk >= Mrows) return;
    const ushort* vb = v + (long)h * NPQ * 64 + d;
    float acc = 0.f;
    int center = 230 + tk;
#pragma unroll
    for (int kk = 0; kk < 33; kk++) {
        int src = center + kk - 16;
        if (src >= 0 && src < NP) acc = fmaf(rw[h * 33 + kk], bf2f(vb[(long)src * 64]), acc);
    }
    oh[(long)tk * 512 + h * 64 + d] += acc;
}

// ---------------- layer-2 cls-token attention row: sim1(row0)+softmax+@Bm+resconv -> oh row0
__global__ __launch_bounds__(256)
void k_cls(const ushort* __restrict__ qb, const float* __restrict__ klT,
           const float* __restrict__ Bm, const ushort* __restrict__ vb,
           const float* __restrict__ rw, float* __restrict__ oh)
{
    int h = blockIdx.x, t = threadIdx.x, wid = t >> 6, lane = t & 63;
    __shared__ float qs[64], p[256], red[256];
    __shared__ float rm[4], rsum[4], fin[2];
    if (t < 64) qs[t] = bf2f(qb[((long)h * NPQ + 230) * 64 + t]);
    __syncthreads();
    float s = 0.f;
    for (int d = 0; d < 64; d++) s = fmaf(qs[d], klT[((long)h * 64 + d) * 256 + t], s);
    float m = s;
#pragma unroll
    for (int o = 32; o > 0; o >>= 1) m = fmaxf(m, __shfl_down(m, o));
    if (lane == 0) rm[wid] = m;
    __syncthreads();
    if (t == 0) fin[0] = fmaxf(fmaxf(rm[0], rm[1]), fmaxf(rm[2], rm[3]));
    __syncthreads();
    float e = __expf(s - fin[0]);
    float ss = e;
#pragma unroll
    for (int o = 32; o > 0; o >>= 1) ss += __shfl_down(ss, o);
    if (lane == 0) rsum[wid] = ss;
    __syncthreads();
    if (t == 0) fin[1] = rsum[0] + rsum[1] + rsum[2] + rsum[3];
    __syncthreads();
    p[t] = e / fin[1];
    __syncthreads();
    int d = t & 63, grp = t >> 6;
    float o = 0.f;
    for (int j = grp * 64; j < grp * 64 + 64; j++) o = fmaf(p[j], Bm[((long)h * 256 + j) * 64 + d], o);
    red[t] = o;
    __syncthreads();
    if (t < 64) {
        float val = red[t] + red[t + 64] + red[t + 128] + red[t + 192];
#pragma unroll
        for (int kk = 0; kk < 33; kk++)
            val = fmaf(rw[h * 33 + kk], bf2f(vb[((long)h * NPQ + 214 + kk) * 64 + t]), val);
        oh[h * 64 + t] = val;
    }
}

// ---------------- plain float4 copy
__global__ __launch_bounds__(256)
void k_copy4(const float4* __restrict__ src, float4* __restrict__ dst, long n4)
{
    long i = (long)blockIdx.x * 256 + threadIdx.x;
    if (i < n4) dst[i] = src[i];
}

// ---------------- PPEG: 7x7 + 5x5 + 3x3 depthwise + identity
__global__ __launch_bounds__(256)
void k_ppeg(const float* __restrict__ cnn, float* __restrict__ hbuf,
            const float* __restrict__ w7, const float* __restrict__ b7,
            const float* __restrict__ w5, const float* __restrict__ b5,
            const float* __restrict__ w3, const float* __restrict__ b3)
{
    __shared__ float tile[14 * 14 * 64];
    int lc = threadIdx.x & 63, sp0 = threadIdx.x >> 6;
    int c0 = blockIdx.x * 8, r0 = blockIdx.y * 8, cb = blockIdx.z * 64;
    for (int p = sp0; p < 196; p += 4) {
        int pr = p / 14, pc = p % 14;
        int gr = r0 + pr - 3, gc = c0 + pc - 3;
        float val = 0.f;
        if (gr >= 0 && gr < HG && gc >= 0 && gc < HG)
            val = cnn[(long)(gr * HG + gc) * 512 + cb + lc];
        tile[p * 64 + lc] = val;
    }
    __syncthreads();
    int c = cb + lc;
    float bb = b7[c] + b5[c] + b3[c];
    float acc[16];
    int bidx[16];
#pragma unroll
    for (int u = 0; u < 16; u++) {
        int sp = sp0 + 4 * u;
        int orr = sp >> 3, occ = sp & 7;
        bidx[u] = (orr * 14 + occ) * 64 + lc;
        acc[u] = bb + tile[((orr + 3) * 14 + (occ + 3)) * 64 + lc];
    }
    for (int kr = 0; kr < 7; kr++)
        for (int kc = 0; kc < 7; kc++) {
            float w = w7[c * 49 + kr * 7 + kc];
            int koff = (kr * 14 + kc) * 64;
#pragma unroll
            for (int u = 0; u < 16; u++) acc[u] = fmaf(w, tile[bidx[u] + koff], acc[u]);
        }
    for (int kr = 0; kr < 5; kr++)
        for (int kc = 0; kc < 5; kc++) {
            float w = w5[c * 25 + kr * 5 + kc];
            int koff = ((kr + 1) * 14 + kc + 1) * 64;
#pragma unroll
            for (int u = 0; u < 16; u++) acc[u] = fmaf(w, tile[bidx[u] + koff], acc[u]);
        }
    for (int kr = 0; kr < 3; kr++)
        for (int kc = 0; kc < 3; kc++) {
            float w = w3[c * 9 + kr * 3 + kc];
            int koff = ((kr + 2) * 14 + kc + 2) * 64;
#pragma unroll
            for (int u = 0; u < 16; u++) acc[u] = fmaf(w, tile[bidx[u] + koff], acc[u]);
        }
#pragma unroll
    for (int u = 0; u < 16; u++) {
        int sp = sp0 + 4 * u;
        int orr = sp >> 3, occ = sp & 7;
        int gr = r0 + orr, gc = c0 + occ;
        if (gr < HG && gc < HG)
            hbuf[(long)(1 + gr * HG + gc) * 512 + c] = acc[u];
    }
}

// ---------------- final: LN(row0) -> fc2 -> softmax/argmax
__global__ __launch_bounds__(256)
void k_final(const float* __restrict__ hbuf, const float* __restrict__ g,
             const float* __restrict__ b, const float* __restrict__ W2,
             const float* __restrict__ b2, float* __restrict__ out)
{
    __shared__ float y[512];
    __shared__ float rs[4], rq[4], st[2], lg[8];
    int t = threadIdx.x, wid = t >> 6, lane = t & 63;
    float x1 = hbuf[t], x2 = hbuf[t + 256];
    float s = x1 + x2, q = x1 * x1 + x2 * x2;
#pragma unroll
    for (int o = 32; o > 0; o >>= 1) { s += __shfl_down(s, o); q += __shfl_down(q, o); }
    if (lane == 0) { rs[wid] = s; rq[wid] = q; }
    __syncthreads();
    if (t == 0) {
        float S = rs[0] + rs[1] + rs[2] + rs[3];
        float Q = rq[0] + rq[1] + rq[2] + rq[3];
        float mean = S / 512.f;
        float var = Q / 512.f - mean * mean;
        st[0] = mean; st[1] = rsqrtf(var + 1e-5f);
    }
    __syncthreads();
    float mean = st[0], rstd = st[1];
    y[t] = (x1 - mean) * rstd * g[t] + b[t];
    y[t + 256] = (x2 - mean) * rstd * g[t + 256] + b[t + 256];
    __syncthreads();
    if (t < 5) {
        float acc = b2[t];
        for (int kx = 0; kx < 512; kx++) acc = fmaf(y[kx], W2[kx * 5 + t], acc);
        lg[t] = acc;
    }
    __syncthreads();
    if (t == 0) {
        float mx = lg[0]; int am = 0;
        for (int j = 1; j < 5; j++) if (lg[j] > mx) { mx = lg[j]; am = j; }
        float e[5], se = 0.f;
        for (int j = 0; j < 5; j++) { e[j] = __expf(lg[j] - mx); se += e[j]; }
        for (int j = 0; j < 5; j++) { out[j] = lg[j]; out[5 + j] = e[j] / se; }
        out[10] = (float)am;
    }
}

extern "C" void kernel_launch(void* const* d_in, const int* in_sizes, int n_in,
                              void* d_out, int out_size, void* d_ws, size_t ws_size,
                              hipStream_t stream)
{
    const float* data  = (const float*)d_in[0];
    const float* Wfc1  = (const float*)d_in[1];
    const float* bfc1  = (const float*)d_in[2];
    const float* cls   = (const float*)d_in[3];
    const float* ln1g  = (const float*)d_in[4];
    const float* ln1b  = (const float*)d_in[5];
    const float* qkv1  = (const float*)d_in[6];
    const float* out1w = (const float*)d_in[7];
    const float* out1b = (const float*)d_in[8];
    const float* res1  = (const float*)d_in[9];
    const float* w7    = (const float*)d_in[10];
    const float* b7    = (const float*)d_in[11];
    const float* w5    = (const float*)d_in[12];
    const float* b5    = (const float*)d_in[13];
    const float* w3    = (const float*)d_in[14];
    const float* b3    = (const float*)d_in[15];
    const float* ln2g  = (const float*)d_in[16];
    const float* ln2b  = (const float*)d_in[17];
    const float* qkv2  = (const float*)d_in[18];
    const float* out2w = (const float*)d_in[19];
    const float* out2b = (const float*)d_in[20];
    const float* res2  = (const float*)d_in[21];
    const float* normg = (const float*)d_in[22];
    const float* normb = (const float*)d_in[23];
    const float* Wfc2  = (const float*)d_in[24];
    const float* bfc2  = (const float*)d_in[25];
    float* out = (float*)d_out;

    float* W = (float*)d_ws;
    size_t off = 0;
    auto alloc = [&](size_t n) { size_t o = off; off += (n + 255) & ~(size_t)255; return o; };
    float*  hbuf   = W + alloc((size_t)NTOK * 512);
    float*  ohreg  = W + alloc((size_t)15232 * 512);          // fp32 oh; bf16 xln aliases here
    float*  oh     = ohreg;
    ushort* xln    = (ushort*)ohreg;
    ushort* qb16   = (ushort*)(W + alloc((size_t)8 * NPQ * 32));   // bf16: 8*NPQ*64 elems = /2 floats
    ushort* kb16   = (ushort*)(W + alloc((size_t)8 * NPQ * 32));
    ushort* vb16   = (ushort*)(W + alloc((size_t)8 * NPQ * 32));
    float*  ql     = W + alloc(8 * 256 * 64);
    float*  klT    = W + alloc(8 * 64 * 256);
    ushort* klb    = (ushort*)(W + alloc(8 * 256 * 32));
    float*  a2     = W + alloc(8 * 65536);
    float*  z0     = W + alloc(8 * 65536);
    float*  z1     = W + alloc(8 * 65536);
    float*  m1     = W + alloc(8 * 65536);
    float*  ma     = W + alloc(8 * 65536);
    float*  mb     = W + alloc(8 * 65536);
    float*  t1     = W + alloc(8 * 256 * 64);
    float*  Bm     = W + alloc(8 * 256 * 64);
    ushort* BmT16  = (ushort*)(W + alloc(8 * 64 * 128));
    float*  scal   = W + alloc(64);
    ushort* simb16 = (ushort*)(W + alloc((size_t)3840 * 128 * 8));  // bf16 3840*256*8
    ushort* ohb16  = (ushort*)(W + alloc((size_t)15232 * 256));     // bf16 15232*512
    ushort* WfcT   = (ushort*)(W + alloc(1024 * 256));              // bf16 512*1024
    ushort* qkv1T  = (ushort*)(W + alloc(1536 * 256));              // bf16 1536*512
    ushort* qkv2T  = (ushort*)(W + alloc(1536 * 256));
    ushort* out1T  = (ushort*)(W + alloc(512 * 256));               // bf16 512*512
    ushort* out2T  = (ushort*)(W + alloc(512 * 256));
    float*  big    = W + alloc(7987200);   // datab | pacc+pml | sim1 slabs | ppeg cnn
    ushort* datab  = (ushort*)big;         // bf16 15104*1024
    float*  pacc   = big;
    float*  pml    = big + 7864320;
    float*  simbuf = big;
    float*  cnn    = big;
    if (ws_size < off * sizeof(float)) return;

    // ---- prep: weight transposes + data cvt, fc1 (MFMA) ----
    k_wT<<<dim3(16, 32, 1), 256, 0, stream>>>(Wfc1, WfcT, 1024, 512, 0, 0);
    k_wT<<<dim3(48, 16, 1), 256, 0, stream>>>(qkv1, qkv1T, 512, 1536, 0, 0);
    k_wT<<<dim3(48, 16, 1), 256, 0, stream>>>(qkv2, qkv2T, 512, 1536, 0, 0);
    k_wT<<<dim3(16, 16, 1), 256, 0, stream>>>(out1w, out1T, 512, 512, 0, 0);
    k_wT<<<dim3(16, 16, 1), 256, 0, stream>>>(out2w, out2T, 512, 512, 0, 0);
    k_cvt<<<15000, 256, 0, stream>>>((const float4*)data, (ushort4*)datab, 3840000);
    gemm_mfma<4, 4, 2, 2><<<dim3(4, 118, 1), 256, 0, stream>>>(
        datab, 1024, 0, WfcT, 1024, 0, hbuf + 512, 512, 0, 15000, 1024, bfc1, 1, 0);
    k_padcls<<<130, 256, 0, stream>>>(hbuf, cls);

    auto layer = [&](const float* lng, const float* lnb, const ushort* qkvT,
                     const float* outW, const ushort* outT, const float* outB,
                     const float* resW, bool full) {
        k_layernorm<<<NP, 256, 0, stream>>>(hbuf, xln, lng, lnb, 230);
        gemm_qkv_mfma<<<dim3(12, 120, 1), 256, 0, stream>>>(xln, qkvT, qb16, kb16, vb16);
        k_landmarks<<<dim3(256, 8), 64, 0, stream>>>(qb16, kb16, ql, klT, klb, (unsigned*)scal);
        gemm_f32<<<dim3(4, 4, 8), 256, 0, stream>>>(ql, 64, 16384, klT, 256, 16384,
            a2, 256, 65536, 256, 256, 64, nullptr, nullptr, 0, 0, 0.f, 1.f, 0, 0);
        k_softmax256<<<dim3(256, 8), 256, 0, stream>>>(a2, 65536);
        k_colmax<<<8, 256, 0, stream>>>(a2, (unsigned*)scal);
        k_zinit<<<dim3(8, 8, 8), 256, 0, stream>>>(a2, z0, (const unsigned*)scal);
        float* zi = z0; float* zo = z1;
        for (int it = 0; it < 6; ++it) {
            gemm_f32<<<dim3(4, 4, 8), 256, 0, stream>>>(a2, 256, 65536, zi, 256, 65536,
                m1, 256, 65536, 256, 256, 256, nullptr, nullptr, 0, 0, 0.f, 1.f, 0, 0);
            gemm_f32<<<dim3(4, 4, 8), 256, 0, stream>>>(m1, 256, 65536, m1, 256, 65536,
                ma, 256, 65536, 256, 256, 256, nullptr, m1, 256, 65536, 7.f, -1.f, 0, 0);
            gemm_f32<<<dim3(4, 4, 8), 256, 0, stream>>>(m1, 256, 65536, ma, 256, 65536,
                mb, 256, 65536, 256, 256, 256, nullptr, m1, 256, 65536, 15.f, -1.f, 0, 0);
            gemm_f32<<<dim3(4, 4, 8), 256, 0, stream>>>(zi, 256, 65536, mb, 256, 65536,
                zo, 256, 65536, 256, 256, 256, nullptr, zi, 256, 65536, 3.25f, -0.25f, 0, 0);
            float* tmp = zi; zi = zo; zo = tmp;
        }
        k_a3v_partial<<<dim3(60, 8), 256, 0, stream>>>(ql, kb16, vb16, pacc, pml);
        k_a3v_merge<<<dim3(64, 8), 256, 0, stream>>>(pacc, pml, t1);
        gemm_f32<<<dim3(1, 4, 8), 256, 0, stream>>>(zi, 256, 65536, t1, 64, 16384,
            Bm, 64, 16384, 256, 64, 256, nullptr, nullptr, 0, 0, 0.f, 1.f, 0, 0);
        if (full) {
            k_wT<<<dim3(2, 8, 8), 256, 0, stream>>>(Bm, BmT16, 256, 64, 16384, 16384);
            for (int s0 = 0; s0 < NTOK; s0 += 3840) {
                int ms = NTOK - s0 < 3840 ? NTOK - s0 : 3840;
                int gy = (ms + 127) / 128;
                gemm_mfma<4, 4, 2, 2><<<dim3(2, gy, 8), 256, 0, stream>>>(
                    qb16 + (long)(230 + s0) * 64, 64, (long)NPQ * 64,
                    klb, 64, 16384,
                    simbuf, 256, (long)3840 * 256, ms, 64, nullptr, 0, 0);
                k_softmax256b<<<dim3(ms, 8), 256, 0, stream>>>(simbuf, simb16,
                    (long)3840 * 256, (long)3840 * 256);
                gemm_mfma<2, 4, 4, 1><<<dim3(1, gy, 8), 256, 0, stream>>>(
                    simb16, 256, (long)3840 * 256,
                    BmT16, 256, 16384,
                    oh + (long)s0 * 512, 512, 64, ms, 256, nullptr, 0, 0);
            }
            k_resconv<<<dim3((NTOK + 3) / 4, 8), 256, 0, stream>>>(oh, vb16, resW, NTOK);
            k_cvt<<<7565, 256, 0, stream>>>((const float4*)oh, (ushort4*)ohb16, 1936640);
            gemm_mfma<4, 4, 2, 2><<<dim3(4, 119, 1), 256, 0, stream>>>(
                ohb16, 512, 0, outT, 512, 0, hbuf, 512, 0, NTOK, 512, outB, 0, 1);
        } else {
            k_cls<<<8, 256, 0, stream>>>(qb16, klT, Bm, vb16, resW, oh);
            gemm_f32<<<dim3(8, 1, 1), 256, 0, stream>>>(oh, 512, 0, outW, 512, 0,
                hbuf, 512, 0, 1, 512, 512, outB, nullptr, 0, 0, 0.f, 1.f, 0, 1);
        }
    };

    layer(ln1g, ln1b, qkv1T, out1w, out1T, out1b, res1, true);
    k_copy4<<<(1936512 + 255) / 256, 256, 0, stream>>>((const float4*)(hbuf + 512), (float4*)cnn, 1936512);
    k_ppeg<<<dim3(16, 16, 8), 256, 0, stream>>>(cnn, hbuf, w7, b7, w5, b5, w3, b3);
    layer(ln2g, ln2b, qkv2T, out2w, out2T, out2b, res2, false);
    k_final<<<1, 256, 0, stream>>>(hbuf, normg, normb, Wfc2, bfc2, out);
}

// Round 3
// 1896.459 us; speedup vs baseline: 1.7870x; 1.3029x over previous
//
#include <hip/hip_runtime.h>
#include <math.h>

#define NP 15360
#define NPQ 15488
#define NTOK 15130
#define HG 123

typedef __attribute__((ext_vector_type(8))) short s8b;
typedef __attribute__((ext_vector_type(4))) float f4;

__device__ inline float bf2f(ushort u) { return __uint_as_float(((unsigned)u) << 16); }
__device__ inline ushort f2bf(float f) {
    unsigned u = __float_as_uint(f);
    unsigned r = (u + 0x7fffu + ((u >> 16) & 1u)) >> 16;
    return (ushort)r;
}

// ---------------- generic fp32 GEMM (small/sensitive ops): C = cS*(A@B) + eS*E + bias
__global__ __launch_bounds__(256)
void gemm_f32(const float* __restrict__ A, int lda, long sA,
              const float* __restrict__ B, int ldb, long sB,
              float* __restrict__ C, int ldc, long sC,
              int M, int N, int K,
              const float* __restrict__ bias,
              const float* __restrict__ E, int ldE, long sE, float eS,
              float cS, int relu, int accum)
{
    A += (long)blockIdx.z * sA;
    B += (long)blockIdx.z * sB;
    C += (long)blockIdx.z * sC;
    if (E) E += (long)blockIdx.z * sE;
    const int m0 = blockIdx.y * 64, n0 = blockIdx.x * 64;
    const int t = threadIdx.x;
    const int tx = t & 15, ty = t >> 4;
    __shared__ float As[16][64];
    __shared__ float Bs[16][64];
    float acc[4][4] = {};
    const int arow = t >> 2, akc = (t & 3) * 4;
    const int brow = t >> 4, bnc = (t & 15) * 4;
    for (int k0 = 0; k0 < K; k0 += 16) {
        float4 av = make_float4(0.f, 0.f, 0.f, 0.f);
        if (m0 + arow < M) av = *(const float4*)(A + (long)(m0 + arow) * lda + k0 + akc);
        As[akc + 0][arow] = av.x; As[akc + 1][arow] = av.y;
        As[akc + 2][arow] = av.z; As[akc + 3][arow] = av.w;
        float4 bv = *(const float4*)(B + (long)(k0 + brow) * ldb + n0 + bnc);
        *(float4*)&Bs[brow][bnc] = bv;
        __syncthreads();
#pragma unroll
        for (int kk = 0; kk < 16; ++kk) {
            float4 a4 = *(const float4*)&As[kk][ty * 4];
            float4 b4 = *(const float4*)&Bs[kk][tx * 4];
            float a[4] = {a4.x, a4.y, a4.z, a4.w};
            float b[4] = {b4.x, b4.y, b4.z, b4.w};
#pragma unroll
            for (int i = 0; i < 4; i++)
#pragma unroll
                for (int j = 0; j < 4; j++) acc[i][j] = fmaf(a[i], b[j], acc[i][j]);
        }
        __syncthreads();
    }
#pragma unroll
    for (int i = 0; i < 4; i++) {
        int m = m0 + ty * 4 + i;
        if (m < M) {
#pragma unroll
            for (int j = 0; j < 4; j++) {
                int n = n0 + tx * 4 + j;
                float v = cS * acc[i][j];
                if (E) v = fmaf(eS, E[(long)m * ldE + n], v);
                if (bias) v += bias[n];
                if (relu) v = fmaxf(v, 0.f);
                if (accum) C[(long)m * ldc + n] += v;
                else C[(long)m * ldc + n] = v;
            }
        }
    }
}

// ---------------- bf16 MFMA GEMM: C(fp32) = A(bf16,[M][K]) @ Bt(bf16,[N][K])^T
template<int MT, int NT, int WROWS, int WCOLS>
__global__ __launch_bounds__(256)
void gemm_mfma(const ushort* __restrict__ A, int lda, long sA,
               const ushort* __restrict__ Bt, int ldb, long sB,
               float* __restrict__ C, int ldc, long sC,
               int M, int K,
               const float* __restrict__ bias, int relu, int accum)
{
    constexpr int TM = MT * 16 * WROWS;
    constexpr int TN = NT * 16 * WCOLS;
    constexpr int BKP = 40;
    __shared__ ushort As[TM * BKP];
    __shared__ ushort Bs[TN * BKP];
    A  += (long)blockIdx.z * sA;
    Bt += (long)blockIdx.z * sB;
    C  += (long)blockIdx.z * sC;
    const int t = threadIdx.x;
    const int m0 = blockIdx.y * TM, n0 = blockIdx.x * TN;
    const int w = t >> 6, l = t & 63;
    const int wm = (w / WCOLS) * (MT * 16), wn = (w % WCOLS) * (NT * 16);
    const int lr = l & 15;
    const int lk = (l >> 4) * 8;
    f4 acc[MT][NT] = {};
    for (int k0 = 0; k0 < K; k0 += 32) {
        for (int c = t; c < TM * 4; c += 256) {
            int row = c >> 2, kc = (c & 3) * 8;
            s8b v = *(const s8b*)(A + (long)(m0 + row) * lda + k0 + kc);
            *(s8b*)(&As[row * BKP + kc]) = v;
        }
        for (int c = t; c < TN * 4; c += 256) {
            int row = c >> 2, kc = (c & 3) * 8;
            s8b v = *(const s8b*)(Bt + (long)(n0 + row) * ldb + k0 + kc);
            *(s8b*)(&Bs[row * BKP + kc]) = v;
        }
        __syncthreads();
        s8b af[MT], bf[NT];
#pragma unroll
        for (int i = 0; i < MT; i++) af[i] = *(const s8b*)(&As[(wm + i * 16 + lr) * BKP + lk]);
#pragma unroll
        for (int j = 0; j < NT; j++) bf[j] = *(const s8b*)(&Bs[(wn + j * 16 + lr) * BKP + lk]);
#pragma unroll
        for (int i = 0; i < MT; i++)
#pragma unroll
            for (int j = 0; j < NT; j++)
                acc[i][j] = __builtin_amdgcn_mfma_f32_16x16x32_bf16(af[i], bf[j], acc[i][j], 0, 0, 0);
        __syncthreads();
    }
    const int orow = (l >> 4) * 4;
#pragma unroll
    for (int i = 0; i < MT; i++) {
#pragma unroll
        for (int r = 0; r < 4; r++) {
            int m = m0 + wm + i * 16 + orow + r;
            if (m < M) {
#pragma unroll
                for (int j = 0; j < NT; j++) {
                    int n = n0 + wn + j * 16 + lr;
                    float vv = acc[i][j][r];
                    if (bias) vv += bias[n];
                    if (relu) vv = fmaxf(vv, 0.f);
                    if (accum) C[(long)m * ldc + n] += vv;
                    else C[(long)m * ldc + n] = vv;
                }
            }
        }
    }
}

// ---------------- bf16-in/bf16-out MFMA GEMM, B row-major [K][N]: C16 = bf16(cS*(A@B) + eS*E16)
__global__ __launch_bounds__(256)
void gemm_nn16(const ushort* __restrict__ A, const ushort* __restrict__ B,
               const ushort* __restrict__ E, ushort* __restrict__ C,
               int N, int K, float cS, float eS, long sAB)
{
    __shared__ ushort As[64 * 40];
    __shared__ ushort Bs[64 * 40];
    A += (long)blockIdx.z * sAB;
    B += (long)blockIdx.z * sAB;
    if (E) E += (long)blockIdx.z * sAB;
    C += (long)blockIdx.z * sAB;
    const int t = threadIdx.x;
    const int m0 = blockIdx.y * 64, n0 = blockIdx.x * 64;
    const int w = t >> 6, l = t & 63;
    const int wm = (w >> 1) * 32, wn = (w & 1) * 32;
    const int lr = l & 15, lk = (l >> 4) * 8;
    f4 acc[2][2] = {};
    for (int k0 = 0; k0 < K; k0 += 32) {
        {
            int row = t >> 2, kc = (t & 3) * 8;
            s8b v = *(const s8b*)(A + (long)(m0 + row) * K + k0 + kc);
            *(s8b*)(&As[row * 40 + kc]) = v;
            int kk = t >> 3, nc = (t & 7) * 8;
            s8b vb = *(const s8b*)(B + (long)(k0 + kk) * N + n0 + nc);
#pragma unroll
            for (int j = 0; j < 8; j++) Bs[(nc + j) * 40 + kk] = ((ushort*)&vb)[j];
        }
        __syncthreads();
        s8b af[2], bf[2];
#pragma unroll
        for (int i = 0; i < 2; i++) af[i] = *(const s8b*)(&As[(wm + i * 16 + lr) * 40 + lk]);
#pragma unroll
        for (int j = 0; j < 2; j++) bf[j] = *(const s8b*)(&Bs[(wn + j * 16 + lr) * 40 + lk]);
#pragma unroll
        for (int i = 0; i < 2; i++)
#pragma unroll
            for (int j = 0; j < 2; j++)
                acc[i][j] = __builtin_amdgcn_mfma_f32_16x16x32_bf16(af[i], bf[j], acc[i][j], 0, 0, 0);
        __syncthreads();
    }
    const int orow = (l >> 4) * 4;
#pragma unroll
    for (int i = 0; i < 2; i++)
#pragma unroll
        for (int r = 0; r < 4; r++) {
            int m = m0 + wm + i * 16 + orow + r;
#pragma unroll
            for (int j = 0; j < 2; j++) {
                int n = n0 + wn + j * 16 + lr;
                float vv = cS * acc[i][j][r];
                if (E) vv = fmaf(eS, bf2f(E[(long)m * N + n]), vv);
                C[(long)m * N + n] = f2bf(vv);
            }
        }
}

// ---------------- qkv MFMA GEMM, scatter into bf16 q/k/v [head][NPQ][64], q scaled 1/8
__global__ __launch_bounds__(256)
void gemm_qkv_mfma(const ushort* __restrict__ A, const ushort* __restrict__ Bt,
                   ushort* __restrict__ qo, ushort* __restrict__ ko, ushort* __restrict__ vo)
{
    constexpr int BKP = 40;
    __shared__ ushort As[128 * BKP];
    __shared__ ushort Bs[128 * BKP];
    const int t = threadIdx.x;
    const int m0 = blockIdx.y * 128, n0 = blockIdx.x * 128;
    const int w = t >> 6, l = t & 63;
    const int wm = (w >> 1) * 64, wn = (w & 1) * 64;
    const int lr = l & 15;
    const int lk = (l >> 4) * 8;
    f4 acc[4][4] = {};
    for (int k0 = 0; k0 < 512; k0 += 32) {
        for (int c = t; c < 512; c += 256) {
            int row = c >> 2, kc = (c & 3) * 8;
            s8b va = *(const s8b*)(A + (long)(m0 + row) * 512 + k0 + kc);
            *(s8b*)(&As[row * BKP + kc]) = va;
            s8b vb = *(const s8b*)(Bt + (long)(n0 + row) * 512 + k0 + kc);
            *(s8b*)(&Bs[row * BKP + kc]) = vb;
        }
        __syncthreads();
        s8b af[4], bf[4];
#pragma unroll
        for (int i = 0; i < 4; i++) af[i] = *(const s8b*)(&As[(wm + i * 16 + lr) * BKP + lk]);
#pragma unroll
        for (int j = 0; j < 4; j++) bf[j] = *(const s8b*)(&Bs[(wn + j * 16 + lr) * BKP + lk]);
#pragma unroll
        for (int i = 0; i < 4; i++)
#pragma unroll
            for (int j = 0; j < 4; j++)
                acc[i][j] = __builtin_amdgcn_mfma_f32_16x16x32_bf16(af[i], bf[j], acc[i][j], 0, 0, 0);
        __syncthreads();
    }
    const int orow = (l >> 4) * 4;
#pragma unroll
    for (int i = 0; i < 4; i++) {
#pragma unroll
        for (int r = 0; r < 4; r++) {
            int m = m0 + wm + i * 16 + orow + r;
#pragma unroll
            for (int j = 0; j < 4; j++) {
                int col = n0 + wn + j * 16 + lr;
                int which = col >> 9, h = (col >> 6) & 7, d = col & 63;
                float vv = acc[i][j][r];
                if (which == 0) vv *= 0.125f;
                ushort* dst = which == 0 ? qo : (which == 1 ? ko : vo);
                dst[((long)h * NPQ + m) * 64 + d] = f2bf(vv);
            }
        }
    }
}

// ---------------- flash a3@v: per (key-chunk, q-tile, head); MFMA QK^T + online softmax + MFMA PV
__global__ __launch_bounds__(256)
void k_flash_a3v(const ushort* __restrict__ qlb, const ushort* __restrict__ kg,
                 const ushort* __restrict__ vg,
                 float* __restrict__ pacc, float* __restrict__ pml)
{
    const int c = blockIdx.x;      // key chunk (256 keys)
    const int qt = blockIdx.y;     // q-tile (128 landmarks)
    const int h = blockIdx.z;
    const int t = threadIdx.x;
    const int w = t >> 6, lane = t & 63;
    const int quad = lane >> 4, l16 = lane & 15;

    __shared__ union {
        struct { ushort Vt[64][40]; ushort Ps[128][40]; } s;
        float Os[128][68];
    } L;

    s8b aq[2][2];
    const ushort* qbase = qlb + ((long)h * 256 + qt * 128 + w * 32) * 64;
#pragma unroll
    for (int mi = 0; mi < 2; mi++)
#pragma unroll
        for (int kf = 0; kf < 2; kf++)
            aq[mi][kf] = *(const s8b*)(qbase + (mi * 16 + l16) * 64 + kf * 32 + quad * 8);

    f4 oacc[2][4] = {};
    float mrow[2][4], lrow[2][4];
#pragma unroll
    for (int mi = 0; mi < 2; mi++)
#pragma unroll
        for (int r = 0; r < 4; r++) { mrow[mi][r] = -INFINITY; lrow[mi][r] = 0.f; }

    const ushort* kh = kg + (long)h * NPQ * 64;
    const ushort* vh = vg + (long)h * NPQ * 64;
    const int key0c = c * 256;

    for (int sub = 0; sub < 8; sub++) {
        int key0 = key0c + sub * 32;
        __syncthreads();
        {   // stage V^T [dim][key]
            int kk = t >> 3, dc = (t & 7) * 8;
            s8b vv = *(const s8b*)(vh + (long)(key0 + kk) * 64 + dc);
#pragma unroll
            for (int j = 0; j < 8; j++) L.s.Vt[dc + j][kk] = ((ushort*)&vv)[j];
        }
        s8b bq[2][2];
#pragma unroll
        for (int nj = 0; nj < 2; nj++)
#pragma unroll
            for (int kf = 0; kf < 2; kf++)
                bq[nj][kf] = *(const s8b*)(kh + (long)(key0 + nj * 16 + l16) * 64 + kf * 32 + quad * 8);
        f4 sacc[2][2] = {};
#pragma unroll
        for (int mi = 0; mi < 2; mi++)
#pragma unroll
            for (int nj = 0; nj < 2; nj++) {
                sacc[mi][nj] = __builtin_amdgcn_mfma_f32_16x16x32_bf16(aq[mi][0], bq[nj][0], sacc[mi][nj], 0, 0, 0);
                sacc[mi][nj] = __builtin_amdgcn_mfma_f32_16x16x32_bf16(aq[mi][1], bq[nj][1], sacc[mi][nj], 0, 0, 0);
            }
#pragma unroll
        for (int mi = 0; mi < 2; mi++)
#pragma unroll
            for (int r = 0; r < 4; r++) {
                float mx = fmaxf(sacc[mi][0][r], sacc[mi][1][r]);
#pragma unroll
                for (int d = 1; d < 16; d <<= 1) mx = fmaxf(mx, __shfl_xor(mx, d));
                float mn = fmaxf(mrow[mi][r], mx);
                float f = __expf(mrow[mi][r] - mn);
                float p0 = __expf(sacc[mi][0][r] - mn);
                float p1 = __expf(sacc[mi][1][r] - mn);
                float ps = p0 + p1;
#pragma unroll
                for (int d = 1; d < 16; d <<= 1) ps += __shfl_xor(ps, d);
                lrow[mi][r] = lrow[mi][r] * f + ps;
                mrow[mi][r] = mn;
#pragma unroll
                for (int dj = 0; dj < 4; dj++) oacc[mi][dj][r] *= f;
                int row = w * 32 + mi * 16 + quad * 4 + r;
                L.s.Ps[row][l16]      = f2bf(p0);
                L.s.Ps[row][16 + l16] = f2bf(p1);
            }
        __syncthreads();
        s8b ap[2], bv[4];
#pragma unroll
        for (int mi = 0; mi < 2; mi++)
            ap[mi] = *(const s8b*)(&L.s.Ps[w * 32 + mi * 16 + l16][quad * 8]);
#pragma unroll
        for (int dj = 0; dj < 4; dj++)
            bv[dj] = *(const s8b*)(&L.s.Vt[dj * 16 + l16][quad * 8]);
#pragma unroll
        for (int mi = 0; mi < 2; mi++)
#pragma unroll
            for (int dj = 0; dj < 4; dj++)
                oacc[mi][dj] = __builtin_amdgcn_mfma_f32_16x16x32_bf16(ap[mi], bv[dj], oacc[mi][dj], 0, 0, 0);
    }
    __syncthreads();
#pragma unroll
    for (int mi = 0; mi < 2; mi++)
#pragma unroll
        for (int dj = 0; dj < 4; dj++)
#pragma unroll
            for (int r = 0; r < 4; r++)
                L.Os[w * 32 + mi * 16 + quad * 4 + r][dj * 16 + l16] = oacc[mi][dj][r];
    long pbase = (long)(h * 60 + c);
    if (l16 == 0) {
#pragma unroll
        for (int mi = 0; mi < 2; mi++)
#pragma unroll
            for (int r = 0; r < 4; r++) {
                int i = qt * 128 + w * 32 + mi * 16 + quad * 4 + r;
                pml[pbase * 512 + i] = mrow[mi][r];
                pml[pbase * 512 + 256 + i] = lrow[mi][r];
            }
    }
    __syncthreads();
    float* pc = pacc + pbase * 16384 + qt * 128;
    int d = t >> 2, ig = t & 3;
#pragma unroll
    for (int u = 0; u < 8; u++) {
        int i0 = ig * 32 + u * 4;
        float4 v4 = make_float4(L.Os[i0][d], L.Os[i0 + 1][d], L.Os[i0 + 2][d], L.Os[i0 + 3][d]);
        *(float4*)(pc + (long)d * 256 + i0) = v4;
    }
}

// ---------------- layernorm over 512, writes bf16 xln (first `pad` rows zero)
__global__ __launch_bounds__(256)
void k_layernorm(const float* __restrict__ h, ushort* __restrict__ xln,
                 const float* __restrict__ g, const float* __restrict__ b, int pad)
{
    int row = blockIdx.x, t = threadIdx.x;
    if (row < pad) {
        xln[(long)row * 512 + t] = 0;
        xln[(long)row * 512 + t + 256] = 0;
        return;
    }
    const float* src = h + (long)(row - pad) * 512;
    float x1 = src[t], x2 = src[t + 256];
    float s = x1 + x2, q = x1 * x1 + x2 * x2;
    __shared__ float rs[4], rq[4], st[2];
    int wid = t >> 6, lane = t & 63;
#pragma unroll
    for (int o = 32; o > 0; o >>= 1) { s += __shfl_down(s, o); q += __shfl_down(q, o); }
    if (lane == 0) { rs[wid] = s; rq[wid] = q; }
    __syncthreads();
    if (t == 0) {
        float S = rs[0] + rs[1] + rs[2] + rs[3];
        float Q = rq[0] + rq[1] + rq[2] + rq[3];
        float mean = S / 512.f;
        float var = Q / 512.f - mean * mean;
        st[0] = mean; st[1] = rsqrtf(var + 1e-5f);
    }
    __syncthreads();
    float mean = st[0], rstd = st[1];
    xln[(long)row * 512 + t] = f2bf((x1 - mean) * rstd * g[t] + b[t]);
    xln[(long)row * 512 + t + 256] = f2bf((x2 - mean) * rstd * g[t + 256] + b[t + 256]);
}

__global__ __launch_bounds__(256)
void k_padcls(float* __restrict__ hbuf, const float* __restrict__ cls)
{
    int i = blockIdx.x, t = threadIdx.x;
    if (i == 0) { hbuf[t] = cls[t]; hbuf[t + 256] = cls[t + 256]; }
    else {
        hbuf[(long)(15000 + i) * 512 + t] = hbuf[(long)i * 512 + t];
        hbuf[(long)(15000 + i) * 512 + t + 256] = hbuf[(long)i * 512 + t + 256];
    }
}

__global__ __launch_bounds__(256)
void k_wT(const float* __restrict__ Wm, ushort* __restrict__ Wt, int K, int N, long sW, long sWt)
{
    Wm += (long)blockIdx.z * sW; Wt += (long)blockIdx.z * sWt;
    __shared__ float tile[32][33];
    int tx = threadIdx.x & 31, ty = threadIdx.x >> 5;
    int n0 = blockIdx.x * 32, k0 = blockIdx.y * 32;
#pragma unroll
    for (int u = 0; u < 4; u++) tile[ty + u * 8][tx] = Wm[(long)(k0 + ty + u * 8) * N + n0 + tx];
    __syncthreads();
#pragma unroll
    for (int u = 0; u < 4; u++) Wt[(long)(n0 + ty + u * 8) * K + k0 + tx] = f2bf(tile[tx][ty + u * 8]);
}

__global__ __launch_bounds__(256)
void k_cvt(const float4* __restrict__ src, ushort4* __restrict__ dst, long n4)
{
    long i = (long)blockIdx.x * 256 + threadIdx.x;
    if (i < n4) {
        float4 v = src[i];
        ushort4 o;
        o.x = f2bf(v.x); o.y = f2bf(v.y); o.z = f2bf(v.z); o.w = f2bf(v.w);
        dst[i] = o;
    }
}

__global__ __launch_bounds__(256)
void k_b2f(const ushort4* __restrict__ src, float4* __restrict__ dst, long n4)
{
    long i = (long)blockIdx.x * 256 + threadIdx.x;
    if (i < n4) {
        ushort4 v = src[i];
        dst[i] = make_float4(bf2f(v.x), bf2f(v.y), bf2f(v.z), bf2f(v.w));
    }
}

// ---------------- landmarks: ql f32 + bf16, klT f32 [h][d][i], klb bf16 [h][i][d]; zero scal
__global__ __launch_bounds__(64)
void k_landmarks(const ushort* __restrict__ q, const ushort* __restrict__ k,
                 float* __restrict__ ql, ushort* __restrict__ qlb,
                 float* __restrict__ klT, ushort* __restrict__ klb,
                 unsigned* __restrict__ scal)
{
    int i = blockIdx.x, h = blockIdx.y, d = threadIdx.x;
    if (i == 0 && h == 0 && d == 0) { scal[0] = 0u; scal[1] = 0u; }
    long base = ((long)h * NPQ + (long)i * 60) * 64 + d;
    float sq = 0.f, sk = 0.f;
    for (int j = 0; j < 60; j++) { sq += bf2f(q[base + j * 64]); sk += bf2f(k[base + j * 64]); }
    float qv = sq / 60.f, kv = sk / 60.f;
    ql[((long)h * 256 + i) * 64 + d] = qv;
    qlb[((long)h * 256 + i) * 64 + d] = f2bf(qv);
    klT[((long)h * 64 + d) * 256 + i] = kv;
    klb[((long)h * 256 + i) * 64 + d] = f2bf(kv);
}

// ---------------- in-place fp32 row softmax (row length 256) + bf16 copy
__global__ __launch_bounds__(256)
void k_softmax256(float* __restrict__ X, ushort* __restrict__ X16, long headStride)
{
    float* row = X + (long)blockIdx.y * headStride + (long)blockIdx.x * 256;
    int t = threadIdx.x, wid = t >> 6, lane = t & 63;
    float x = row[t];
    __shared__ float rm[4], rsum[4], fin[2];
    float m = x;
#pragma unroll
    for (int o = 32; o > 0; o >>= 1) m = fmaxf(m, __shfl_down(m, o));
    if (lane == 0) rm[wid] = m;
    __syncthreads();
    if (t == 0) fin[0] = fmaxf(fmaxf(rm[0], rm[1]), fmaxf(rm[2], rm[3]));
    __syncthreads();
    float e = __expf(x - fin[0]);
    float s = e;
#pragma unroll
    for (int o = 32; o > 0; o >>= 1) s += __shfl_down(s, o);
    if (lane == 0) rsum[wid] = s;
    __syncthreads();
    if (t == 0) fin[1] = rsum[0] + rsum[1] + rsum[2] + rsum[3];
    __syncthreads();
    float v = e / fin[1];
    row[t] = v;
    if (X16) X16[(long)blockIdx.y * headStride + (long)blockIdx.x * 256 + t] = f2bf(v);
}

__global__ __launch_bounds__(256)
void k_softmax256b(const float* __restrict__ X, ushort* __restrict__ O, long hsX, long hsO)
{
    const float* row = X + (long)blockIdx.y * hsX + (long)blockIdx.x * 256;
    ushort* orow = O + (long)blockIdx.y * hsO + (long)blockIdx.x * 256;
    int t = threadIdx.x, wid = t >> 6, lane = t & 63;
    float x = row[t];
    __shared__ float rm[4], rsum[4], fin[2];
    float m = x;
#pragma unroll
    for (int o = 32; o > 0; o >>= 1) m = fmaxf(m, __shfl_down(m, o));
    if (lane == 0) rm[wid] = m;
    __syncthreads();
    if (t == 0) fin[0] = fmaxf(fmaxf(rm[0], rm[1]), fmaxf(rm[2], rm[3]));
    __syncthreads();
    float e = __expf(x - fin[0]);
    float s = e;
#pragma unroll
    for (int o = 32; o > 0; o >>= 1) s += __shfl_down(s, o);
    if (lane == 0) rsum[wid] = s;
    __syncthreads();
    if (t == 0) fin[1] = rsum[0] + rsum[1] + rsum[2] + rsum[3];
    __syncthreads();
    orow[t] = f2bf(e / fin[1]);
}

__global__ __launch_bounds__(256)
void k_colmax(const float* __restrict__ a2, unsigned* __restrict__ scal)
{
    int h = blockIdx.x, t = threadIdx.x, wid = t >> 6, lane = t & 63;
    const float* A = a2 + (long)h * 65536;
    float cs = 0.f, rs = 0.f;
    for (int i = 0; i < 256; i++) cs += A[(long)i * 256 + t];
    for (int j = 0; j < 256; j++) rs += A[(long)t * 256 + j];
    __shared__ float r1[4], r2[4];
    float m1v = cs, m2v = rs;
#pragma unroll
    for (int o = 32; o > 0; o >>= 1) {
        m1v = fmaxf(m1v, __shfl_down(m1v, o));
        m2v = fmaxf(m2v, __shfl_down(m2v, o));
    }
    if (lane == 0) { r1[wid] = m1v; r2[wid] = m2v; }
    __syncthreads();
    if (t == 0) {
        float a = fmaxf(fmaxf(r1[0], r1[1]), fmaxf(r1[2], r1[3]));
        float b = fmaxf(fmaxf(r2[0], r2[1]), fmaxf(r2[2], r2[3]));
        atomicMax(scal + 0, __float_as_uint(a));
        atomicMax(scal + 1, __float_as_uint(b));
    }
}

// ---------------- z0 = a2^T / (scal0*scal1), bf16 out
__global__ __launch_bounds__(256)
void k_zinit(const float* __restrict__ a2, ushort* __restrict__ zb, const unsigned* __restrict__ scal)
{
    float s = 1.f / (__uint_as_float(scal[0]) * __uint_as_float(scal[1]));
    const float* A = a2 + (long)blockIdx.z * 65536;
    ushort* Z = zb + (long)blockIdx.z * 65536;
    __shared__ float tile[32][33];
    int tx = threadIdx.x & 31, ty = threadIdx.x >> 5;
    int i0 = blockIdx.x * 32, j0 = blockIdx.y * 32;
#pragma unroll
    for (int u = 0; u < 4; u++) tile[ty + u * 8][tx] = A[(long)(j0 + ty + u * 8) * 256 + i0 + tx];
    __syncthreads();
#pragma unroll
    for (int u = 0; u < 4; u++) Z[(long)(i0 + ty + u * 8) * 256 + j0 + tx] = f2bf(tile[tx][ty + u * 8] * s);
}

__global__ __launch_bounds__(256)
void k_a3v_merge(const float* __restrict__ pacc, const float* __restrict__ pml,
                 float* __restrict__ t1)
{
    int d = blockIdx.x, h = blockIdx.y, i = threadIdx.x;
    float M = -INFINITY, L = 0.f, num = 0.f;
    for (int c = 0; c < 60; c++) {
        float mc = pml[(long)(h * 60 + c) * 2 * 256 + i];
        float lc = pml[((long)(h * 60 + c) * 2 + 1) * 256 + i];
        float ac = pacc[((long)(h * 60 + c) * 64 + d) * 256 + i];
        if (mc > M) {
            float f = __expf(M - mc);
            num = num * f + ac; L = L * f + lc; M = mc;
        } else {
            float p = __expf(mc - M);
            num = fmaf(p, ac, num); L = fmaf(p, lc, L);
        }
    }
    t1[((long)h * 256 + i) * 64 + d] = num / L;
}

__global__ __launch_bounds__(256)
void k_resconv(float* __restrict__ oh, const ushort* __restrict__ v,
               const float* __restrict__ rw, int Mrows)
{
    int h = blockIdx.y;
    int d = threadIdx.x & 63, r = threadIdx.x >> 6;
    int tk = blockIdx.x * 4 + r;
    if (tk >= Mrows) return;
    const ushort* vb = v + (long)h * NPQ * 64 + d;
    float acc = 0.f;
    int center = 230 + tk;
#pragma unroll
    for (int kk = 0; kk < 33; kk++) {
        int src = center + kk - 16;
        if (src >= 0 && src < NP) acc = fmaf(rw[h * 33 + kk], bf2f(vb[(long)src * 64]), acc);
    }
    oh[(long)tk * 512 + h * 64 + d] += acc;
}

__global__ __launch_bounds__(256)
void k_cls(const ushort* __restrict__ qb, const float* __restrict__ klT,
           const float* __restrict__ Bm, const ushort* __restrict__ vb,
           const float* __restrict__ rw, float* __restrict__ oh)
{
    int h = blockIdx.x, t = threadIdx.x, wid = t >> 6, lane = t & 63;
    __shared__ float qs[64], p[256], red[256];
    __shared__ float rm[4], rsum[4], fin[2];
    if (t < 64) qs[t] = bf2f(qb[((long)h * NPQ + 230) * 64 + t]);
    __syncthreads();
    float s = 0.f;
    for (int d = 0; d < 64; d++) s = fmaf(qs[d], klT[((long)h * 64 + d) * 256 + t], s);
    float m = s;
#pragma unroll
    for (int o = 32; o > 0; o >>= 1) m = fmaxf(m, __shfl_down(m, o));
    if (lane == 0) rm[wid] = m;
    __syncthreads();
    if (t == 0) fin[0] = fmaxf(fmaxf(rm[0], rm[1]), fmaxf(rm[2], rm[3]));
    __syncthreads();
    float e = __expf(s - fin[0]);
    float ss = e;
#pragma unroll
    for (int o = 32; o > 0; o >>= 1) ss += __shfl_down(ss, o);
    if (lane == 0) rsum[wid] = ss;
    __syncthreads();
    if (t == 0) fin[1] = rsum[0] + rsum[1] + rsum[2] + rsum[3];
    __syncthreads();
    p[t] = e / fin[1];
    __syncthreads();
    int d = t & 63, grp = t >> 6;
    float o = 0.f;
    for (int j = grp * 64; j < grp * 64 + 64; j++) o = fmaf(p[j], Bm[((long)h * 256 + j) * 64 + d], o);
    red[t] = o;
    __syncthreads();
    if (t < 64) {
        float val = red[t] + red[t + 64] + red[t + 128] + red[t + 192];
#pragma unroll
        for (int kk = 0; kk < 33; kk++)
            val = fmaf(rw[h * 33 + kk], bf2f(vb[((long)h * NPQ + 214 + kk) * 64 + t]), val);
        oh[h * 64 + t] = val;
    }
}

__global__ __launch_bounds__(256)
void k_copy4(const float4* __restrict__ src, float4* __restrict__ dst, long n4)
{
    long i = (long)blockIdx.x * 256 + threadIdx.x;
    if (i < n4) dst[i] = src[i];
}

__global__ __launch_bounds__(256)
void k_ppeg(const float* __restrict__ cnn, float* __restrict__ hbuf,
            const float* __restrict__ w7, const float* __restrict__ b7,
            const float* __restrict__ w5, const float* __restrict__ b5,
            const float* __restrict__ w3, const float* __restrict__ b3)
{
    __shared__ float tile[14 * 14 * 64];
    int lc = threadIdx.x & 63, sp0 = threadIdx.x >> 6;
    int c0 = blockIdx.x * 8, r0 = blockIdx.y * 8, cb = blockIdx.z * 64;
    for (int p = sp0; p < 196; p += 4) {
        int pr = p / 14, pc = p % 14;
        int gr = r0 + pr - 3, gc = c0 + pc - 3;
        float val = 0.f;
        if (gr >= 0 && gr < HG && gc >= 0 && gc < HG)
            val = cnn[(long)(gr * HG + gc) * 512 + cb + lc];
        tile[p * 64 + lc] = val;
    }
    __syncthreads();
    int c = cb + lc;
    float bb = b7[c] + b5[c] + b3[c];
    float acc[16];
    int bidx[16];
#pragma unroll
    for (int u = 0; u < 16; u++) {
        int sp = sp0 + 4 * u;
        int orr = sp >> 3, occ = sp & 7;
        bidx[u] = (orr * 14 + occ) * 64 + lc;
        acc[u] = bb + tile[((orr + 3) * 14 + (occ + 3)) * 64 + lc];
    }
    for (int kr = 0; kr < 7; kr++)
        for (int kc = 0; kc < 7; kc++) {
            float w = w7[c * 49 + kr * 7 + kc];
            int koff = (kr * 14 + kc) * 64;
#pragma unroll
            for (int u = 0; u < 16; u++) acc[u] = fmaf(w, tile[bidx[u] + koff], acc[u]);
        }
    for (int kr = 0; kr < 5; kr++)
        for (int kc = 0; kc < 5; kc++) {
            float w = w5[c * 25 + kr * 5 + kc];
            int koff = ((kr + 1) * 14 + kc + 1) * 64;
#pragma unroll
            for (int u = 0; u < 16; u++) acc[u] = fmaf(w, tile[bidx[u] + koff], acc[u]);
        }
    for (int kr = 0; kr < 3; kr++)
        for (int kc = 0; kc < 3; kc++) {
            float w = w3[c * 9 + kr * 3 + kc];
            int koff = ((kr + 2) * 14 + kc + 2) * 64;
#pragma unroll
            for (int u = 0; u < 16; u++) acc[u] = fmaf(w, tile[bidx[u] + koff], acc[u]);
        }
#pragma unroll
    for (int u = 0; u < 16; u++) {
        int sp = sp0 + 4 * u;
        int orr = sp >> 3, occ = sp & 7;
        int gr = r0 + orr, gc = c0 + occ;
        if (gr < HG && gc < HG)
            hbuf[(long)(1 + gr * HG + gc) * 512 + c] = acc[u];
    }
}

__global__ __launch_bounds__(256)
void k_final(const float* __restrict__ hbuf, const float* __restrict__ g,
             const float* __restrict__ b, const float* __restrict__ W2,
             const float* __restrict__ b2, float* __restrict__ out)
{
    __shared__ float y[512];
    __shared__ float rs[4], rq[4], st[2], lg[8];
    int t = threadIdx.x, wid = t >> 6, lane = t & 63;
    float x1 = hbuf[t], x2 = hbuf[t + 256];
    float s = x1 + x2, q = x1 * x1 + x2 * x2;
#pragma unroll
    for (int o = 32; o > 0; o >>= 1) { s += __shfl_down(s, o); q += __shfl_down(q, o); }
    if (lane == 0) { rs[wid] = s; rq[wid] = q; }
    __syncthreads();
    if (t == 0) {
        float S = rs[0] + rs[1] + rs[2] + rs[3];
        float Q = rq[0] + rq[1] + rq[2] + rq[3];
        float mean = S / 512.f;
        float var = Q / 512.f - mean * mean;
        st[0] = mean; st[1] = rsqrtf(var + 1e-5f);
    }
    __syncthreads();
    float mean = st[0], rstd = st[1];
    y[t] = (x1 - mean) * rstd * g[t] + b[t];
    y[t + 256] = (x2 - mean) * rstd * g[t + 256] + b[t + 256];
    __syncthreads();
    if (t < 5) {
        float acc = b2[t];
        for (int kx = 0; kx < 512; kx++) acc = fmaf(y[kx], W2[kx * 5 + t], acc);
        lg[t] = acc;
    }
    __syncthreads();
    if (t == 0) {
        float mx = lg[0]; int am = 0;
        for (int j = 1; j < 5; j++) if (lg[j] > mx) { mx = lg[j]; am = j; }
        float e[5], se = 0.f;
        for (int j = 0; j < 5; j++) { e[j] = __expf(lg[j] - mx); se += e[j]; }
        for (int j = 0; j < 5; j++) { out[j] = lg[j]; out[5 + j] = e[j] / se; }
        out[10] = (float)am;
    }
}

extern "C" void kernel_launch(void* const* d_in, const int* in_sizes, int n_in,
                              void* d_out, int out_size, void* d_ws, size_t ws_size,
                              hipStream_t stream)
{
    const float* data  = (const float*)d_in[0];
    const float* Wfc1  = (const float*)d_in[1];
    const float* bfc1  = (const float*)d_in[2];
    const float* cls   = (const float*)d_in[3];
    const float* ln1g  = (const float*)d_in[4];
    const float* ln1b  = (const float*)d_in[5];
    const float* qkv1  = (const float*)d_in[6];
    const float* out1w = (const float*)d_in[7];
    const float* out1b = (const float*)d_in[8];
    const float* res1  = (const float*)d_in[9];
    const float* w7    = (const float*)d_in[10];
    const float* b7    = (const float*)d_in[11];
    const float* w5    = (const float*)d_in[12];
    const float* b5    = (const float*)d_in[13];
    const float* w3    = (const float*)d_in[14];
    const float* b3    = (const float*)d_in[15];
    const float* ln2g  = (const float*)d_in[16];
    const float* ln2b  = (const float*)d_in[17];
    const float* qkv2  = (const float*)d_in[18];
    const float* out2w = (const float*)d_in[19];
    const float* out2b = (const float*)d_in[20];
    const float* res2  = (const float*)d_in[21];
    const float* normg = (const float*)d_in[22];
    const float* normb = (const float*)d_in[23];
    const float* Wfc2  = (const float*)d_in[24];
    const float* bfc2  = (const float*)d_in[25];
    float* out = (float*)d_out;

    float* W = (float*)d_ws;
    size_t off = 0;
    auto alloc = [&](size_t n) { size_t o = off; off += (n + 255) & ~(size_t)255; return o; };
    float*  hbuf   = W + alloc((size_t)NTOK * 512);
    float*  ohreg  = W + alloc((size_t)15232 * 512);
    float*  oh     = ohreg;
    ushort* xln    = (ushort*)ohreg;
    ushort* qb16   = (ushort*)(W + alloc((size_t)8 * NPQ * 32));
    ushort* kb16   = (ushort*)(W + alloc((size_t)8 * NPQ * 32));
    ushort* vb16   = (ushort*)(W + alloc((size_t)8 * NPQ * 32));
    float*  ql     = W + alloc(8 * 256 * 64);
    ushort* qlb    = (ushort*)(W + alloc(8 * 256 * 32));
    float*  klT    = W + alloc(8 * 64 * 256);
    ushort* klb    = (ushort*)(W + alloc(8 * 256 * 32));
    float*  a2     = W + alloc(8 * 65536);
    ushort* a2b    = (ushort*)(W + alloc(8 * 32768));
    ushort* zb0    = (ushort*)(W + alloc(8 * 32768));
    ushort* zb1    = (ushort*)(W + alloc(8 * 32768));
    ushort* m1b    = (ushort*)(W + alloc(8 * 32768));
    ushort* mab    = (ushort*)(W + alloc(8 * 32768));
    ushort* mbb    = (ushort*)(W + alloc(8 * 32768));
    float*  z0     = W + alloc(8 * 65536);
    float*  z1     = W + alloc(8 * 65536);
    float*  m1     = W + alloc(8 * 65536);
    float*  ma     = W + alloc(8 * 65536);
    float*  mb     = W + alloc(8 * 65536);
    float*  t1     = W + alloc(8 * 256 * 64);
    float*  Bm     = W + alloc(8 * 256 * 64);
    ushort* BmT16  = (ushort*)(W + alloc(8 * 64 * 128));
    float*  scal   = W + alloc(64);
    ushort* simb16 = (ushort*)(W + alloc((size_t)3840 * 128 * 8));
    ushort* ohb16  = (ushort*)(W + alloc((size_t)15232 * 256));
    ushort* WfcT   = (ushort*)(W + alloc(1024 * 256));
    ushort* qkv1T  = (ushort*)(W + alloc(1536 * 256));
    ushort* qkv2T  = (ushort*)(W + alloc(1536 * 256));
    ushort* out1T  = (ushort*)(W + alloc(512 * 256));
    ushort* out2T  = (ushort*)(W + alloc(512 * 256));
    float*  big    = W + alloc(8110080);   // datab | pacc+pml | sim1 slabs | ppeg cnn
    ushort* datab  = (ushort*)big;
    float*  pacc   = big;
    float*  pml    = big + 7864320;
    float*  simbuf = big;
    float*  cnn    = big;
    if (ws_size < off * sizeof(float)) return;

    k_wT<<<dim3(16, 32, 1), 256, 0, stream>>>(Wfc1, WfcT, 1024, 512, 0, 0);
    k_wT<<<dim3(48, 16, 1), 256, 0, stream>>>(qkv1, qkv1T, 512, 1536, 0, 0);
    k_wT<<<dim3(48, 16, 1), 256, 0, stream>>>(qkv2, qkv2T, 512, 1536, 0, 0);
    k_wT<<<dim3(16, 16, 1), 256, 0, stream>>>(out1w, out1T, 512, 512, 0, 0);
    k_wT<<<dim3(16, 16, 1), 256, 0, stream>>>(out2w, out2T, 512, 512, 0, 0);
    k_cvt<<<15000, 256, 0, stream>>>((const float4*)data, (ushort4*)datab, 3840000);
    gemm_mfma<4, 4, 2, 2><<<dim3(4, 118, 1), 256, 0, stream>>>(
        datab, 1024, 0, WfcT, 1024, 0, hbuf + 512, 512, 0, 15000, 1024, bfc1, 1, 0);
    k_padcls<<<130, 256, 0, stream>>>(hbuf, cls);

    auto layer = [&](const float* lng, const float* lnb, const ushort* qkvT,
                     const float* outW, const ushort* outT, const float* outB,
                     const float* resW, bool full) {
        k_layernorm<<<NP, 256, 0, stream>>>(hbuf, xln, lng, lnb, 230);
        gemm_qkv_mfma<<<dim3(12, 120, 1), 256, 0, stream>>>(xln, qkvT, qb16, kb16, vb16);
        k_landmarks<<<dim3(256, 8), 64, 0, stream>>>(qb16, kb16, ql, qlb, klT, klb, (unsigned*)scal);
        gemm_f32<<<dim3(4, 4, 8), 256, 0, stream>>>(ql, 64, 16384, klT, 256, 16384,
            a2, 256, 65536, 256, 256, 64, nullptr, nullptr, 0, 0, 0.f, 1.f, 0, 0);
        k_softmax256<<<dim3(256, 8), 256, 0, stream>>>(a2, a2b, 65536);
        k_colmax<<<8, 256, 0, stream>>>(a2, (unsigned*)scal);
        k_zinit<<<dim3(8, 8, 8), 256, 0, stream>>>(a2, zb0, (const unsigned*)scal);
        // pinv iters 0-3 in bf16 MFMA
        ushort* zbi = zb0; ushort* zbo = zb1;
        for (int it = 0; it < 4; ++it) {
            gemm_nn16<<<dim3(4, 4, 8), 256, 0, stream>>>(a2b, zbi, nullptr, m1b, 256, 256, 1.f, 0.f, 65536);
            gemm_nn16<<<dim3(4, 4, 8), 256, 0, stream>>>(m1b, m1b, m1b, mab, 256, 256, -1.f, 7.f, 65536);
            gemm_nn16<<<dim3(4, 4, 8), 256, 0, stream>>>(m1b, mab, m1b, mbb, 256, 256, -1.f, 15.f, 65536);
            gemm_nn16<<<dim3(4, 4, 8), 256, 0, stream>>>(zbi, mbb, zbi, zbo, 256, 256, -0.25f, 3.25f, 65536);
            ushort* tmp = zbi; zbi = zbo; zbo = tmp;
        }
        k_b2f<<<512, 256, 0, stream>>>((const ushort4*)zbi, (float4*)z0, 131072);
        // pinv iters 4-5 in fp32
        float* zi = z0; float* zo = z1;
        for (int it = 0; it < 2; ++it) {
            gemm_f32<<<dim3(4, 4, 8), 256, 0, stream>>>(a2, 256, 65536, zi, 256, 65536,
                m1, 256, 65536, 256, 256, 256, nullptr, nullptr, 0, 0, 0.f, 1.f, 0, 0);
            gemm_f32<<<dim3(4, 4, 8), 256, 0, stream>>>(m1, 256, 65536, m1, 256, 65536,
                ma, 256, 65536, 256, 256, 256, nullptr, m1, 256, 65536, 7.f, -1.f, 0, 0);
            gemm_f32<<<dim3(4, 4, 8), 256, 0, stream>>>(m1, 256, 65536, ma, 256, 65536,
                mb, 256, 65536, 256, 256, 256, nullptr, m1, 256, 65536, 15.f, -1.f, 0, 0);
            gemm_f32<<<dim3(4, 4, 8), 256, 0, stream>>>(zi, 256, 65536, mb, 256, 65536,
                zo, 256, 65536, 256, 256, 256, nullptr, zi, 256, 65536, 3.25f, -0.25f, 0, 0);
            float* tmp = zi; zi = zo; zo = tmp;
        }
        k_flash_a3v<<<dim3(60, 2, 8), 256, 0, stream>>>(qlb, kb16, vb16, pacc, pml);
        k_a3v_merge<<<dim3(64, 8), 256, 0, stream>>>(pacc, pml, t1);
        gemm_f32<<<dim3(1, 4, 8), 256, 0, stream>>>(zi, 256, 65536, t1, 64, 16384,
            Bm, 64, 16384, 256, 64, 256, nullptr, nullptr, 0, 0, 0.f, 1.f, 0, 0);
        if (full) {
            k_wT<<<dim3(2, 8, 8), 256, 0, stream>>>(Bm, BmT16, 256, 64, 16384, 16384);
            for (int s0 = 0; s0 < NTOK; s0 += 3840) {
                int ms = NTOK - s0 < 3840 ? NTOK - s0 : 3840;
                int gy = (ms + 127) / 128;
                gemm_mfma<4, 4, 2, 2><<<dim3(2, gy, 8), 256, 0, stream>>>(
                    qb16 + (long)(230 + s0) * 64, 64, (long)NPQ * 64,
                    klb, 64, 16384,
                    simbuf, 256, (long)3840 * 256, ms, 64, nullptr, 0, 0);
                k_softmax256b<<<dim3(ms, 8), 256, 0, stream>>>(simbuf, simb16,
                    (long)3840 * 256, (long)3840 * 256);
                gemm_mfma<2, 4, 4, 1><<<dim3(1, gy, 8), 256, 0, stream>>>(
                    simb16, 256, (long)3840 * 256,
                    BmT16, 256, 16384,
                    oh + (long)s0 * 512, 512, 64, ms, 256, nullptr, 0, 0);
            }
            k_resconv<<<dim3((NTOK + 3) / 4, 8), 256, 0, stream>>>(oh, vb16, resW, NTOK);
            k_cvt<<<7565, 256, 0, stream>>>((const float4*)oh, (ushort4*)ohb16, 1936640);
            gemm_mfma<4, 4, 2, 2><<<dim3(4, 119, 1), 256, 0, stream>>>(
                ohb16, 512, 0, outT, 512, 0, hbuf, 512, 0, NTOK, 512, outB, 0, 1);
        } else {
            k_cls<<<8, 256, 0, stream>>>(qb16, klT, Bm, vb16, resW, oh);
            gemm_f32<<<dim3(8, 1, 1), 256, 0, stream>>>(oh, 512, 0, outW, 512, 0,
                hbuf, 512, 0, 1, 512, 512, outB, nullptr, 0, 0, 0.f, 1.f, 0, 1);
        }
    };

    layer(ln1g, ln1b, qkv1T, out1w, out1T, out1b, res1, true);
    k_copy4<<<(1936512 + 255) / 256, 256, 0, stream>>>((const float4*)(hbuf + 512), (float4*)cnn, 1936512);
    k_ppeg<<<dim3(16, 16, 8), 256, 0, stream>>>(cnn, hbuf, w7, b7, w5, b5, w3, b3);
    layer(ln2g, ln2b, qkv2T, out2w, out2T, out2b, res2, false);
    k_final<<<1, 256, 0, stream>>>(hbuf, normg, normb, Wfc2, bfc2, out);
}

// Round 4
// 1587.107 us; speedup vs baseline: 2.1354x; 1.1949x over previous
//
#include <hip/hip_runtime.h>
#include <math.h>

#define NP 15360
#define NPQ 15488
#define NTOK 15130
#define HG 123

typedef __attribute__((ext_vector_type(8))) short s8b;
typedef __attribute__((ext_vector_type(4))) float f4;

__device__ inline float bf2f(ushort u) { return __uint_as_float(((unsigned)u) << 16); }
__device__ inline ushort f2bf(float f) {
    unsigned u = __float_as_uint(f);
    unsigned r = (u + 0x7fffu + ((u >> 16) & 1u)) >> 16;
    return (ushort)r;
}

// ---------------- generic fp32 GEMM (small/sensitive ops): C = cS*(A@B) + eS*E + bias
__global__ __launch_bounds__(256)
void gemm_f32(const float* __restrict__ A, int lda, long sA,
              const float* __restrict__ B, int ldb, long sB,
              float* __restrict__ C, int ldc, long sC,
              int M, int N, int K,
              const float* __restrict__ bias,
              const float* __restrict__ E, int ldE, long sE, float eS,
              float cS, int relu, int accum)
{
    A += (long)blockIdx.z * sA;
    B += (long)blockIdx.z * sB;
    C += (long)blockIdx.z * sC;
    if (E) E += (long)blockIdx.z * sE;
    const int m0 = blockIdx.y * 64, n0 = blockIdx.x * 64;
    const int t = threadIdx.x;
    const int tx = t & 15, ty = t >> 4;
    __shared__ float As[16][64];
    __shared__ float Bs[16][64];
    float acc[4][4] = {};
    const int arow = t >> 2, akc = (t & 3) * 4;
    const int brow = t >> 4, bnc = (t & 15) * 4;
    for (int k0 = 0; k0 < K; k0 += 16) {
        float4 av = make_float4(0.f, 0.f, 0.f, 0.f);
        if (m0 + arow < M) av = *(const float4*)(A + (long)(m0 + arow) * lda + k0 + akc);
        As[akc + 0][arow] = av.x; As[akc + 1][arow] = av.y;
        As[akc + 2][arow] = av.z; As[akc + 3][arow] = av.w;
        float4 bv = *(const float4*)(B + (long)(k0 + brow) * ldb + n0 + bnc);
        *(float4*)&Bs[brow][bnc] = bv;
        __syncthreads();
#pragma unroll
        for (int kk = 0; kk < 16; ++kk) {
            float4 a4 = *(const float4*)&As[kk][ty * 4];
            float4 b4 = *(const float4*)&Bs[kk][tx * 4];
            float a[4] = {a4.x, a4.y, a4.z, a4.w};
            float b[4] = {b4.x, b4.y, b4.z, b4.w};
#pragma unroll
            for (int i = 0; i < 4; i++)
#pragma unroll
                for (int j = 0; j < 4; j++) acc[i][j] = fmaf(a[i], b[j], acc[i][j]);
        }
        __syncthreads();
    }
#pragma unroll
    for (int i = 0; i < 4; i++) {
        int m = m0 + ty * 4 + i;
        if (m < M) {
#pragma unroll
            for (int j = 0; j < 4; j++) {
                int n = n0 + tx * 4 + j;
                float v = cS * acc[i][j];
                if (E) v = fmaf(eS, E[(long)m * ldE + n], v);
                if (bias) v += bias[n];
                if (relu) v = fmaxf(v, 0.f);
                if (accum) C[(long)m * ldc + n] += v;
                else C[(long)m * ldc + n] = v;
            }
        }
    }
}

// ---------------- bf16 MFMA GEMM: C(fp32) = A(bf16,[M][K]) @ Bt(bf16,[N][K])^T
template<int MT, int NT, int WROWS, int WCOLS>
__global__ __launch_bounds__(256)
void gemm_mfma(const ushort* __restrict__ A, int lda, long sA,
               const ushort* __restrict__ Bt, int ldb, long sB,
               float* __restrict__ C, int ldc, long sC,
               int M, int K,
               const float* __restrict__ bias, int relu, int accum)
{
    constexpr int TM = MT * 16 * WROWS;
    constexpr int TN = NT * 16 * WCOLS;
    constexpr int BKP = 40;
    __shared__ ushort As[TM * BKP];
    __shared__ ushort Bs[TN * BKP];
    A  += (long)blockIdx.z * sA;
    Bt += (long)blockIdx.z * sB;
    C  += (long)blockIdx.z * sC;
    const int t = threadIdx.x;
    const int m0 = blockIdx.y * TM, n0 = blockIdx.x * TN;
    const int w = t >> 6, l = t & 63;
    const int wm = (w / WCOLS) * (MT * 16), wn = (w % WCOLS) * (NT * 16);
    const int lr = l & 15;
    const int lk = (l >> 4) * 8;
    f4 acc[MT][NT] = {};
    for (int k0 = 0; k0 < K; k0 += 32) {
        for (int c = t; c < TM * 4; c += 256) {
            int row = c >> 2, kc = (c & 3) * 8;
            s8b v = *(const s8b*)(A + (long)(m0 + row) * lda + k0 + kc);
            *(s8b*)(&As[row * BKP + kc]) = v;
        }
        for (int c = t; c < TN * 4; c += 256) {
            int row = c >> 2, kc = (c & 3) * 8;
            s8b v = *(const s8b*)(Bt + (long)(n0 + row) * ldb + k0 + kc);
            *(s8b*)(&Bs[row * BKP + kc]) = v;
        }
        __syncthreads();
        s8b af[MT], bf[NT];
#pragma unroll
        for (int i = 0; i < MT; i++) af[i] = *(const s8b*)(&As[(wm + i * 16 + lr) * BKP + lk]);
#pragma unroll
        for (int j = 0; j < NT; j++) bf[j] = *(const s8b*)(&Bs[(wn + j * 16 + lr) * BKP + lk]);
#pragma unroll
        for (int i = 0; i < MT; i++)
#pragma unroll
            for (int j = 0; j < NT; j++)
                acc[i][j] = __builtin_amdgcn_mfma_f32_16x16x32_bf16(af[i], bf[j], acc[i][j], 0, 0, 0);
        __syncthreads();
    }
    const int orow = (l >> 4) * 4;
#pragma unroll
    for (int i = 0; i < MT; i++) {
#pragma unroll
        for (int r = 0; r < 4; r++) {
            int m = m0 + wm + i * 16 + orow + r;
            if (m < M) {
#pragma unroll
                for (int j = 0; j < NT; j++) {
                    int n = n0 + wn + j * 16 + lr;
                    float vv = acc[i][j][r];
                    if (bias) vv += bias[n];
                    if (relu) vv = fmaxf(vv, 0.f);
                    if (accum) C[(long)m * ldc + n] += vv;
                    else C[(long)m * ldc + n] = vv;
                }
            }
        }
    }
}

// ---------------- bf16-in/bf16-out MFMA GEMM, B row-major [K][N]: C16 = bf16(cS*(A@B) + eS*E16)
__global__ __launch_bounds__(256)
void gemm_nn16(const ushort* __restrict__ A, const ushort* __restrict__ B,
               const ushort* __restrict__ E, ushort* __restrict__ C,
               int N, int K, float cS, float eS, long sAB)
{
    __shared__ ushort As[64 * 40];
    __shared__ ushort Bs[64 * 40];
    A += (long)blockIdx.z * sAB;
    B += (long)blockIdx.z * sAB;
    if (E) E += (long)blockIdx.z * sAB;
    C += (long)blockIdx.z * sAB;
    const int t = threadIdx.x;
    const int m0 = blockIdx.y * 64, n0 = blockIdx.x * 64;
    const int w = t >> 6, l = t & 63;
    const int wm = (w >> 1) * 32, wn = (w & 1) * 32;
    const int lr = l & 15, lk = (l >> 4) * 8;
    f4 acc[2][2] = {};
    for (int k0 = 0; k0 < K; k0 += 32) {
        {
            int row = t >> 2, kc = (t & 3) * 8;
            s8b v = *(const s8b*)(A + (long)(m0 + row) * K + k0 + kc);
            *(s8b*)(&As[row * 40 + kc]) = v;
            int kk = t >> 3, nc = (t & 7) * 8;
            s8b vb = *(const s8b*)(B + (long)(k0 + kk) * N + n0 + nc);
#pragma unroll
            for (int j = 0; j < 8; j++) Bs[(nc + j) * 40 + kk] = ((ushort*)&vb)[j];
        }
        __syncthreads();
        s8b af[2], bf[2];
#pragma unroll
        for (int i = 0; i < 2; i++) af[i] = *(const s8b*)(&As[(wm + i * 16 + lr) * 40 + lk]);
#pragma unroll
        for (int j = 0; j < 2; j++) bf[j] = *(const s8b*)(&Bs[(wn + j * 16 + lr) * 40 + lk]);
#pragma unroll
        for (int i = 0; i < 2; i++)
#pragma unroll
            for (int j = 0; j < 2; j++)
                acc[i][j] = __builtin_amdgcn_mfma_f32_16x16x32_bf16(af[i], bf[j], acc[i][j], 0, 0, 0);
        __syncthreads();
    }
    const int orow = (l >> 4) * 4;
#pragma unroll
    for (int i = 0; i < 2; i++)
#pragma unroll
        for (int r = 0; r < 4; r++) {
            int m = m0 + wm + i * 16 + orow + r;
#pragma unroll
            for (int j = 0; j < 2; j++) {
                int n = n0 + wn + j * 16 + lr;
                float vv = cS * acc[i][j][r];
                if (E) vv = fmaf(eS, bf2f(E[(long)m * N + n]), vv);
                C[(long)m * N + n] = f2bf(vv);
            }
        }
}

// ---------------- qkv MFMA GEMM, scatter into bf16 q/k/v [head][NPQ][64], q scaled 1/8
__global__ __launch_bounds__(256)
void gemm_qkv_mfma(const ushort* __restrict__ A, const ushort* __restrict__ Bt,
                   ushort* __restrict__ qo, ushort* __restrict__ ko, ushort* __restrict__ vo)
{
    constexpr int BKP = 40;
    __shared__ ushort As[128 * BKP];
    __shared__ ushort Bs[128 * BKP];
    const int t = threadIdx.x;
    const int m0 = blockIdx.y * 128, n0 = blockIdx.x * 128;
    const int w = t >> 6, l = t & 63;
    const int wm = (w >> 1) * 64, wn = (w & 1) * 64;
    const int lr = l & 15;
    const int lk = (l >> 4) * 8;
    f4 acc[4][4] = {};
    for (int k0 = 0; k0 < 512; k0 += 32) {
        for (int c = t; c < 512; c += 256) {
            int row = c >> 2, kc = (c & 3) * 8;
            s8b va = *(const s8b*)(A + (long)(m0 + row) * 512 + k0 + kc);
            *(s8b*)(&As[row * BKP + kc]) = va;
            s8b vb = *(const s8b*)(Bt + (long)(n0 + row) * 512 + k0 + kc);
            *(s8b*)(&Bs[row * BKP + kc]) = vb;
        }
        __syncthreads();
        s8b af[4], bf[4];
#pragma unroll
        for (int i = 0; i < 4; i++) af[i] = *(const s8b*)(&As[(wm + i * 16 + lr) * BKP + lk]);
#pragma unroll
        for (int j = 0; j < 4; j++) bf[j] = *(const s8b*)(&Bs[(wn + j * 16 + lr) * BKP + lk]);
#pragma unroll
        for (int i = 0; i < 4; i++)
#pragma unroll
            for (int j = 0; j < 4; j++)
                acc[i][j] = __builtin_amdgcn_mfma_f32_16x16x32_bf16(af[i], bf[j], acc[i][j], 0, 0, 0);
        __syncthreads();
    }
    const int orow = (l >> 4) * 4;
#pragma unroll
    for (int i = 0; i < 4; i++) {
#pragma unroll
        for (int r = 0; r < 4; r++) {
            int m = m0 + wm + i * 16 + orow + r;
#pragma unroll
            for (int j = 0; j < 4; j++) {
                int col = n0 + wn + j * 16 + lr;
                int which = col >> 9, h = (col >> 6) & 7, d = col & 63;
                float vv = acc[i][j][r];
                if (which == 0) vv *= 0.125f;
                ushort* dst = which == 0 ? qo : (which == 1 ? ko : vo);
                dst[((long)h * NPQ + m) * 64 + d] = f2bf(vv);
            }
        }
    }
}

// ---------------- flash a3@v: per (key-chunk, q-tile, head); MFMA QK^T + online softmax + MFMA PV
__global__ __launch_bounds__(256)
void k_flash_a3v(const ushort* __restrict__ qlb, const ushort* __restrict__ kg,
                 const ushort* __restrict__ vg,
                 float* __restrict__ pacc, float* __restrict__ pml)
{
    const int c = blockIdx.x;
    const int qt = blockIdx.y;
    const int h = blockIdx.z;
    const int t = threadIdx.x;
    const int w = t >> 6, lane = t & 63;
    const int quad = lane >> 4, l16 = lane & 15;

    __shared__ union {
        struct { ushort Vt[64][40]; ushort Ps[128][40]; } s;
        float Os[128][68];
    } L;

    s8b aq[2][2];
    const ushort* qbase = qlb + ((long)h * 256 + qt * 128 + w * 32) * 64;
#pragma unroll
    for (int mi = 0; mi < 2; mi++)
#pragma unroll
        for (int kf = 0; kf < 2; kf++)
            aq[mi][kf] = *(const s8b*)(qbase + (mi * 16 + l16) * 64 + kf * 32 + quad * 8);

    f4 oacc[2][4] = {};
    float mrow[2][4], lrow[2][4];
#pragma unroll
    for (int mi = 0; mi < 2; mi++)
#pragma unroll
        for (int r = 0; r < 4; r++) { mrow[mi][r] = -INFINITY; lrow[mi][r] = 0.f; }

    const ushort* kh = kg + (long)h * NPQ * 64;
    const ushort* vh = vg + (long)h * NPQ * 64;
    const int key0c = c * 256;

    for (int sub = 0; sub < 8; sub++) {
        int key0 = key0c + sub * 32;
        __syncthreads();
        {
            int kk = t >> 3, dc = (t & 7) * 8;
            s8b vv = *(const s8b*)(vh + (long)(key0 + kk) * 64 + dc);
#pragma unroll
            for (int j = 0; j < 8; j++) L.s.Vt[dc + j][kk] = ((ushort*)&vv)[j];
        }
        s8b bq[2][2];
#pragma unroll
        for (int nj = 0; nj < 2; nj++)
#pragma unroll
            for (int kf = 0; kf < 2; kf++)
                bq[nj][kf] = *(const s8b*)(kh + (long)(key0 + nj * 16 + l16) * 64 + kf * 32 + quad * 8);
        f4 sacc[2][2] = {};
#pragma unroll
        for (int mi = 0; mi < 2; mi++)
#pragma unroll
            for (int nj = 0; nj < 2; nj++) {
                sacc[mi][nj] = __builtin_amdgcn_mfma_f32_16x16x32_bf16(aq[mi][0], bq[nj][0], sacc[mi][nj], 0, 0, 0);
                sacc[mi][nj] = __builtin_amdgcn_mfma_f32_16x16x32_bf16(aq[mi][1], bq[nj][1], sacc[mi][nj], 0, 0, 0);
            }
#pragma unroll
        for (int mi = 0; mi < 2; mi++)
#pragma unroll
            for (int r = 0; r < 4; r++) {
                float mx = fmaxf(sacc[mi][0][r], sacc[mi][1][r]);
#pragma unroll
                for (int d = 1; d < 16; d <<= 1) mx = fmaxf(mx, __shfl_xor(mx, d));
                float mn = fmaxf(mrow[mi][r], mx);
                float f = __expf(mrow[mi][r] - mn);
                float p0 = __expf(sacc[mi][0][r] - mn);
                float p1 = __expf(sacc[mi][1][r] - mn);
                float ps = p0 + p1;
#pragma unroll
                for (int d = 1; d < 16; d <<= 1) ps += __shfl_xor(ps, d);
                lrow[mi][r] = lrow[mi][r] * f + ps;
                mrow[mi][r] = mn;
#pragma unroll
                for (int dj = 0; dj < 4; dj++) oacc[mi][dj][r] *= f;
                int row = w * 32 + mi * 16 + quad * 4 + r;
                L.s.Ps[row][l16]      = f2bf(p0);
                L.s.Ps[row][16 + l16] = f2bf(p1);
            }
        __syncthreads();
        s8b ap[2], bv[4];
#pragma unroll
        for (int mi = 0; mi < 2; mi++)
            ap[mi] = *(const s8b*)(&L.s.Ps[w * 32 + mi * 16 + l16][quad * 8]);
#pragma unroll
        for (int dj = 0; dj < 4; dj++)
            bv[dj] = *(const s8b*)(&L.s.Vt[dj * 16 + l16][quad * 8]);
#pragma unroll
        for (int mi = 0; mi < 2; mi++)
#pragma unroll
            for (int dj = 0; dj < 4; dj++)
                oacc[mi][dj] = __builtin_amdgcn_mfma_f32_16x16x32_bf16(ap[mi], bv[dj], oacc[mi][dj], 0, 0, 0);
    }
    __syncthreads();
#pragma unroll
    for (int mi = 0; mi < 2; mi++)
#pragma unroll
        for (int dj = 0; dj < 4; dj++)
#pragma unroll
            for (int r = 0; r < 4; r++)
                L.Os[w * 32 + mi * 16 + quad * 4 + r][dj * 16 + l16] = oacc[mi][dj][r];
    long pbase = (long)(h * 60 + c);
    if (l16 == 0) {
#pragma unroll
        for (int mi = 0; mi < 2; mi++)
#pragma unroll
            for (int r = 0; r < 4; r++) {
                int i = qt * 128 + w * 32 + mi * 16 + quad * 4 + r;
                pml[pbase * 512 + i] = mrow[mi][r];
                pml[pbase * 512 + 256 + i] = lrow[mi][r];
            }
    }
    __syncthreads();
    float* pc = pacc + pbase * 16384 + qt * 128;
    int d = t >> 2, ig = t & 3;
#pragma unroll
    for (int u = 0; u < 8; u++) {
        int i0 = ig * 32 + u * 4;
        float4 v4 = make_float4(L.Os[i0][d], L.Os[i0 + 1][d], L.Os[i0 + 2][d], L.Os[i0 + 3][d]);
        *(float4*)(pc + (long)d * 256 + i0) = v4;
    }
}

// ---------------- fused sim1+softmax+@Bm attention: 256 landmark keys, V = Bm; writes oh fp32
__global__ __launch_bounds__(256)
void k_attn1(const ushort* __restrict__ qg, const ushort* __restrict__ klb,
             const ushort* __restrict__ Bmb, float* __restrict__ oh)
{
    const int m0 = blockIdx.x * 128;
    const int h = blockIdx.y;
    const int t = threadIdx.x;
    const int w = t >> 6, lane = t & 63;
    const int quad = lane >> 4, l16 = lane & 15;

    __shared__ ushort Vt[64][40];
    __shared__ ushort Ps[128][40];

    s8b aq[2][2];
    const ushort* qbase = qg + ((long)h * NPQ + 230 + m0 + w * 32) * 64;
#pragma unroll
    for (int mi = 0; mi < 2; mi++)
#pragma unroll
        for (int kf = 0; kf < 2; kf++)
            aq[mi][kf] = *(const s8b*)(qbase + (mi * 16 + l16) * 64 + kf * 32 + quad * 8);

    f4 oacc[2][4] = {};
    float mrow[2][4], lrow[2][4];
#pragma unroll
    for (int mi = 0; mi < 2; mi++)
#pragma unroll
        for (int r = 0; r < 4; r++) { mrow[mi][r] = -INFINITY; lrow[mi][r] = 0.f; }

    const ushort* kh = klb + (long)h * 16384;
    const ushort* vh = Bmb + (long)h * 16384;

    for (int sub = 0; sub < 8; sub++) {
        int key0 = sub * 32;
        __syncthreads();
        {
            int kk = t >> 3, dc = (t & 7) * 8;
            s8b vv = *(const s8b*)(vh + (long)(key0 + kk) * 64 + dc);
#pragma unroll
            for (int j = 0; j < 8; j++) Vt[dc + j][kk] = ((ushort*)&vv)[j];
        }
        s8b bq[2][2];
#pragma unroll
        for (int nj = 0; nj < 2; nj++)
#pragma unroll
            for (int kf = 0; kf < 2; kf++)
                bq[nj][kf] = *(const s8b*)(kh + (long)(key0 + nj * 16 + l16) * 64 + kf * 32 + quad * 8);
        f4 sacc[2][2] = {};
#pragma unroll
        for (int mi = 0; mi < 2; mi++)
#pragma unroll
            for (int nj = 0; nj < 2; nj++) {
                sacc[mi][nj] = __builtin_amdgcn_mfma_f32_16x16x32_bf16(aq[mi][0], bq[nj][0], sacc[mi][nj], 0, 0, 0);
                sacc[mi][nj] = __builtin_amdgcn_mfma_f32_16x16x32_bf16(aq[mi][1], bq[nj][1], sacc[mi][nj], 0, 0, 0);
            }
#pragma unroll
        for (int mi = 0; mi < 2; mi++)
#pragma unroll
            for (int r = 0; r < 4; r++) {
                float mx = fmaxf(sacc[mi][0][r], sacc[mi][1][r]);
#pragma unroll
                for (int d = 1; d < 16; d <<= 1) mx = fmaxf(mx, __shfl_xor(mx, d));
                float mn = fmaxf(mrow[mi][r], mx);
                float f = __expf(mrow[mi][r] - mn);
                float p0 = __expf(sacc[mi][0][r] - mn);
                float p1 = __expf(sacc[mi][1][r] - mn);
                float ps = p0 + p1;
#pragma unroll
                for (int d = 1; d < 16; d <<= 1) ps += __shfl_xor(ps, d);
                lrow[mi][r] = lrow[mi][r] * f + ps;
                mrow[mi][r] = mn;
#pragma unroll
                for (int dj = 0; dj < 4; dj++) oacc[mi][dj][r] *= f;
                int row = w * 32 + mi * 16 + quad * 4 + r;
                Ps[row][l16]      = f2bf(p0);
                Ps[row][16 + l16] = f2bf(p1);
            }
        __syncthreads();
        s8b ap[2], bv[4];
#pragma unroll
        for (int mi = 0; mi < 2; mi++)
            ap[mi] = *(const s8b*)(&Ps[w * 32 + mi * 16 + l16][quad * 8]);
#pragma unroll
        for (int dj = 0; dj < 4; dj++)
            bv[dj] = *(const s8b*)(&Vt[dj * 16 + l16][quad * 8]);
#pragma unroll
        for (int mi = 0; mi < 2; mi++)
#pragma unroll
            for (int dj = 0; dj < 4; dj++)
                oacc[mi][dj] = __builtin_amdgcn_mfma_f32_16x16x32_bf16(ap[mi], bv[dj], oacc[mi][dj], 0, 0, 0);
    }
#pragma unroll
    for (int mi = 0; mi < 2; mi++)
#pragma unroll
        for (int r = 0; r < 4; r++) {
            float inv = 1.f / lrow[mi][r];
            int tk = m0 + w * 32 + mi * 16 + quad * 4 + r;
            if (tk < NTOK) {
#pragma unroll
                for (int dj = 0; dj < 4; dj++)
                    oh[(long)tk * 512 + h * 64 + dj * 16 + l16] = oacc[mi][dj][r] * inv;
            }
        }
}

// ---------------- layernorm over 512, writes bf16 xln (first `pad` rows zero)
__global__ __launch_bounds__(256)
void k_layernorm(const float* __restrict__ h, ushort* __restrict__ xln,
                 const float* __restrict__ g, const float* __restrict__ b, int pad)
{
    int row = blockIdx.x, t = threadIdx.x;
    if (row < pad) {
        xln[(long)row * 512 + t] = 0;
        xln[(long)row * 512 + t + 256] = 0;
        return;
    }
    const float* src = h + (long)(row - pad) * 512;
    float x1 = src[t], x2 = src[t + 256];
    float s = x1 + x2, q = x1 * x1 + x2 * x2;
    __shared__ float rs[4], rq[4], st[2];
    int wid = t >> 6, lane = t & 63;
#pragma unroll
    for (int o = 32; o > 0; o >>= 1) { s += __shfl_down(s, o); q += __shfl_down(q, o); }
    if (lane == 0) { rs[wid] = s; rq[wid] = q; }
    __syncthreads();
    if (t == 0) {
        float S = rs[0] + rs[1] + rs[2] + rs[3];
        float Q = rq[0] + rq[1] + rq[2] + rq[3];
        float mean = S / 512.f;
        float var = Q / 512.f - mean * mean;
        st[0] = mean; st[1] = rsqrtf(var + 1e-5f);
    }
    __syncthreads();
    float mean = st[0], rstd = st[1];
    xln[(long)row * 512 + t] = f2bf((x1 - mean) * rstd * g[t] + b[t]);
    xln[(long)row * 512 + t + 256] = f2bf((x2 - mean) * rstd * g[t + 256] + b[t + 256]);
}

__global__ __launch_bounds__(256)
void k_padcls(float* __restrict__ hbuf, const float* __restrict__ cls)
{
    int i = blockIdx.x, t = threadIdx.x;
    if (i == 0) { hbuf[t] = cls[t]; hbuf[t + 256] = cls[t + 256]; }
    else {
        hbuf[(long)(15000 + i) * 512 + t] = hbuf[(long)i * 512 + t];
        hbuf[(long)(15000 + i) * 512 + t + 256] = hbuf[(long)i * 512 + t + 256];
    }
}

__global__ __launch_bounds__(256)
void k_wT(const float* __restrict__ Wm, ushort* __restrict__ Wt, int K, int N, long sW, long sWt)
{
    Wm += (long)blockIdx.z * sW; Wt += (long)blockIdx.z * sWt;
    __shared__ float tile[32][33];
    int tx = threadIdx.x & 31, ty = threadIdx.x >> 5;
    int n0 = blockIdx.x * 32, k0 = blockIdx.y * 32;
#pragma unroll
    for (int u = 0; u < 4; u++) tile[ty + u * 8][tx] = Wm[(long)(k0 + ty + u * 8) * N + n0 + tx];
    __syncthreads();
#pragma unroll
    for (int u = 0; u < 4; u++) Wt[(long)(n0 + ty + u * 8) * K + k0 + tx] = f2bf(tile[tx][ty + u * 8]);
}

__global__ __launch_bounds__(256)
void k_cvt(const float4* __restrict__ src, ushort4* __restrict__ dst, long n4)
{
    long i = (long)blockIdx.x * 256 + threadIdx.x;
    if (i < n4) {
        float4 v = src[i];
        ushort4 o;
        o.x = f2bf(v.x); o.y = f2bf(v.y); o.z = f2bf(v.z); o.w = f2bf(v.w);
        dst[i] = o;
    }
}

__global__ __launch_bounds__(256)
void k_b2f(const ushort4* __restrict__ src, float4* __restrict__ dst, long n4)
{
    long i = (long)blockIdx.x * 256 + threadIdx.x;
    if (i < n4) {
        ushort4 v = src[i];
        dst[i] = make_float4(bf2f(v.x), bf2f(v.y), bf2f(v.z), bf2f(v.w));
    }
}

__global__ __launch_bounds__(64)
void k_landmarks(const ushort* __restrict__ q, const ushort* __restrict__ k,
                 float* __restrict__ ql, ushort* __restrict__ qlb,
                 float* __restrict__ klT, ushort* __restrict__ klb,
                 unsigned* __restrict__ scal)
{
    int i = blockIdx.x, h = blockIdx.y, d = threadIdx.x;
    if (i == 0 && h == 0 && d == 0) { scal[0] = 0u; scal[1] = 0u; }
    long base = ((long)h * NPQ + (long)i * 60) * 64 + d;
    float sq = 0.f, sk = 0.f;
    for (int j = 0; j < 60; j++) { sq += bf2f(q[base + j * 64]); sk += bf2f(k[base + j * 64]); }
    float qv = sq / 60.f, kv = sk / 60.f;
    ql[((long)h * 256 + i) * 64 + d] = qv;
    qlb[((long)h * 256 + i) * 64 + d] = f2bf(qv);
    klT[((long)h * 64 + d) * 256 + i] = kv;
    klb[((long)h * 256 + i) * 64 + d] = f2bf(kv);
}

__global__ __launch_bounds__(256)
void k_softmax256(float* __restrict__ X, ushort* __restrict__ X16, long headStride)
{
    float* row = X + (long)blockIdx.y * headStride + (long)blockIdx.x * 256;
    int t = threadIdx.x, wid = t >> 6, lane = t & 63;
    float x = row[t];
    __shared__ float rm[4], rsum[4], fin[2];
    float m = x;
#pragma unroll
    for (int o = 32; o > 0; o >>= 1) m = fmaxf(m, __shfl_down(m, o));
    if (lane == 0) rm[wid] = m;
    __syncthreads();
    if (t == 0) fin[0] = fmaxf(fmaxf(rm[0], rm[1]), fmaxf(rm[2], rm[3]));
    __syncthreads();
    float e = __expf(x - fin[0]);
    float s = e;
#pragma unroll
    for (int o = 32; o > 0; o >>= 1) s += __shfl_down(s, o);
    if (lane == 0) rsum[wid] = s;
    __syncthreads();
    if (t == 0) fin[1] = rsum[0] + rsum[1] + rsum[2] + rsum[3];
    __syncthreads();
    float v = e / fin[1];
    row[t] = v;
    if (X16) X16[(long)blockIdx.y * headStride + (long)blockIdx.x * 256 + t] = f2bf(v);
}

__global__ __launch_bounds__(256)
void k_colmax(const float* __restrict__ a2, unsigned* __restrict__ scal)
{
    int h = blockIdx.x, t = threadIdx.x, wid = t >> 6, lane = t & 63;
    const float* A = a2 + (long)h * 65536;
    float cs = 0.f, rs = 0.f;
    for (int i = 0; i < 256; i++) cs += A[(long)i * 256 + t];
    for (int j = 0; j < 256; j++) rs += A[(long)t * 256 + j];
    __shared__ float r1[4], r2[4];
    float m1v = cs, m2v = rs;
#pragma unroll
    for (int o = 32; o > 0; o >>= 1) {
        m1v = fmaxf(m1v, __shfl_down(m1v, o));
        m2v = fmaxf(m2v, __shfl_down(m2v, o));
    }
    if (lane == 0) { r1[wid] = m1v; r2[wid] = m2v; }
    __syncthreads();
    if (t == 0) {
        float a = fmaxf(fmaxf(r1[0], r1[1]), fmaxf(r1[2], r1[3]));
        float b = fmaxf(fmaxf(r2[0], r2[1]), fmaxf(r2[2], r2[3]));
        atomicMax(scal + 0, __float_as_uint(a));
        atomicMax(scal + 1, __float_as_uint(b));
    }
}

__global__ __launch_bounds__(256)
void k_zinit(const float* __restrict__ a2, ushort* __restrict__ zb, const unsigned* __restrict__ scal)
{
    float s = 1.f / (__uint_as_float(scal[0]) * __uint_as_float(scal[1]));
    const float* A = a2 + (long)blockIdx.z * 65536;
    ushort* Z = zb + (long)blockIdx.z * 65536;
    __shared__ float tile[32][33];
    int tx = threadIdx.x & 31, ty = threadIdx.x >> 5;
    int i0 = blockIdx.x * 32, j0 = blockIdx.y * 32;
#pragma unroll
    for (int u = 0; u < 4; u++) tile[ty + u * 8][tx] = A[(long)(j0 + ty + u * 8) * 256 + i0 + tx];
    __syncthreads();
#pragma unroll
    for (int u = 0; u < 4; u++) Z[(long)(i0 + ty + u * 8) * 256 + j0 + tx] = f2bf(tile[tx][ty + u * 8] * s);
}

__global__ __launch_bounds__(256)
void k_a3v_merge(const float* __restrict__ pacc, const float* __restrict__ pml,
                 float* __restrict__ t1)
{
    int d = blockIdx.x, h = blockIdx.y, i = threadIdx.x;
    float M = -INFINITY, L = 0.f, num = 0.f;
    for (int c = 0; c < 60; c++) {
        float mc = pml[(long)(h * 60 + c) * 2 * 256 + i];
        float lc = pml[((long)(h * 60 + c) * 2 + 1) * 256 + i];
        float ac = pacc[((long)(h * 60 + c) * 64 + d) * 256 + i];
        if (mc > M) {
            float f = __expf(M - mc);
            num = num * f + ac; L = L * f + lc; M = mc;
        } else {
            float p = __expf(mc - M);
            num = fmaf(p, ac, num); L = fmaf(p, lc, L);
        }
    }
    t1[((long)h * 256 + i) * 64 + d] = num / L;
}

__global__ __launch_bounds__(256)
void k_resconv(float* __restrict__ oh, const ushort* __restrict__ v,
               const float* __restrict__ rw, int Mrows)
{
    int h = blockIdx.y;
    int d = threadIdx.x & 63, r = threadIdx.x >> 6;
    int tk = blockIdx.x * 4 + r;
    if (tk >= Mrows) return;
    const ushort* vb = v + (long)h * NPQ * 64 + d;
    float acc = 0.f;
    int center = 230 + tk;
#pragma unroll
    for (int kk = 0; kk < 33; kk++) {
        int src = center + kk - 16;
        if (src >= 0 && src < NP) acc = fmaf(rw[h * 33 + kk], bf2f(vb[(long)src * 64]), acc);
    }
    oh[(long)tk * 512 + h * 64 + d] += acc;
}

__global__ __launch_bounds__(256)
void k_cls(const ushort* __restrict__ qb, const float* __restrict__ klT,
           const float* __restrict__ Bm, const ushort* __restrict__ vb,
           const float* __restrict__ rw, float* __restrict__ oh)
{
    int h = blockIdx.x, t = threadIdx.x, wid = t >> 6, lane = t & 63;
    __shared__ float qs[64], p[256], red[256];
    __shared__ float rm[4], rsum[4], fin[2];
    if (t < 64) qs[t] = bf2f(qb[((long)h * NPQ + 230) * 64 + t]);
    __syncthreads();
    float s = 0.f;
    for (int d = 0; d < 64; d++) s = fmaf(qs[d], klT[((long)h * 64 + d) * 256 + t], s);
    float m = s;
#pragma unroll
    for (int o = 32; o > 0; o >>= 1) m = fmaxf(m, __shfl_down(m, o));
    if (lane == 0) rm[wid] = m;
    __syncthreads();
    if (t == 0) fin[0] = fmaxf(fmaxf(rm[0], rm[1]), fmaxf(rm[2], rm[3]));
    __syncthreads();
    float e = __expf(s - fin[0]);
    float ss = e;
#pragma unroll
    for (int o = 32; o > 0; o >>= 1) ss += __shfl_down(ss, o);
    if (lane == 0) rsum[wid] = ss;
    __syncthreads();
    if (t == 0) fin[1] = rsum[0] + rsum[1] + rsum[2] + rsum[3];
    __syncthreads();
    p[t] = e / fin[1];
    __syncthreads();
    int d = t & 63, grp = t >> 6;
    float o = 0.f;
    for (int j = grp * 64; j < grp * 64 + 64; j++) o = fmaf(p[j], Bm[((long)h * 256 + j) * 64 + d], o);
    red[t] = o;
    __syncthreads();
    if (t < 64) {
        float val = red[t] + red[t + 64] + red[t + 128] + red[t + 192];
#pragma unroll
        for (int kk = 0; kk < 33; kk++)
            val = fmaf(rw[h * 33 + kk], bf2f(vb[((long)h * NPQ + 214 + kk) * 64 + t]), val);
        oh[h * 64 + t] = val;
    }
}

__global__ __launch_bounds__(256)
void k_copy4(const float4* __restrict__ src, float4* __restrict__ dst, long n4)
{
    long i = (long)blockIdx.x * 256 + threadIdx.x;
    if (i < n4) dst[i] = src[i];
}

// ---------------- combine w7+w5+w3+identity into wc[49][512], bc = b7+b5+b3
__global__ __launch_bounds__(512)
void k_wcomb(const float* __restrict__ w7, const float* __restrict__ b7,
             const float* __restrict__ w5, const float* __restrict__ b5,
             const float* __restrict__ w3, const float* __restrict__ b3,
             float* __restrict__ wc, float* __restrict__ bc)
{
    int k = blockIdx.x, c = threadIdx.x;
    int kr = k / 7, kc = k % 7;
    float v = w7[c * 49 + k];
    if (kr >= 1 && kr <= 5 && kc >= 1 && kc <= 5) v += w5[c * 25 + (kr - 1) * 5 + (kc - 1)];
    if (kr >= 2 && kr <= 4 && kc >= 2 && kc <= 4) v += w3[c * 9 + (kr - 2) * 3 + (kc - 2)];
    if (k == 24) v += 1.f;
    wc[k * 512 + c] = v;
    if (k == 0) bc[c] = b7[c] + b5[c] + b3[c];
}

// ---------------- PPEG v2: single 7x7 combined depthwise; bf16 LDS tile; 8x4 spatial x 64ch per block
__global__ __launch_bounds__(256)
void k_ppeg2(const float* __restrict__ cnn, float* __restrict__ hbuf,
             const float* __restrict__ wc, const float* __restrict__ bc)
{
    __shared__ ushort tile[140][64];   // [10 rows x 14 cols][64 ch] bf16
    int t = threadIdx.x;
    int cp = t & 31;     // channel pair
    int g = t >> 5;      // 8 groups x 4 outputs = 32 spatial positions
    int c0 = blockIdx.x * 8, r0 = blockIdx.y * 4, cb = blockIdx.z * 64;
    for (int idx = t; idx < 140 * 32; idx += 256) {
        int pos = idx >> 5, pp = idx & 31;
        int pr = pos / 14, pc = pos % 14;
        int gr = r0 + pr - 3, gc = c0 + pc - 3;
        float v0 = 0.f, v1 = 0.f;
        if (gr >= 0 && gr < HG && gc >= 0 && gc < HG) {
            const float* src = cnn + (long)(gr * HG + gc) * 512 + cb + pp * 2;
            v0 = src[0]; v1 = src[1];
        }
        tile[pos][pp * 2] = f2bf(v0);
        tile[pos][pp * 2 + 1] = f2bf(v1);
    }
    __syncthreads();
    float acc[4][2] = {};
    for (int kr = 0; kr < 7; kr++)
#pragma unroll
        for (int kc = 0; kc < 7; kc++) {
            float w0 = wc[(kr * 7 + kc) * 512 + cb + cp * 2];
            float w1 = wc[(kr * 7 + kc) * 512 + cb + cp * 2 + 1];
#pragma unroll
            for (int u = 0; u < 4; u++) {
                int p = g * 4 + u;
                int orow = p >> 3, ocol = p & 7;
                unsigned pk = *(const unsigned*)&tile[(orow + kr) * 14 + (ocol + kc)][cp * 2];
                acc[u][0] = fmaf(w0, bf2f((ushort)pk), acc[u][0]);
                acc[u][1] = fmaf(w1, bf2f((ushort)(pk >> 16)), acc[u][1]);
            }
        }
    float b0 = bc[cb + cp * 2], b1 = bc[cb + cp * 2 + 1];
#pragma unroll
    for (int u = 0; u < 4; u++) {
        int p = g * 4 + u;
        int orow = p >> 3, ocol = p & 7;
        int gr = r0 + orow, gc = c0 + ocol;
        if (gr < HG && gc < HG) {
            float* dst = hbuf + (long)(1 + gr * HG + gc) * 512 + cb + cp * 2;
            dst[0] = acc[u][0] + b0;
            dst[1] = acc[u][1] + b1;
        }
    }
}

__global__ __launch_bounds__(256)
void k_final(const float* __restrict__ hbuf, const float* __restrict__ g,
             const float* __restrict__ b, const float* __restrict__ W2,
             const float* __restrict__ b2, float* __restrict__ out)
{
    __shared__ float y[512];
    __shared__ float rs[4], rq[4], st[2], lg[8];
    int t = threadIdx.x, wid = t >> 6, lane = t & 63;
    float x1 = hbuf[t], x2 = hbuf[t + 256];
    float s = x1 + x2, q = x1 * x1 + x2 * x2;
#pragma unroll
    for (int o = 32; o > 0; o >>= 1) { s += __shfl_down(s, o); q += __shfl_down(q, o); }
    if (lane == 0) { rs[wid] = s; rq[wid] = q; }
    __syncthreads();
    if (t == 0) {
        float S = rs[0] + rs[1] + rs[2] + rs[3];
        float Q = rq[0] + rq[1] + rq[2] + rq[3];
        float mean = S / 512.f;
        float var = Q / 512.f - mean * mean;
        st[0] = mean; st[1] = rsqrtf(var + 1e-5f);
    }
    __syncthreads();
    float mean = st[0], rstd = st[1];
    y[t] = (x1 - mean) * rstd * g[t] + b[t];
    y[t + 256] = (x2 - mean) * rstd * g[t + 256] + b[t + 256];
    __syncthreads();
    if (t < 5) {
        float acc = b2[t];
        for (int kx = 0; kx < 512; kx++) acc = fmaf(y[kx], W2[kx * 5 + t], acc);
        lg[t] = acc;
    }
    __syncthreads();
    if (t == 0) {
        float mx = lg[0]; int am = 0;
        for (int j = 1; j < 5; j++) if (lg[j] > mx) { mx = lg[j]; am = j; }
        float e[5], se = 0.f;
        for (int j = 0; j < 5; j++) { e[j] = __expf(lg[j] - mx); se += e[j]; }
        for (int j = 0; j < 5; j++) { out[j] = lg[j]; out[5 + j] = e[j] / se; }
        out[10] = (float)am;
    }
}

extern "C" void kernel_launch(void* const* d_in, const int* in_sizes, int n_in,
                              void* d_out, int out_size, void* d_ws, size_t ws_size,
                              hipStream_t stream)
{
    const float* data  = (const float*)d_in[0];
    const float* Wfc1  = (const float*)d_in[1];
    const float* bfc1  = (const float*)d_in[2];
    const float* cls   = (const float*)d_in[3];
    const float* ln1g  = (const float*)d_in[4];
    const float* ln1b  = (const float*)d_in[5];
    const float* qkv1  = (const float*)d_in[6];
    const float* out1w = (const float*)d_in[7];
    const float* out1b = (const float*)d_in[8];
    const float* res1  = (const float*)d_in[9];
    const float* w7    = (const float*)d_in[10];
    const float* b7    = (const float*)d_in[11];
    const float* w5    = (const float*)d_in[12];
    const float* b5    = (const float*)d_in[13];
    const float* w3    = (const float*)d_in[14];
    const float* b3    = (const float*)d_in[15];
    const float* ln2g  = (const float*)d_in[16];
    const float* ln2b  = (const float*)d_in[17];
    const float* qkv2  = (const float*)d_in[18];
    const float* out2w = (const float*)d_in[19];
    const float* out2b = (const float*)d_in[20];
    const float* res2  = (const float*)d_in[21];
    const float* normg = (const float*)d_in[22];
    const float* normb = (const float*)d_in[23];
    const float* Wfc2  = (const float*)d_in[24];
    const float* bfc2  = (const float*)d_in[25];
    float* out = (float*)d_out;

    float* W = (float*)d_ws;
    size_t off = 0;
    auto alloc = [&](size_t n) { size_t o = off; off += (n + 255) & ~(size_t)255; return o; };
    float*  hbuf   = W + alloc((size_t)NTOK * 512);
    float*  ohreg  = W + alloc((size_t)15232 * 512);
    float*  oh     = ohreg;
    ushort* xln    = (ushort*)ohreg;
    ushort* qb16   = (ushort*)(W + alloc((size_t)8 * NPQ * 32));
    ushort* kb16   = (ushort*)(W + alloc((size_t)8 * NPQ * 32));
    ushort* vb16   = (ushort*)(W + alloc((size_t)8 * NPQ * 32));
    float*  ql     = W + alloc(8 * 256 * 64);
    ushort* qlb    = (ushort*)(W + alloc(8 * 256 * 32));
    float*  klT    = W + alloc(8 * 64 * 256);
    ushort* klb    = (ushort*)(W + alloc(8 * 256 * 32));
    float*  a2     = W + alloc(8 * 65536);
    ushort* a2b    = (ushort*)(W + alloc(8 * 32768));
    ushort* zb0    = (ushort*)(W + alloc(8 * 32768));
    ushort* zb1    = (ushort*)(W + alloc(8 * 32768));
    ushort* m1b    = (ushort*)(W + alloc(8 * 32768));
    ushort* mab    = (ushort*)(W + alloc(8 * 32768));
    ushort* mbb    = (ushort*)(W + alloc(8 * 32768));
    float*  z0     = W + alloc(8 * 65536);
    float*  z1     = W + alloc(8 * 65536);
    float*  m1     = W + alloc(8 * 65536);
    float*  ma     = W + alloc(8 * 65536);
    float*  mb     = W + alloc(8 * 65536);
    float*  t1     = W + alloc(8 * 256 * 64);
    float*  Bm     = W + alloc(8 * 256 * 64);
    ushort* Bmb    = (ushort*)(W + alloc(8 * 256 * 32));
    float*  scal   = W + alloc(64);
    ushort* ohb16  = (ushort*)(W + alloc((size_t)15232 * 256));
    ushort* WfcT   = (ushort*)(W + alloc(1024 * 256));
    ushort* qkv1T  = (ushort*)(W + alloc(1536 * 256));
    ushort* qkv2T  = (ushort*)(W + alloc(1536 * 256));
    ushort* out1T  = (ushort*)(W + alloc(512 * 256));
    ushort* out2T  = (ushort*)(W + alloc(512 * 256));
    float*  wc     = W + alloc(49 * 512);
    float*  bc     = W + alloc(512);
    float*  big    = W + alloc(8110080);   // datab | pacc+pml | ppeg cnn
    ushort* datab  = (ushort*)big;
    float*  pacc   = big;
    float*  pml    = big + 7864320;
    float*  cnn    = big;
    if (ws_size < off * sizeof(float)) return;

    k_wT<<<dim3(16, 32, 1), 256, 0, stream>>>(Wfc1, WfcT, 1024, 512, 0, 0);
    k_wT<<<dim3(48, 16, 1), 256, 0, stream>>>(qkv1, qkv1T, 512, 1536, 0, 0);
    k_wT<<<dim3(48, 16, 1), 256, 0, stream>>>(qkv2, qkv2T, 512, 1536, 0, 0);
    k_wT<<<dim3(16, 16, 1), 256, 0, stream>>>(out1w, out1T, 512, 512, 0, 0);
    k_wT<<<dim3(16, 16, 1), 256, 0, stream>>>(out2w, out2T, 512, 512, 0, 0);
    k_wcomb<<<49, 512, 0, stream>>>(w7, b7, w5, b5, w3, b3, wc, bc);
    k_cvt<<<15000, 256, 0, stream>>>((const float4*)data, (ushort4*)datab, 3840000);
    gemm_mfma<4, 4, 2, 2><<<dim3(4, 118, 1), 256, 0, stream>>>(
        datab, 1024, 0, WfcT, 1024, 0, hbuf + 512, 512, 0, 15000, 1024, bfc1, 1, 0);
    k_padcls<<<130, 256, 0, stream>>>(hbuf, cls);

    auto layer = [&](const float* lng, const float* lnb, const ushort* qkvT,
                     const float* outW, const ushort* outT, const float* outB,
                     const float* resW, bool full) {
        k_layernorm<<<NP, 256, 0, stream>>>(hbuf, xln, lng, lnb, 230);
        gemm_qkv_mfma<<<dim3(12, 120, 1), 256, 0, stream>>>(xln, qkvT, qb16, kb16, vb16);
        k_landmarks<<<dim3(256, 8), 64, 0, stream>>>(qb16, kb16, ql, qlb, klT, klb, (unsigned*)scal);
        gemm_f32<<<dim3(4, 4, 8), 256, 0, stream>>>(ql, 64, 16384, klT, 256, 16384,
            a2, 256, 65536, 256, 256, 64, nullptr, nullptr, 0, 0, 0.f, 1.f, 0, 0);
        k_softmax256<<<dim3(256, 8), 256, 0, stream>>>(a2, a2b, 65536);
        k_colmax<<<8, 256, 0, stream>>>(a2, (unsigned*)scal);
        k_zinit<<<dim3(8, 8, 8), 256, 0, stream>>>(a2, zb0, (const unsigned*)scal);
        // pinv iters 0-4 in bf16 MFMA
        ushort* zbi = zb0; ushort* zbo = zb1;
        for (int it = 0; it < 5; ++it) {
            gemm_nn16<<<dim3(4, 4, 8), 256, 0, stream>>>(a2b, zbi, nullptr, m1b, 256, 256, 1.f, 0.f, 65536);
            gemm_nn16<<<dim3(4, 4, 8), 256, 0, stream>>>(m1b, m1b, m1b, mab, 256, 256, -1.f, 7.f, 65536);
            gemm_nn16<<<dim3(4, 4, 8), 256, 0, stream>>>(m1b, mab, m1b, mbb, 256, 256, -1.f, 15.f, 65536);
            gemm_nn16<<<dim3(4, 4, 8), 256, 0, stream>>>(zbi, mbb, zbi, zbo, 256, 256, -0.25f, 3.25f, 65536);
            ushort* tmp = zbi; zbi = zbo; zbo = tmp;
        }
        k_b2f<<<512, 256, 0, stream>>>((const ushort4*)zbi, (float4*)z0, 131072);
        // final pinv iter in fp32
        float* zi = z0; float* zo = z1;
        {
            gemm_f32<<<dim3(4, 4, 8), 256, 0, stream>>>(a2, 256, 65536, zi, 256, 65536,
                m1, 256, 65536, 256, 256, 256, nullptr, nullptr, 0, 0, 0.f, 1.f, 0, 0);
            gemm_f32<<<dim3(4, 4, 8), 256, 0, stream>>>(m1, 256, 65536, m1, 256, 65536,
                ma, 256, 65536, 256, 256, 256, nullptr, m1, 256, 65536, 7.f, -1.f, 0, 0);
            gemm_f32<<<dim3(4, 4, 8), 256, 0, stream>>>(m1, 256, 65536, ma, 256, 65536,
                mb, 256, 65536, 256, 256, 256, nullptr, m1, 256, 65536, 15.f, -1.f, 0, 0);
            gemm_f32<<<dim3(4, 4, 8), 256, 0, stream>>>(zi, 256, 65536, mb, 256, 65536,
                zo, 256, 65536, 256, 256, 256, nullptr, zi, 256, 65536, 3.25f, -0.25f, 0, 0);
            float* tmp = zi; zi = zo; zo = tmp;
        }
        k_flash_a3v<<<dim3(60, 2, 8), 256, 0, stream>>>(qlb, kb16, vb16, pacc, pml);
        k_a3v_merge<<<dim3(64, 8), 256, 0, stream>>>(pacc, pml, t1);
        gemm_f32<<<dim3(1, 4, 8), 256, 0, stream>>>(zi, 256, 65536, t1, 64, 16384,
            Bm, 64, 16384, 256, 64, 256, nullptr, nullptr, 0, 0, 0.f, 1.f, 0, 0);
        if (full) {
            k_cvt<<<128, 256, 0, stream>>>((const float4*)Bm, (ushort4*)Bmb, 32768);
            k_attn1<<<dim3(119, 8), 256, 0, stream>>>(qb16, klb, Bmb, oh);
            k_resconv<<<dim3((NTOK + 3) / 4, 8), 256, 0, stream>>>(oh, vb16, resW, NTOK);
            k_cvt<<<7565, 256, 0, stream>>>((const float4*)oh, (ushort4*)ohb16, 1936640);
            gemm_mfma<4, 4, 2, 2><<<dim3(4, 119, 1), 256, 0, stream>>>(
                ohb16, 512, 0, outT, 512, 0, hbuf, 512, 0, NTOK, 512, outB, 0, 1);
        } else {
            k_cls<<<8, 256, 0, stream>>>(qb16, klT, Bm, vb16, resW, oh);
            gemm_f32<<<dim3(8, 1, 1), 256, 0, stream>>>(oh, 512, 0, outW, 512, 0,
                hbuf, 512, 0, 1, 512, 512, outB, nullptr, 0, 0, 0.f, 1.f, 0, 1);
        }
    };

    layer(ln1g, ln1b, qkv1T, out1w, out1T, out1b, res1, true);
    k_copy4<<<(1936512 + 255) / 256, 256, 0, stream>>>((const float4*)(hbuf + 512), (float4*)cnn, 1936512);
    k_ppeg2<<<dim3(16, 31, 8), 256, 0, stream>>>(cnn, hbuf, wc, bc);
    layer(ln2g, ln2b, qkv2T, out2w, out2T, out2b, res2, false);
    k_final<<<1, 256, 0, stream>>>(hbuf, normg, normb, Wfc2, bfc2, out);
}

// Round 5
// 1466.661 us; speedup vs baseline: 2.3107x; 1.0821x over previous
//
#include <hip/hip_runtime.h>
#include <math.h>

#define NP 15360
#define NPQ 15488
#define NTOK 15130
#define HG 123

typedef __attribute__((ext_vector_type(8))) short s8b;
typedef __attribute__((ext_vector_type(4))) float f4;

__device__ inline float bf2f(ushort u) { return __uint_as_float(((unsigned)u) << 16); }
__device__ inline ushort f2bf(float f) {
    unsigned u = __float_as_uint(f);
    unsigned r = (u + 0x7fffu + ((u >> 16) & 1u)) >> 16;
    return (ushort)r;
}

// ---------------- generic fp32 GEMM (small/sensitive ops): C = cS*(A@B) + eS*E + bias
__global__ __launch_bounds__(256)
void gemm_f32(const float* __restrict__ A, int lda, long sA,
              const float* __restrict__ B, int ldb, long sB,
              float* __restrict__ C, int ldc, long sC,
              int M, int N, int K,
              const float* __restrict__ bias,
              const float* __restrict__ E, int ldE, long sE, float eS,
              float cS, int relu, int accum)
{
    A += (long)blockIdx.z * sA;
    B += (long)blockIdx.z * sB;
    C += (long)blockIdx.z * sC;
    if (E) E += (long)blockIdx.z * sE;
    const int m0 = blockIdx.y * 64, n0 = blockIdx.x * 64;
    const int t = threadIdx.x;
    const int tx = t & 15, ty = t >> 4;
    __shared__ float As[16][64];
    __shared__ float Bs[16][64];
    float acc[4][4] = {};
    const int arow = t >> 2, akc = (t & 3) * 4;
    const int brow = t >> 4, bnc = (t & 15) * 4;
    for (int k0 = 0; k0 < K; k0 += 16) {
        float4 av = make_float4(0.f, 0.f, 0.f, 0.f);
        if (m0 + arow < M) av = *(const float4*)(A + (long)(m0 + arow) * lda + k0 + akc);
        As[akc + 0][arow] = av.x; As[akc + 1][arow] = av.y;
        As[akc + 2][arow] = av.z; As[akc + 3][arow] = av.w;
        float4 bv = *(const float4*)(B + (long)(k0 + brow) * ldb + n0 + bnc);
        *(float4*)&Bs[brow][bnc] = bv;
        __syncthreads();
#pragma unroll
        for (int kk = 0; kk < 16; ++kk) {
            float4 a4 = *(const float4*)&As[kk][ty * 4];
            float4 b4 = *(const float4*)&Bs[kk][tx * 4];
            float a[4] = {a4.x, a4.y, a4.z, a4.w};
            float b[4] = {b4.x, b4.y, b4.z, b4.w};
#pragma unroll
            for (int i = 0; i < 4; i++)
#pragma unroll
                for (int j = 0; j < 4; j++) acc[i][j] = fmaf(a[i], b[j], acc[i][j]);
        }
        __syncthreads();
    }
#pragma unroll
    for (int i = 0; i < 4; i++) {
        int m = m0 + ty * 4 + i;
        if (m < M) {
#pragma unroll
            for (int j = 0; j < 4; j++) {
                int n = n0 + tx * 4 + j;
                float v = cS * acc[i][j];
                if (E) v = fmaf(eS, E[(long)m * ldE + n], v);
                if (bias) v += bias[n];
                if (relu) v = fmaxf(v, 0.f);
                if (accum) C[(long)m * ldc + n] += v;
                else C[(long)m * ldc + n] = v;
            }
        }
    }
}

// ---------------- bf16 MFMA GEMM: C(fp32) = A(bf16,[M][K]) @ Bt(bf16,[N][K])^T
template<int MT, int NT, int WROWS, int WCOLS>
__global__ __launch_bounds__(256)
void gemm_mfma(const ushort* __restrict__ A, int lda, long sA,
               const ushort* __restrict__ Bt, int ldb, long sB,
               float* __restrict__ C, int ldc, long sC,
               int M, int K,
               const float* __restrict__ bias, int relu, int accum)
{
    constexpr int TM = MT * 16 * WROWS;
    constexpr int TN = NT * 16 * WCOLS;
    constexpr int BKP = 40;
    __shared__ ushort As[TM * BKP];
    __shared__ ushort Bs[TN * BKP];
    A  += (long)blockIdx.z * sA;
    Bt += (long)blockIdx.z * sB;
    C  += (long)blockIdx.z * sC;
    const int t = threadIdx.x;
    const int m0 = blockIdx.y * TM, n0 = blockIdx.x * TN;
    const int w = t >> 6, l = t & 63;
    const int wm = (w / WCOLS) * (MT * 16), wn = (w % WCOLS) * (NT * 16);
    const int lr = l & 15;
    const int lk = (l >> 4) * 8;
    f4 acc[MT][NT] = {};
    for (int k0 = 0; k0 < K; k0 += 32) {
        for (int c = t; c < TM * 4; c += 256) {
            int row = c >> 2, kc = (c & 3) * 8;
            s8b v = *(const s8b*)(A + (long)(m0 + row) * lda + k0 + kc);
            *(s8b*)(&As[row * BKP + kc]) = v;
        }
        for (int c = t; c < TN * 4; c += 256) {
            int row = c >> 2, kc = (c & 3) * 8;
            s8b v = *(const s8b*)(Bt + (long)(n0 + row) * ldb + k0 + kc);
            *(s8b*)(&Bs[row * BKP + kc]) = v;
        }
        __syncthreads();
        s8b af[MT], bf[NT];
#pragma unroll
        for (int i = 0; i < MT; i++) af[i] = *(const s8b*)(&As[(wm + i * 16 + lr) * BKP + lk]);
#pragma unroll
        for (int j = 0; j < NT; j++) bf[j] = *(const s8b*)(&Bs[(wn + j * 16 + lr) * BKP + lk]);
#pragma unroll
        for (int i = 0; i < MT; i++)
#pragma unroll
            for (int j = 0; j < NT; j++)
                acc[i][j] = __builtin_amdgcn_mfma_f32_16x16x32_bf16(af[i], bf[j], acc[i][j], 0, 0, 0);
        __syncthreads();
    }
    const int orow = (l >> 4) * 4;
#pragma unroll
    for (int i = 0; i < MT; i++) {
#pragma unroll
        for (int r = 0; r < 4; r++) {
            int m = m0 + wm + i * 16 + orow + r;
            if (m < M) {
#pragma unroll
                for (int j = 0; j < NT; j++) {
                    int n = n0 + wn + j * 16 + lr;
                    float vv = acc[i][j][r];
                    if (bias) vv += bias[n];
                    if (relu) vv = fmaxf(vv, 0.f);
                    if (accum) C[(long)m * ldc + n] += vv;
                    else C[(long)m * ldc + n] = vv;
                }
            }
        }
    }
}

// ---------------- bf16-in/bf16-out MFMA GEMM, B row-major [K][N]: C16 = bf16(cS*(A@B) + eS*E16)
__global__ __launch_bounds__(256)
void gemm_nn16(const ushort* __restrict__ A, const ushort* __restrict__ B,
               const ushort* __restrict__ E, ushort* __restrict__ C,
               int N, int K, float cS, float eS, long sAB)
{
    __shared__ ushort As[64 * 40];
    __shared__ ushort Bs[64 * 40];
    A += (long)blockIdx.z * sAB;
    B += (long)blockIdx.z * sAB;
    if (E) E += (long)blockIdx.z * sAB;
    C += (long)blockIdx.z * sAB;
    const int t = threadIdx.x;
    const int m0 = blockIdx.y * 64, n0 = blockIdx.x * 64;
    const int w = t >> 6, l = t & 63;
    const int wm = (w >> 1) * 32, wn = (w & 1) * 32;
    const int lr = l & 15, lk = (l >> 4) * 8;
    f4 acc[2][2] = {};
    for (int k0 = 0; k0 < K; k0 += 32) {
        {
            int row = t >> 2, kc = (t & 3) * 8;
            s8b v = *(const s8b*)(A + (long)(m0 + row) * K + k0 + kc);
            *(s8b*)(&As[row * 40 + kc]) = v;
            int kk = t >> 3, nc = (t & 7) * 8;
            s8b vb = *(const s8b*)(B + (long)(k0 + kk) * N + n0 + nc);
#pragma unroll
            for (int j = 0; j < 8; j++) Bs[(nc + j) * 40 + kk] = ((ushort*)&vb)[j];
        }
        __syncthreads();
        s8b af[2], bf[2];
#pragma unroll
        for (int i = 0; i < 2; i++) af[i] = *(const s8b*)(&As[(wm + i * 16 + lr) * 40 + lk]);
#pragma unroll
        for (int j = 0; j < 2; j++) bf[j] = *(const s8b*)(&Bs[(wn + j * 16 + lr) * 40 + lk]);
#pragma unroll
        for (int i = 0; i < 2; i++)
#pragma unroll
            for (int j = 0; j < 2; j++)
                acc[i][j] = __builtin_amdgcn_mfma_f32_16x16x32_bf16(af[i], bf[j], acc[i][j], 0, 0, 0);
        __syncthreads();
    }
    const int orow = (l >> 4) * 4;
#pragma unroll
    for (int i = 0; i < 2; i++)
#pragma unroll
        for (int r = 0; r < 4; r++) {
            int m = m0 + wm + i * 16 + orow + r;
#pragma unroll
            for (int j = 0; j < 2; j++) {
                int n = n0 + wn + j * 16 + lr;
                float vv = cS * acc[i][j][r];
                if (E) vv = fmaf(eS, bf2f(E[(long)m * N + n]), vv);
                C[(long)m * N + n] = f2bf(vv);
            }
        }
}

// ---------------- qkv MFMA GEMM, scatter into bf16 q/k/v [head][NPQ][64], q scaled 1/8
__global__ __launch_bounds__(256)
void gemm_qkv_mfma(const ushort* __restrict__ A, const ushort* __restrict__ Bt,
                   ushort* __restrict__ qo, ushort* __restrict__ ko, ushort* __restrict__ vo)
{
    constexpr int BKP = 40;
    __shared__ ushort As[128 * BKP];
    __shared__ ushort Bs[128 * BKP];
    const int t = threadIdx.x;
    const int m0 = blockIdx.y * 128, n0 = blockIdx.x * 128;
    const int w = t >> 6, l = t & 63;
    const int wm = (w >> 1) * 64, wn = (w & 1) * 64;
    const int lr = l & 15;
    const int lk = (l >> 4) * 8;
    f4 acc[4][4] = {};
    for (int k0 = 0; k0 < 512; k0 += 32) {
        for (int c = t; c < 512; c += 256) {
            int row = c >> 2, kc = (c & 3) * 8;
            s8b va = *(const s8b*)(A + (long)(m0 + row) * 512 + k0 + kc);
            *(s8b*)(&As[row * BKP + kc]) = va;
            s8b vb = *(const s8b*)(Bt + (long)(n0 + row) * 512 + k0 + kc);
            *(s8b*)(&Bs[row * BKP + kc]) = vb;
        }
        __syncthreads();
        s8b af[4], bf[4];
#pragma unroll
        for (int i = 0; i < 4; i++) af[i] = *(const s8b*)(&As[(wm + i * 16 + lr) * BKP + lk]);
#pragma unroll
        for (int j = 0; j < 4; j++) bf[j] = *(const s8b*)(&Bs[(wn + j * 16 + lr) * BKP + lk]);
#pragma unroll
        for (int i = 0; i < 4; i++)
#pragma unroll
            for (int j = 0; j < 4; j++)
                acc[i][j] = __builtin_amdgcn_mfma_f32_16x16x32_bf16(af[i], bf[j], acc[i][j], 0, 0, 0);
        __syncthreads();
    }
    const int orow = (l >> 4) * 4;
#pragma unroll
    for (int i = 0; i < 4; i++) {
#pragma unroll
        for (int r = 0; r < 4; r++) {
            int m = m0 + wm + i * 16 + orow + r;
#pragma unroll
            for (int j = 0; j < 4; j++) {
                int col = n0 + wn + j * 16 + lr;
                int which = col >> 9, h = (col >> 6) & 7, d = col & 63;
                float vv = acc[i][j][r];
                if (which == 0) vv *= 0.125f;
                ushort* dst = which == 0 ? qo : (which == 1 ? ko : vo);
                dst[((long)h * NPQ + m) * 64 + d] = f2bf(vv);
            }
        }
    }
}

// ---------------- flash a3@v: per (key-chunk, q-tile, head); MFMA QK^T + online softmax + MFMA PV
__global__ __launch_bounds__(256)
void k_flash_a3v(const ushort* __restrict__ qlb, const ushort* __restrict__ kg,
                 const ushort* __restrict__ vg,
                 float* __restrict__ pacc, float* __restrict__ pml)
{
    const int c = blockIdx.x;
    const int qt = blockIdx.y;
    const int h = blockIdx.z;
    const int t = threadIdx.x;
    const int w = t >> 6, lane = t & 63;
    const int quad = lane >> 4, l16 = lane & 15;

    __shared__ union {
        struct { ushort Vt[64][40]; ushort Ps[128][40]; } s;
        float Os[128][68];
    } L;

    s8b aq[2][2];
    const ushort* qbase = qlb + ((long)h * 256 + qt * 128 + w * 32) * 64;
#pragma unroll
    for (int mi = 0; mi < 2; mi++)
#pragma unroll
        for (int kf = 0; kf < 2; kf++)
            aq[mi][kf] = *(const s8b*)(qbase + (mi * 16 + l16) * 64 + kf * 32 + quad * 8);

    f4 oacc[2][4] = {};
    float mrow[2][4], lrow[2][4];
#pragma unroll
    for (int mi = 0; mi < 2; mi++)
#pragma unroll
        for (int r = 0; r < 4; r++) { mrow[mi][r] = -INFINITY; lrow[mi][r] = 0.f; }

    const ushort* kh = kg + (long)h * NPQ * 64;
    const ushort* vh = vg + (long)h * NPQ * 64;
    const int key0c = c * 256;

    for (int sub = 0; sub < 8; sub++) {
        int key0 = key0c + sub * 32;
        __syncthreads();
        {
            int kk = t >> 3, dc = (t & 7) * 8;
            s8b vv = *(const s8b*)(vh + (long)(key0 + kk) * 64 + dc);
#pragma unroll
            for (int j = 0; j < 8; j++) L.s.Vt[dc + j][kk] = ((ushort*)&vv)[j];
        }
        s8b bq[2][2];
#pragma unroll
        for (int nj = 0; nj < 2; nj++)
#pragma unroll
            for (int kf = 0; kf < 2; kf++)
                bq[nj][kf] = *(const s8b*)(kh + (long)(key0 + nj * 16 + l16) * 64 + kf * 32 + quad * 8);
        f4 sacc[2][2] = {};
#pragma unroll
        for (int mi = 0; mi < 2; mi++)
#pragma unroll
            for (int nj = 0; nj < 2; nj++) {
                sacc[mi][nj] = __builtin_amdgcn_mfma_f32_16x16x32_bf16(aq[mi][0], bq[nj][0], sacc[mi][nj], 0, 0, 0);
                sacc[mi][nj] = __builtin_amdgcn_mfma_f32_16x16x32_bf16(aq[mi][1], bq[nj][1], sacc[mi][nj], 0, 0, 0);
            }
#pragma unroll
        for (int mi = 0; mi < 2; mi++)
#pragma unroll
            for (int r = 0; r < 4; r++) {
                float mx = fmaxf(sacc[mi][0][r], sacc[mi][1][r]);
#pragma unroll
                for (int d = 1; d < 16; d <<= 1) mx = fmaxf(mx, __shfl_xor(mx, d));
                float mn = fmaxf(mrow[mi][r], mx);
                float f = __expf(mrow[mi][r] - mn);
                float p0 = __expf(sacc[mi][0][r] - mn);
                float p1 = __expf(sacc[mi][1][r] - mn);
                float ps = p0 + p1;
#pragma unroll
                for (int d = 1; d < 16; d <<= 1) ps += __shfl_xor(ps, d);
                lrow[mi][r] = lrow[mi][r] * f + ps;
                mrow[mi][r] = mn;
#pragma unroll
                for (int dj = 0; dj < 4; dj++) oacc[mi][dj][r] *= f;
                int row = w * 32 + mi * 16 + quad * 4 + r;
                L.s.Ps[row][l16]      = f2bf(p0);
                L.s.Ps[row][16 + l16] = f2bf(p1);
            }
        __syncthreads();
        s8b ap[2], bv[4];
#pragma unroll
        for (int mi = 0; mi < 2; mi++)
            ap[mi] = *(const s8b*)(&L.s.Ps[w * 32 + mi * 16 + l16][quad * 8]);
#pragma unroll
        for (int dj = 0; dj < 4; dj++)
            bv[dj] = *(const s8b*)(&L.s.Vt[dj * 16 + l16][quad * 8]);
#pragma unroll
        for (int mi = 0; mi < 2; mi++)
#pragma unroll
            for (int dj = 0; dj < 4; dj++)
                oacc[mi][dj] = __builtin_amdgcn_mfma_f32_16x16x32_bf16(ap[mi], bv[dj], oacc[mi][dj], 0, 0, 0);
    }
    __syncthreads();
#pragma unroll
    for (int mi = 0; mi < 2; mi++)
#pragma unroll
        for (int dj = 0; dj < 4; dj++)
#pragma unroll
            for (int r = 0; r < 4; r++)
                L.Os[w * 32 + mi * 16 + quad * 4 + r][dj * 16 + l16] = oacc[mi][dj][r];
    long pbase = (long)(h * 60 + c);
    if (l16 == 0) {
#pragma unroll
        for (int mi = 0; mi < 2; mi++)
#pragma unroll
            for (int r = 0; r < 4; r++) {
                int i = qt * 128 + w * 32 + mi * 16 + quad * 4 + r;
                pml[pbase * 512 + i] = mrow[mi][r];
                pml[pbase * 512 + 256 + i] = lrow[mi][r];
            }
    }
    __syncthreads();
    float* pc = pacc + pbase * 16384 + qt * 128;
    int d = t >> 2, ig = t & 3;
#pragma unroll
    for (int u = 0; u < 8; u++) {
        int i0 = ig * 32 + u * 4;
        float4 v4 = make_float4(L.Os[i0][d], L.Os[i0 + 1][d], L.Os[i0 + 2][d], L.Os[i0 + 3][d]);
        *(float4*)(pc + (long)d * 256 + i0) = v4;
    }
}

// ---------------- fused sim1+softmax+@Bm attention + depthwise res-conv; writes bf16 ohb
__global__ __launch_bounds__(256)
void k_attn1(const ushort* __restrict__ qg, const ushort* __restrict__ klb,
             const ushort* __restrict__ Bmb, const ushort* __restrict__ vg,
             const float* __restrict__ rw, ushort* __restrict__ ohb)
{
    const int m0 = blockIdx.x * 128;
    const int h = blockIdx.y;
    const int t = threadIdx.x;
    const int w = t >> 6, lane = t & 63;
    const int quad = lane >> 4, l16 = lane & 15;

    __shared__ union {
        struct { ushort Vt[64][40]; ushort Ps[128][40]; } s;
        float Os[128][68];
    } L;

    s8b aq[2][2];
    const ushort* qbase = qg + ((long)h * NPQ + 230 + m0 + w * 32) * 64;
#pragma unroll
    for (int mi = 0; mi < 2; mi++)
#pragma unroll
        for (int kf = 0; kf < 2; kf++)
            aq[mi][kf] = *(const s8b*)(qbase + (mi * 16 + l16) * 64 + kf * 32 + quad * 8);

    f4 oacc[2][4] = {};
    float mrow[2][4], lrow[2][4];
#pragma unroll
    for (int mi = 0; mi < 2; mi++)
#pragma unroll
        for (int r = 0; r < 4; r++) { mrow[mi][r] = -INFINITY; lrow[mi][r] = 0.f; }

    const ushort* kh = klb + (long)h * 16384;
    const ushort* vvh = Bmb + (long)h * 16384;

    for (int sub = 0; sub < 8; sub++) {
        int key0 = sub * 32;
        __syncthreads();
        {
            int kk = t >> 3, dc = (t & 7) * 8;
            s8b vv = *(const s8b*)(vvh + (long)(key0 + kk) * 64 + dc);
#pragma unroll
            for (int j = 0; j < 8; j++) L.s.Vt[dc + j][kk] = ((ushort*)&vv)[j];
        }
        s8b bq[2][2];
#pragma unroll
        for (int nj = 0; nj < 2; nj++)
#pragma unroll
            for (int kf = 0; kf < 2; kf++)
                bq[nj][kf] = *(const s8b*)(kh + (long)(key0 + nj * 16 + l16) * 64 + kf * 32 + quad * 8);
        f4 sacc[2][2] = {};
#pragma unroll
        for (int mi = 0; mi < 2; mi++)
#pragma unroll
            for (int nj = 0; nj < 2; nj++) {
                sacc[mi][nj] = __builtin_amdgcn_mfma_f32_16x16x32_bf16(aq[mi][0], bq[nj][0], sacc[mi][nj], 0, 0, 0);
                sacc[mi][nj] = __builtin_amdgcn_mfma_f32_16x16x32_bf16(aq[mi][1], bq[nj][1], sacc[mi][nj], 0, 0, 0);
            }
#pragma unroll
        for (int mi = 0; mi < 2; mi++)
#pragma unroll
            for (int r = 0; r < 4; r++) {
                float mx = fmaxf(sacc[mi][0][r], sacc[mi][1][r]);
#pragma unroll
                for (int d = 1; d < 16; d <<= 1) mx = fmaxf(mx, __shfl_xor(mx, d));
                float mn = fmaxf(mrow[mi][r], mx);
                float f = __expf(mrow[mi][r] - mn);
                float p0 = __expf(sacc[mi][0][r] - mn);
                float p1 = __expf(sacc[mi][1][r] - mn);
                float ps = p0 + p1;
#pragma unroll
                for (int d = 1; d < 16; d <<= 1) ps += __shfl_xor(ps, d);
                lrow[mi][r] = lrow[mi][r] * f + ps;
                mrow[mi][r] = mn;
#pragma unroll
                for (int dj = 0; dj < 4; dj++) oacc[mi][dj][r] *= f;
                int row = w * 32 + mi * 16 + quad * 4 + r;
                L.s.Ps[row][l16]      = f2bf(p0);
                L.s.Ps[row][16 + l16] = f2bf(p1);
            }
        __syncthreads();
        s8b ap[2], bv[4];
#pragma unroll
        for (int mi = 0; mi < 2; mi++)
            ap[mi] = *(const s8b*)(&L.s.Ps[w * 32 + mi * 16 + l16][quad * 8]);
#pragma unroll
        for (int dj = 0; dj < 4; dj++)
            bv[dj] = *(const s8b*)(&L.s.Vt[dj * 16 + l16][quad * 8]);
#pragma unroll
        for (int mi = 0; mi < 2; mi++)
#pragma unroll
            for (int dj = 0; dj < 4; dj++)
                oacc[mi][dj] = __builtin_amdgcn_mfma_f32_16x16x32_bf16(ap[mi], bv[dj], oacc[mi][dj], 0, 0, 0);
    }
    __syncthreads();
    // normalized attn tile -> LDS (C-layout rows owned by this wave)
#pragma unroll
    for (int mi = 0; mi < 2; mi++)
#pragma unroll
        for (int r = 0; r < 4; r++) {
            float inv = 1.f / lrow[mi][r];
#pragma unroll
            for (int dj = 0; dj < 4; dj++)
                L.Os[w * 32 + mi * 16 + quad * 4 + r][dj * 16 + l16] = oacc[mi][dj][r] * inv;
        }
    __syncthreads();
    // conv phase: wave w owns tk strip [m0+w*32, +32), lane = d; register-cached v
    const ushort* vh = vg + (long)h * NPQ * 64;
    int tk0 = m0 + w * 32;
    int base = 214 + tk0;             // 230 + tk0 - 16
    float vr[64];
#pragma unroll
    for (int i = 0; i < 64; i++) {
        int src = base + i;
        vr[i] = (src < NP) ? bf2f(vh[(long)src * 64 + lane]) : 0.f;
    }
    float conv[32];
#pragma unroll
    for (int i = 0; i < 32; i++) conv[i] = 0.f;
#pragma unroll
    for (int kk = 0; kk < 33; kk++) {
        float wk = rw[h * 33 + kk];
#pragma unroll
        for (int i = 0; i < 32; i++) conv[i] = fmaf(wk, vr[i + kk], conv[i]);
    }
#pragma unroll
    for (int i = 0; i < 32; i++) {
        int tk = tk0 + i;
        if (tk < NTOK) {
            float val = L.Os[w * 32 + i][lane] + conv[i];
            ohb[(long)tk * 512 + h * 64 + lane] = f2bf(val);
        }
    }
}

// ---------------- layernorm over 512, writes bf16 xln (first `pad` rows zero)
__global__ __launch_bounds__(256)
void k_layernorm(const float* __restrict__ h, ushort* __restrict__ xln,
                 const float* __restrict__ g, const float* __restrict__ b, int pad)
{
    int row = blockIdx.x, t = threadIdx.x;
    if (row < pad) {
        xln[(long)row * 512 + t] = 0;
        xln[(long)row * 512 + t + 256] = 0;
        return;
    }
    const float* src = h + (long)(row - pad) * 512;
    float x1 = src[t], x2 = src[t + 256];
    float s = x1 + x2, q = x1 * x1 + x2 * x2;
    __shared__ float rs[4], rq[4], st[2];
    int wid = t >> 6, lane = t & 63;
#pragma unroll
    for (int o = 32; o > 0; o >>= 1) { s += __shfl_down(s, o); q += __shfl_down(q, o); }
    if (lane == 0) { rs[wid] = s; rq[wid] = q; }
    __syncthreads();
    if (t == 0) {
        float S = rs[0] + rs[1] + rs[2] + rs[3];
        float Q = rq[0] + rq[1] + rq[2] + rq[3];
        float mean = S / 512.f;
        float var = Q / 512.f - mean * mean;
        st[0] = mean; st[1] = rsqrtf(var + 1e-5f);
    }
    __syncthreads();
    float mean = st[0], rstd = st[1];
    xln[(long)row * 512 + t] = f2bf((x1 - mean) * rstd * g[t] + b[t]);
    xln[(long)row * 512 + t + 256] = f2bf((x2 - mean) * rstd * g[t + 256] + b[t + 256]);
}

__global__ __launch_bounds__(256)
void k_padcls(float* __restrict__ hbuf, const float* __restrict__ cls)
{
    int i = blockIdx.x, t = threadIdx.x;
    if (i == 0) { hbuf[t] = cls[t]; hbuf[t + 256] = cls[t + 256]; }
    else {
        hbuf[(long)(15000 + i) * 512 + t] = hbuf[(long)i * 512 + t];
        hbuf[(long)(15000 + i) * 512 + t + 256] = hbuf[(long)i * 512 + t + 256];
    }
}

__global__ __launch_bounds__(256)
void k_wT(const float* __restrict__ Wm, ushort* __restrict__ Wt, int K, int N, long sW, long sWt)
{
    Wm += (long)blockIdx.z * sW; Wt += (long)blockIdx.z * sWt;
    __shared__ float tile[32][33];
    int tx = threadIdx.x & 31, ty = threadIdx.x >> 5;
    int n0 = blockIdx.x * 32, k0 = blockIdx.y * 32;
#pragma unroll
    for (int u = 0; u < 4; u++) tile[ty + u * 8][tx] = Wm[(long)(k0 + ty + u * 8) * N + n0 + tx];
    __syncthreads();
#pragma unroll
    for (int u = 0; u < 4; u++) Wt[(long)(n0 + ty + u * 8) * K + k0 + tx] = f2bf(tile[tx][ty + u * 8]);
}

__global__ __launch_bounds__(256)
void k_cvt(const float4* __restrict__ src, ushort4* __restrict__ dst, long n4)
{
    long i = (long)blockIdx.x * 256 + threadIdx.x;
    if (i < n4) {
        float4 v = src[i];
        ushort4 o;
        o.x = f2bf(v.x); o.y = f2bf(v.y); o.z = f2bf(v.z); o.w = f2bf(v.w);
        dst[i] = o;
    }
}

__global__ __launch_bounds__(256)
void k_b2f(const ushort4* __restrict__ src, float4* __restrict__ dst, long n4)
{
    long i = (long)blockIdx.x * 256 + threadIdx.x;
    if (i < n4) {
        ushort4 v = src[i];
        dst[i] = make_float4(bf2f(v.x), bf2f(v.y), bf2f(v.z), bf2f(v.w));
    }
}

__global__ __launch_bounds__(64)
void k_landmarks(const ushort* __restrict__ q, const ushort* __restrict__ k,
                 float* __restrict__ ql, ushort* __restrict__ qlb,
                 float* __restrict__ klT, ushort* __restrict__ klb,
                 unsigned* __restrict__ scal)
{
    int i = blockIdx.x, h = blockIdx.y, d = threadIdx.x;
    if (i == 0 && h == 0 && d == 0) { scal[0] = 0u; scal[1] = 0u; }
    long base = ((long)h * NPQ + (long)i * 60) * 64 + d;
    float sq = 0.f, sk = 0.f;
    for (int j = 0; j < 60; j++) { sq += bf2f(q[base + j * 64]); sk += bf2f(k[base + j * 64]); }
    float qv = sq / 60.f, kv = sk / 60.f;
    ql[((long)h * 256 + i) * 64 + d] = qv;
    qlb[((long)h * 256 + i) * 64 + d] = f2bf(qv);
    klT[((long)h * 64 + d) * 256 + i] = kv;
    klb[((long)h * 256 + i) * 64 + d] = f2bf(kv);
}

__global__ __launch_bounds__(256)
void k_softmax256(float* __restrict__ X, ushort* __restrict__ X16, long headStride)
{
    float* row = X + (long)blockIdx.y * headStride + (long)blockIdx.x * 256;
    int t = threadIdx.x, wid = t >> 6, lane = t & 63;
    float x = row[t];
    __shared__ float rm[4], rsum[4], fin[2];
    float m = x;
#pragma unroll
    for (int o = 32; o > 0; o >>= 1) m = fmaxf(m, __shfl_down(m, o));
    if (lane == 0) rm[wid] = m;
    __syncthreads();
    if (t == 0) fin[0] = fmaxf(fmaxf(rm[0], rm[1]), fmaxf(rm[2], rm[3]));
    __syncthreads();
    float e = __expf(x - fin[0]);
    float s = e;
#pragma unroll
    for (int o = 32; o > 0; o >>= 1) s += __shfl_down(s, o);
    if (lane == 0) rsum[wid] = s;
    __syncthreads();
    if (t == 0) fin[1] = rsum[0] + rsum[1] + rsum[2] + rsum[3];
    __syncthreads();
    float v = e / fin[1];
    row[t] = v;
    if (X16) X16[(long)blockIdx.y * headStride + (long)blockIdx.x * 256 + t] = f2bf(v);
}

__global__ __launch_bounds__(256)
void k_colmax(const float* __restrict__ a2, unsigned* __restrict__ scal)
{
    int h = blockIdx.x, t = threadIdx.x, wid = t >> 6, lane = t & 63;
    const float* A = a2 + (long)h * 65536;
    float cs = 0.f, rs = 0.f;
    for (int i = 0; i < 256; i++) cs += A[(long)i * 256 + t];
    for (int j = 0; j < 256; j++) rs += A[(long)t * 256 + j];
    __shared__ float r1[4], r2[4];
    float m1v = cs, m2v = rs;
#pragma unroll
    for (int o = 32; o > 0; o >>= 1) {
        m1v = fmaxf(m1v, __shfl_down(m1v, o));
        m2v = fmaxf(m2v, __shfl_down(m2v, o));
    }
    if (lane == 0) { r1[wid] = m1v; r2[wid] = m2v; }
    __syncthreads();
    if (t == 0) {
        float a = fmaxf(fmaxf(r1[0], r1[1]), fmaxf(r1[2], r1[3]));
        float b = fmaxf(fmaxf(r2[0], r2[1]), fmaxf(r2[2], r2[3]));
        atomicMax(scal + 0, __float_as_uint(a));
        atomicMax(scal + 1, __float_as_uint(b));
    }
}

__global__ __launch_bounds__(256)
void k_zinit(const float* __restrict__ a2, ushort* __restrict__ zb, const unsigned* __restrict__ scal)
{
    float s = 1.f / (__uint_as_float(scal[0]) * __uint_as_float(scal[1]));
    const float* A = a2 + (long)blockIdx.z * 65536;
    ushort* Z = zb + (long)blockIdx.z * 65536;
    __shared__ float tile[32][33];
    int tx = threadIdx.x & 31, ty = threadIdx.x >> 5;
    int i0 = blockIdx.x * 32, j0 = blockIdx.y * 32;
#pragma unroll
    for (int u = 0; u < 4; u++) tile[ty + u * 8][tx] = A[(long)(j0 + ty + u * 8) * 256 + i0 + tx];
    __syncthreads();
#pragma unroll
    for (int u = 0; u < 4; u++) Z[(long)(i0 + ty + u * 8) * 256 + j0 + tx] = f2bf(tile[tx][ty + u * 8] * s);
}

__global__ __launch_bounds__(256)
void k_a3v_merge(const float* __restrict__ pacc, const float* __restrict__ pml,
                 float* __restrict__ t1)
{
    int d = blockIdx.x, h = blockIdx.y, i = threadIdx.x;
    float M = -INFINITY, L = 0.f, num = 0.f;
    for (int c = 0; c < 60; c++) {
        float mc = pml[(long)(h * 60 + c) * 2 * 256 + i];
        float lc = pml[((long)(h * 60 + c) * 2 + 1) * 256 + i];
        float ac = pacc[((long)(h * 60 + c) * 64 + d) * 256 + i];
        if (mc > M) {
            float f = __expf(M - mc);
            num = num * f + ac; L = L * f + lc; M = mc;
        } else {
            float p = __expf(mc - M);
            num = fmaf(p, ac, num); L = fmaf(p, lc, L);
        }
    }
    t1[((long)h * 256 + i) * 64 + d] = num / L;
}

__global__ __launch_bounds__(256)
void k_cls(const ushort* __restrict__ qb, const float* __restrict__ klT,
           const float* __restrict__ Bm, const ushort* __restrict__ vb,
           const float* __restrict__ rw, float* __restrict__ oh)
{
    int h = blockIdx.x, t = threadIdx.x, wid = t >> 6, lane = t & 63;
    __shared__ float qs[64], p[256], red[256];
    __shared__ float rm[4], rsum[4], fin[2];
    if (t < 64) qs[t] = bf2f(qb[((long)h * NPQ + 230) * 64 + t]);
    __syncthreads();
    float s = 0.f;
    for (int d = 0; d < 64; d++) s = fmaf(qs[d], klT[((long)h * 64 + d) * 256 + t], s);
    float m = s;
#pragma unroll
    for (int o = 32; o > 0; o >>= 1) m = fmaxf(m, __shfl_down(m, o));
    if (lane == 0) rm[wid] = m;
    __syncthreads();
    if (t == 0) fin[0] = fmaxf(fmaxf(rm[0], rm[1]), fmaxf(rm[2], rm[3]));
    __syncthreads();
    float e = __expf(s - fin[0]);
    float ss = e;
#pragma unroll
    for (int o = 32; o > 0; o >>= 1) ss += __shfl_down(ss, o);
    if (lane == 0) rsum[wid] = ss;
    __syncthreads();
    if (t == 0) fin[1] = rsum[0] + rsum[1] + rsum[2] + rsum[3];
    __syncthreads();
    p[t] = e / fin[1];
    __syncthreads();
    int d = t & 63, grp = t >> 6;
    float o = 0.f;
    for (int j = grp * 64; j < grp * 64 + 64; j++) o = fmaf(p[j], Bm[((long)h * 256 + j) * 64 + d], o);
    red[t] = o;
    __syncthreads();
    if (t < 64) {
        float val = red[t] + red[t + 64] + red[t + 128] + red[t + 192];
#pragma unroll
        for (int kk = 0; kk < 33; kk++)
            val = fmaf(rw[h * 33 + kk], bf2f(vb[((long)h * NPQ + 214 + kk) * 64 + t]), val);
        oh[h * 64 + t] = val;
    }
}

__global__ __launch_bounds__(256)
void k_copy4(const float4* __restrict__ src, float4* __restrict__ dst, long n4)
{
    long i = (long)blockIdx.x * 256 + threadIdx.x;
    if (i < n4) dst[i] = src[i];
}

// ---------------- combine w7+w5+w3+identity into wc[49][512], bc = b7+b5+b3
__global__ __launch_bounds__(512)
void k_wcomb(const float* __restrict__ w7, const float* __restrict__ b7,
             const float* __restrict__ w5, const float* __restrict__ b5,
             const float* __restrict__ w3, const float* __restrict__ b3,
             float* __restrict__ wc, float* __restrict__ bc)
{
    int k = blockIdx.x, c = threadIdx.x;
    int kr = k / 7, kc = k % 7;
    float v = w7[c * 49 + k];
    if (kr >= 1 && kr <= 5 && kc >= 1 && kc <= 5) v += w5[c * 25 + (kr - 1) * 5 + (kc - 1)];
    if (kr >= 2 && kr <= 4 && kc >= 2 && kc <= 4) v += w3[c * 9 + (kr - 2) * 3 + (kc - 2)];
    if (k == 24) v += 1.f;
    wc[k * 512 + c] = v;
    if (k == 0) bc[c] = b7[c] + b5[c] + b3[c];
}

// ---------------- PPEG v2: single 7x7 combined depthwise; bf16 LDS tile
__global__ __launch_bounds__(256)
void k_ppeg2(const float* __restrict__ cnn, float* __restrict__ hbuf,
             const float* __restrict__ wc, const float* __restrict__ bc)
{
    __shared__ ushort tile[140][64];
    int t = threadIdx.x;
    int cp = t & 31;
    int g = t >> 5;
    int c0 = blockIdx.x * 8, r0 = blockIdx.y * 4, cb = blockIdx.z * 64;
    for (int idx = t; idx < 140 * 32; idx += 256) {
        int pos = idx >> 5, pp = idx & 31;
        int pr = pos / 14, pc = pos % 14;
        int gr = r0 + pr - 3, gc = c0 + pc - 3;
        float v0 = 0.f, v1 = 0.f;
        if (gr >= 0 && gr < HG && gc >= 0 && gc < HG) {
            const float* src = cnn + (long)(gr * HG + gc) * 512 + cb + pp * 2;
            v0 = src[0]; v1 = src[1];
        }
        tile[pos][pp * 2] = f2bf(v0);
        tile[pos][pp * 2 + 1] = f2bf(v1);
    }
    __syncthreads();
    float acc[4][2] = {};
    for (int kr = 0; kr < 7; kr++)
#pragma unroll
        for (int kc = 0; kc < 7; kc++) {
            float w0 = wc[(kr * 7 + kc) * 512 + cb + cp * 2];
            float w1 = wc[(kr * 7 + kc) * 512 + cb + cp * 2 + 1];
#pragma unroll
            for (int u = 0; u < 4; u++) {
                int p = g * 4 + u;
                int orow = p >> 3, ocol = p & 7;
                unsigned pk = *(const unsigned*)&tile[(orow + kr) * 14 + (ocol + kc)][cp * 2];
                acc[u][0] = fmaf(w0, bf2f((ushort)pk), acc[u][0]);
                acc[u][1] = fmaf(w1, bf2f((ushort)(pk >> 16)), acc[u][1]);
            }
        }
    float b0 = bc[cb + cp * 2], b1 = bc[cb + cp * 2 + 1];
#pragma unroll
    for (int u = 0; u < 4; u++) {
        int p = g * 4 + u;
        int orow = p >> 3, ocol = p & 7;
        int gr = r0 + orow, gc = c0 + ocol;
        if (gr < HG && gc < HG) {
            float* dst = hbuf + (long)(1 + gr * HG + gc) * 512 + cb + cp * 2;
            dst[0] = acc[u][0] + b0;
            dst[1] = acc[u][1] + b1;
        }
    }
}

__global__ __launch_bounds__(256)
void k_final(const float* __restrict__ hbuf, const float* __restrict__ g,
             const float* __restrict__ b, const float* __restrict__ W2,
             const float* __restrict__ b2, float* __restrict__ out)
{
    __shared__ float y[512];
    __shared__ float rs[4], rq[4], st[2], lg[8];
    int t = threadIdx.x, wid = t >> 6, lane = t & 63;
    float x1 = hbuf[t], x2 = hbuf[t + 256];
    float s = x1 + x2, q = x1 * x1 + x2 * x2;
#pragma unroll
    for (int o = 32; o > 0; o >>= 1) { s += __shfl_down(s, o); q += __shfl_down(q, o); }
    if (lane == 0) { rs[wid] = s; rq[wid] = q; }
    __syncthreads();
    if (t == 0) {
        float S = rs[0] + rs[1] + rs[2] + rs[3];
        float Q = rq[0] + rq[1] + rq[2] + rq[3];
        float mean = S / 512.f;
        float var = Q / 512.f - mean * mean;
        st[0] = mean; st[1] = rsqrtf(var + 1e-5f);
    }
    __syncthreads();
    float mean = st[0], rstd = st[1];
    y[t] = (x1 - mean) * rstd * g[t] + b[t];
    y[t + 256] = (x2 - mean) * rstd * g[t + 256] + b[t + 256];
    __syncthreads();
    if (t < 5) {
        float acc = b2[t];
        for (int kx = 0; kx < 512; kx++) acc = fmaf(y[kx], W2[kx * 5 + t], acc);
        lg[t] = acc;
    }
    __syncthreads();
    if (t == 0) {
        float mx = lg[0]; int am = 0;
        for (int j = 1; j < 5; j++) if (lg[j] > mx) { mx = lg[j]; am = j; }
        float e[5], se = 0.f;
        for (int j = 0; j < 5; j++) { e[j] = __expf(lg[j] - mx); se += e[j]; }
        for (int j = 0; j < 5; j++) { out[j] = lg[j]; out[5 + j] = e[j] / se; }
        out[10] = (float)am;
    }
}

extern "C" void kernel_launch(void* const* d_in, const int* in_sizes, int n_in,
                              void* d_out, int out_size, void* d_ws, size_t ws_size,
                              hipStream_t stream)
{
    const float* data  = (const float*)d_in[0];
    const float* Wfc1  = (const float*)d_in[1];
    const float* bfc1  = (const float*)d_in[2];
    const float* cls   = (const float*)d_in[3];
    const float* ln1g  = (const float*)d_in[4];
    const float* ln1b  = (const float*)d_in[5];
    const float* qkv1  = (const float*)d_in[6];
    const float* out1w = (const float*)d_in[7];
    const float* out1b = (const float*)d_in[8];
    const float* res1  = (const float*)d_in[9];
    const float* w7    = (const float*)d_in[10];
    const float* b7    = (const float*)d_in[11];
    const float* w5    = (const float*)d_in[12];
    const float* b5    = (const float*)d_in[13];
    const float* w3    = (const float*)d_in[14];
    const float* b3    = (const float*)d_in[15];
    const float* ln2g  = (const float*)d_in[16];
    const float* ln2b  = (const float*)d_in[17];
    const float* qkv2  = (const float*)d_in[18];
    const float* out2w = (const float*)d_in[19];
    const float* out2b = (const float*)d_in[20];
    const float* res2  = (const float*)d_in[21];
    const float* normg = (const float*)d_in[22];
    const float* normb = (const float*)d_in[23];
    const float* Wfc2  = (const float*)d_in[24];
    const float* bfc2  = (const float*)d_in[25];
    float* out = (float*)d_out;

    float* W = (float*)d_ws;
    size_t off = 0;
    auto alloc = [&](size_t n) { size_t o = off; off += (n + 255) & ~(size_t)255; return o; };
    float*  hbuf   = W + alloc((size_t)NTOK * 512);
    float*  ohreg  = W + alloc((size_t)15232 * 512);
    float*  oh     = ohreg;
    ushort* xln    = (ushort*)ohreg;
    ushort* qb16   = (ushort*)(W + alloc((size_t)8 * NPQ * 32));
    ushort* kb16   = (ushort*)(W + alloc((size_t)8 * NPQ * 32));
    ushort* vb16   = (ushort*)(W + alloc((size_t)8 * NPQ * 32));
    float*  ql     = W + alloc(8 * 256 * 64);
    ushort* qlb    = (ushort*)(W + alloc(8 * 256 * 32));
    float*  klT    = W + alloc(8 * 64 * 256);
    ushort* klb    = (ushort*)(W + alloc(8 * 256 * 32));
    float*  a2     = W + alloc(8 * 65536);
    ushort* a2b    = (ushort*)(W + alloc(8 * 32768));
    ushort* zb0    = (ushort*)(W + alloc(8 * 32768));
    ushort* zb1    = (ushort*)(W + alloc(8 * 32768));
    ushort* m1b    = (ushort*)(W + alloc(8 * 32768));
    ushort* mab    = (ushort*)(W + alloc(8 * 32768));
    ushort* mbb    = (ushort*)(W + alloc(8 * 32768));
    float*  z0     = W + alloc(8 * 65536);
    float*  z1     = W + alloc(8 * 65536);
    float*  m1     = W + alloc(8 * 65536);
    float*  ma     = W + alloc(8 * 65536);
    float*  mb     = W + alloc(8 * 65536);
    float*  t1     = W + alloc(8 * 256 * 64);
    float*  Bm     = W + alloc(8 * 256 * 64);
    ushort* Bmb    = (ushort*)(W + alloc(8 * 256 * 32));
    float*  scal   = W + alloc(64);
    ushort* ohb16  = (ushort*)(W + alloc((size_t)15232 * 256));
    ushort* WfcT   = (ushort*)(W + alloc(1024 * 256));
    ushort* qkv1T  = (ushort*)(W + alloc(1536 * 256));
    ushort* qkv2T  = (ushort*)(W + alloc(1536 * 256));
    ushort* out1T  = (ushort*)(W + alloc(512 * 256));
    ushort* out2T  = (ushort*)(W + alloc(512 * 256));
    float*  wc     = W + alloc(49 * 512);
    float*  bc     = W + alloc(512);
    float*  big    = W + alloc(8110080);   // datab | pacc+pml | ppeg cnn
    ushort* datab  = (ushort*)big;
    float*  pacc   = big;
    float*  pml    = big + 7864320;
    float*  cnn    = big;
    if (ws_size < off * sizeof(float)) return;

    k_wT<<<dim3(16, 32, 1), 256, 0, stream>>>(Wfc1, WfcT, 1024, 512, 0, 0);
    k_wT<<<dim3(48, 16, 1), 256, 0, stream>>>(qkv1, qkv1T, 512, 1536, 0, 0);
    k_wT<<<dim3(48, 16, 1), 256, 0, stream>>>(qkv2, qkv2T, 512, 1536, 0, 0);
    k_wT<<<dim3(16, 16, 1), 256, 0, stream>>>(out1w, out1T, 512, 512, 0, 0);
    k_wT<<<dim3(16, 16, 1), 256, 0, stream>>>(out2w, out2T, 512, 512, 0, 0);
    k_wcomb<<<49, 512, 0, stream>>>(w7, b7, w5, b5, w3, b3, wc, bc);
    k_cvt<<<15000, 256, 0, stream>>>((const float4*)data, (ushort4*)datab, 3840000);
    gemm_mfma<4, 4, 2, 2><<<dim3(4, 118, 1), 256, 0, stream>>>(
        datab, 1024, 0, WfcT, 1024, 0, hbuf + 512, 512, 0, 15000, 1024, bfc1, 1, 0);
    k_padcls<<<130, 256, 0, stream>>>(hbuf, cls);

    auto layer = [&](const float* lng, const float* lnb, const ushort* qkvT,
                     const float* outW, const ushort* outT, const float* outB,
                     const float* resW, bool full) {
        k_layernorm<<<NP, 256, 0, stream>>>(hbuf, xln, lng, lnb, 230);
        gemm_qkv_mfma<<<dim3(12, 120, 1), 256, 0, stream>>>(xln, qkvT, qb16, kb16, vb16);
        k_landmarks<<<dim3(256, 8), 64, 0, stream>>>(qb16, kb16, ql, qlb, klT, klb, (unsigned*)scal);
        gemm_f32<<<dim3(4, 4, 8), 256, 0, stream>>>(ql, 64, 16384, klT, 256, 16384,
            a2, 256, 65536, 256, 256, 64, nullptr, nullptr, 0, 0, 0.f, 1.f, 0, 0);
        k_softmax256<<<dim3(256, 8), 256, 0, stream>>>(a2, a2b, 65536);
        k_colmax<<<8, 256, 0, stream>>>(a2, (unsigned*)scal);
        k_zinit<<<dim3(8, 8, 8), 256, 0, stream>>>(a2, zb0, (const unsigned*)scal);
        // pinv iters 0-4 in bf16 MFMA
        ushort* zbi = zb0; ushort* zbo = zb1;
        for (int it = 0; it < 5; ++it) {
            gemm_nn16<<<dim3(4, 4, 8), 256, 0, stream>>>(a2b, zbi, nullptr, m1b, 256, 256, 1.f, 0.f, 65536);
            gemm_nn16<<<dim3(4, 4, 8), 256, 0, stream>>>(m1b, m1b, m1b, mab, 256, 256, -1.f, 7.f, 65536);
            gemm_nn16<<<dim3(4, 4, 8), 256, 0, stream>>>(m1b, mab, m1b, mbb, 256, 256, -1.f, 15.f, 65536);
            gemm_nn16<<<dim3(4, 4, 8), 256, 0, stream>>>(zbi, mbb, zbi, zbo, 256, 256, -0.25f, 3.25f, 65536);
            ushort* tmp = zbi; zbi = zbo; zbo = tmp;
        }
        k_b2f<<<512, 256, 0, stream>>>((const ushort4*)zbi, (float4*)z0, 131072);
        // final pinv iter in fp32
        float* zi = z0; float* zo = z1;
        {
            gemm_f32<<<dim3(4, 4, 8), 256, 0, stream>>>(a2, 256, 65536, zi, 256, 65536,
                m1, 256, 65536, 256, 256, 256, nullptr, nullptr, 0, 0, 0.f, 1.f, 0, 0);
            gemm_f32<<<dim3(4, 4, 8), 256, 0, stream>>>(m1, 256, 65536, m1, 256, 65536,
                ma, 256, 65536, 256, 256, 256, nullptr, m1, 256, 65536, 7.f, -1.f, 0, 0);
            gemm_f32<<<dim3(4, 4, 8), 256, 0, stream>>>(m1, 256, 65536, ma, 256, 65536,
                mb, 256, 65536, 256, 256, 256, nullptr, m1, 256, 65536, 15.f, -1.f, 0, 0);
            gemm_f32<<<dim3(4, 4, 8), 256, 0, stream>>>(zi, 256, 65536, mb, 256, 65536,
                zo, 256, 65536, 256, 256, 256, nullptr, zi, 256, 65536, 3.25f, -0.25f, 0, 0);
            float* tmp = zi; zi = zo; zo = tmp;
        }
        k_flash_a3v<<<dim3(60, 2, 8), 256, 0, stream>>>(qlb, kb16, vb16, pacc, pml);
        k_a3v_merge<<<dim3(64, 8), 256, 0, stream>>>(pacc, pml, t1);
        gemm_f32<<<dim3(1, 4, 8), 256, 0, stream>>>(zi, 256, 65536, t1, 64, 16384,
            Bm, 64, 16384, 256, 64, 256, nullptr, nullptr, 0, 0, 0.f, 1.f, 0, 0);
        if (full) {
            k_cvt<<<128, 256, 0, stream>>>((const float4*)Bm, (ushort4*)Bmb, 32768);
            k_attn1<<<dim3(119, 8), 256, 0, stream>>>(qb16, klb, Bmb, vb16, resW, ohb16);
            gemm_mfma<4, 4, 2, 2><<<dim3(4, 119, 1), 256, 0, stream>>>(
                ohb16, 512, 0, outT, 512, 0, hbuf, 512, 0, NTOK, 512, outB, 0, 1);
        } else {
            k_cls<<<8, 256, 0, stream>>>(qb16, klT, Bm, vb16, resW, oh);
            gemm_f32<<<dim3(8, 1, 1), 256, 0, stream>>>(oh, 512, 0, outW, 512, 0,
                hbuf, 512, 0, 1, 512, 512, outB, nullptr, 0, 0, 0.f, 1.f, 0, 1);
        }
    };

    layer(ln1g, ln1b, qkv1T, out1w, out1T, out1b, res1, true);
    k_copy4<<<(1936512 + 255) / 256, 256, 0, stream>>>((const float4*)(hbuf + 512), (float4*)cnn, 1936512);
    k_ppeg2<<<dim3(16, 31, 8), 256, 0, stream>>>(cnn, hbuf, wc, bc);
    layer(ln2g, ln2b, qkv2T, out2w, out2T, out2b, res2, false);
    k_final<<<1, 256, 0, stream>>>(hbuf, normg, normb, Wfc2, bfc2, out);
}

// Round 6
// 1454.302 us; speedup vs baseline: 2.3304x; 1.0085x over previous
//
#include <hip/hip_runtime.h>
#include <math.h>

#define NP 15360
#define NPQ 15488
#define NTOK 15130
#define HG 123

typedef __attribute__((ext_vector_type(8))) short s8b;
typedef __attribute__((ext_vector_type(4))) float f4;

__device__ inline float bf2f(ushort u) { return __uint_as_float(((unsigned)u) << 16); }
__device__ inline ushort f2bf(float f) {
    unsigned u = __float_as_uint(f);
    unsigned r = (u + 0x7fffu + ((u >> 16) & 1u)) >> 16;
    return (ushort)r;
}

// ---------------- generic fp32 GEMM (small/sensitive ops): C = cS*(A@B) + eS*E + bias
__global__ __launch_bounds__(256)
void gemm_f32(const float* __restrict__ A, int lda, long sA,
              const float* __restrict__ B, int ldb, long sB,
              float* __restrict__ C, int ldc, long sC,
              int M, int N, int K,
              const float* __restrict__ bias,
              const float* __restrict__ E, int ldE, long sE, float eS,
              float cS, int relu, int accum)
{
    A += (long)blockIdx.z * sA;
    B += (long)blockIdx.z * sB;
    C += (long)blockIdx.z * sC;
    if (E) E += (long)blockIdx.z * sE;
    const int m0 = blockIdx.y * 64, n0 = blockIdx.x * 64;
    const int t = threadIdx.x;
    const int tx = t & 15, ty = t >> 4;
    __shared__ float As[16][64];
    __shared__ float Bs[16][64];
    float acc[4][4] = {};
    const int arow = t >> 2, akc = (t & 3) * 4;
    const int brow = t >> 4, bnc = (t & 15) * 4;
    for (int k0 = 0; k0 < K; k0 += 16) {
        float4 av = make_float4(0.f, 0.f, 0.f, 0.f);
        if (m0 + arow < M) av = *(const float4*)(A + (long)(m0 + arow) * lda + k0 + akc);
        As[akc + 0][arow] = av.x; As[akc + 1][arow] = av.y;
        As[akc + 2][arow] = av.z; As[akc + 3][arow] = av.w;
        float4 bv = *(const float4*)(B + (long)(k0 + brow) * ldb + n0 + bnc);
        *(float4*)&Bs[brow][bnc] = bv;
        __syncthreads();
#pragma unroll
        for (int kk = 0; kk < 16; ++kk) {
            float4 a4 = *(const float4*)&As[kk][ty * 4];
            float4 b4 = *(const float4*)&Bs[kk][tx * 4];
            float a[4] = {a4.x, a4.y, a4.z, a4.w};
            float b[4] = {b4.x, b4.y, b4.z, b4.w};
#pragma unroll
            for (int i = 0; i < 4; i++)
#pragma unroll
                for (int j = 0; j < 4; j++) acc[i][j] = fmaf(a[i], b[j], acc[i][j]);
        }
        __syncthreads();
    }
#pragma unroll
    for (int i = 0; i < 4; i++) {
        int m = m0 + ty * 4 + i;
        if (m < M) {
#pragma unroll
            for (int j = 0; j < 4; j++) {
                int n = n0 + tx * 4 + j;
                float v = cS * acc[i][j];
                if (E) v = fmaf(eS, E[(long)m * ldE + n], v);
                if (bias) v += bias[n];
                if (relu) v = fmaxf(v, 0.f);
                if (accum) C[(long)m * ldc + n] += v;
                else C[(long)m * ldc + n] = v;
            }
        }
    }
}

// ---------------- bf16 MFMA GEMM: C(fp32) = A(bf16,[M][K]) @ Bt(bf16,[N][K])^T
template<int MT, int NT, int WROWS, int WCOLS>
__global__ __launch_bounds__(256)
void gemm_mfma(const ushort* __restrict__ A, int lda, long sA,
               const ushort* __restrict__ Bt, int ldb, long sB,
               float* __restrict__ C, int ldc, long sC,
               int M, int K,
               const float* __restrict__ bias, int relu, int accum)
{
    constexpr int TM = MT * 16 * WROWS;
    constexpr int TN = NT * 16 * WCOLS;
    constexpr int BKP = 40;
    __shared__ ushort As[TM * BKP];
    __shared__ ushort Bs[TN * BKP];
    A  += (long)blockIdx.z * sA;
    Bt += (long)blockIdx.z * sB;
    C  += (long)blockIdx.z * sC;
    const int t = threadIdx.x;
    const int m0 = blockIdx.y * TM, n0 = blockIdx.x * TN;
    const int w = t >> 6, l = t & 63;
    const int wm = (w / WCOLS) * (MT * 16), wn = (w % WCOLS) * (NT * 16);
    const int lr = l & 15;
    const int lk = (l >> 4) * 8;
    f4 acc[MT][NT] = {};
    for (int k0 = 0; k0 < K; k0 += 32) {
        for (int c = t; c < TM * 4; c += 256) {
            int row = c >> 2, kc = (c & 3) * 8;
            s8b v = *(const s8b*)(A + (long)(m0 + row) * lda + k0 + kc);
            *(s8b*)(&As[row * BKP + kc]) = v;
        }
        for (int c = t; c < TN * 4; c += 256) {
            int row = c >> 2, kc = (c & 3) * 8;
            s8b v = *(const s8b*)(Bt + (long)(n0 + row) * ldb + k0 + kc);
            *(s8b*)(&Bs[row * BKP + kc]) = v;
        }
        __syncthreads();
        s8b af[MT], bf[NT];
#pragma unroll
        for (int i = 0; i < MT; i++) af[i] = *(const s8b*)(&As[(wm + i * 16 + lr) * BKP + lk]);
#pragma unroll
        for (int j = 0; j < NT; j++) bf[j] = *(const s8b*)(&Bs[(wn + j * 16 + lr) * BKP + lk]);
#pragma unroll
        for (int i = 0; i < MT; i++)
#pragma unroll
            for (int j = 0; j < NT; j++)
                acc[i][j] = __builtin_amdgcn_mfma_f32_16x16x32_bf16(af[i], bf[j], acc[i][j], 0, 0, 0);
        __syncthreads();
    }
    const int orow = (l >> 4) * 4;
#pragma unroll
    for (int i = 0; i < MT; i++) {
#pragma unroll
        for (int r = 0; r < 4; r++) {
            int m = m0 + wm + i * 16 + orow + r;
            if (m < M) {
#pragma unroll
                for (int j = 0; j < NT; j++) {
                    int n = n0 + wn + j * 16 + lr;
                    float vv = acc[i][j][r];
                    if (bias) vv += bias[n];
                    if (relu) vv = fmaxf(vv, 0.f);
                    if (accum) C[(long)m * ldc + n] += vv;
                    else C[(long)m * ldc + n] = vv;
                }
            }
        }
    }
}

// ---------------- bf16-in/bf16-out MFMA GEMM, B row-major [K][N]: C16 = bf16(cS*(A@B) + eS*E16)
__global__ __launch_bounds__(256)
void gemm_nn16(const ushort* __restrict__ A, const ushort* __restrict__ B,
               const ushort* __restrict__ E, ushort* __restrict__ C,
               int N, int K, float cS, float eS, long sAB)
{
    __shared__ ushort As[64 * 40];
    __shared__ ushort Bs[64 * 40];
    A += (long)blockIdx.z * sAB;
    B += (long)blockIdx.z * sAB;
    if (E) E += (long)blockIdx.z * sAB;
    C += (long)blockIdx.z * sAB;
    const int t = threadIdx.x;
    const int m0 = blockIdx.y * 64, n0 = blockIdx.x * 64;
    const int w = t >> 6, l = t & 63;
    const int wm = (w >> 1) * 32, wn = (w & 1) * 32;
    const int lr = l & 15, lk = (l >> 4) * 8;
    f4 acc[2][2] = {};
    for (int k0 = 0; k0 < K; k0 += 32) {
        {
            int row = t >> 2, kc = (t & 3) * 8;
            s8b v = *(const s8b*)(A + (long)(m0 + row) * K + k0 + kc);
            *(s8b*)(&As[row * 40 + kc]) = v;
            int kk = t >> 3, nc = (t & 7) * 8;
            s8b vb = *(const s8b*)(B + (long)(k0 + kk) * N + n0 + nc);
#pragma unroll
            for (int j = 0; j < 8; j++) Bs[(nc + j) * 40 + kk] = ((ushort*)&vb)[j];
        }
        __syncthreads();
        s8b af[2], bf[2];
#pragma unroll
        for (int i = 0; i < 2; i++) af[i] = *(const s8b*)(&As[(wm + i * 16 + lr) * 40 + lk]);
#pragma unroll
        for (int j = 0; j < 2; j++) bf[j] = *(const s8b*)(&Bs[(wn + j * 16 + lr) * 40 + lk]);
#pragma unroll
        for (int i = 0; i < 2; i++)
#pragma unroll
            for (int j = 0; j < 2; j++)
                acc[i][j] = __builtin_amdgcn_mfma_f32_16x16x32_bf16(af[i], bf[j], acc[i][j], 0, 0, 0);
        __syncthreads();
    }
    const int orow = (l >> 4) * 4;
#pragma unroll
    for (int i = 0; i < 2; i++)
#pragma unroll
        for (int r = 0; r < 4; r++) {
            int m = m0 + wm + i * 16 + orow + r;
#pragma unroll
            for (int j = 0; j < 2; j++) {
                int n = n0 + wn + j * 16 + lr;
                float vv = cS * acc[i][j][r];
                if (E) vv = fmaf(eS, bf2f(E[(long)m * N + n]), vv);
                C[(long)m * N + n] = f2bf(vv);
            }
        }
}

// ---------------- qkv MFMA GEMM, scatter into bf16 q/k/v [head][NPQ][64], q scaled 1/8
__global__ __launch_bounds__(256)
void gemm_qkv_mfma(const ushort* __restrict__ A, const ushort* __restrict__ Bt,
                   ushort* __restrict__ qo, ushort* __restrict__ ko, ushort* __restrict__ vo)
{
    constexpr int BKP = 40;
    __shared__ ushort As[128 * BKP];
    __shared__ ushort Bs[128 * BKP];
    const int t = threadIdx.x;
    const int m0 = blockIdx.y * 128, n0 = blockIdx.x * 128;
    const int w = t >> 6, l = t & 63;
    const int wm = (w >> 1) * 64, wn = (w & 1) * 64;
    const int lr = l & 15;
    const int lk = (l >> 4) * 8;
    f4 acc[4][4] = {};
    for (int k0 = 0; k0 < 512; k0 += 32) {
        for (int c = t; c < 512; c += 256) {
            int row = c >> 2, kc = (c & 3) * 8;
            s8b va = *(const s8b*)(A + (long)(m0 + row) * 512 + k0 + kc);
            *(s8b*)(&As[row * BKP + kc]) = va;
            s8b vb = *(const s8b*)(Bt + (long)(n0 + row) * 512 + k0 + kc);
            *(s8b*)(&Bs[row * BKP + kc]) = vb;
        }
        __syncthreads();
        s8b af[4], bf[4];
#pragma unroll
        for (int i = 0; i < 4; i++) af[i] = *(const s8b*)(&As[(wm + i * 16 + lr) * BKP + lk]);
#pragma unroll
        for (int j = 0; j < 4; j++) bf[j] = *(const s8b*)(&Bs[(wn + j * 16 + lr) * BKP + lk]);
#pragma unroll
        for (int i = 0; i < 4; i++)
#pragma unroll
            for (int j = 0; j < 4; j++)
                acc[i][j] = __builtin_amdgcn_mfma_f32_16x16x32_bf16(af[i], bf[j], acc[i][j], 0, 0, 0);
        __syncthreads();
    }
    const int orow = (l >> 4) * 4;
#pragma unroll
    for (int i = 0; i < 4; i++) {
#pragma unroll
        for (int r = 0; r < 4; r++) {
            int m = m0 + wm + i * 16 + orow + r;
#pragma unroll
            for (int j = 0; j < 4; j++) {
                int col = n0 + wn + j * 16 + lr;
                int which = col >> 9, h = (col >> 6) & 7, d = col & 63;
                float vv = acc[i][j][r];
                if (which == 0) vv *= 0.125f;
                ushort* dst = which == 0 ? qo : (which == 1 ? ko : vo);
                dst[((long)h * NPQ + m) * 64 + d] = f2bf(vv);
            }
        }
    }
}

// ---------------- flash a3@v with rotation-swizzled Vt (kills 16-way staging conflicts)
__global__ __launch_bounds__(256)
void k_flash_a3v(const ushort* __restrict__ qlb, const ushort* __restrict__ kg,
                 const ushort* __restrict__ vg,
                 float* __restrict__ pacc, float* __restrict__ pml)
{
    const int c = blockIdx.x;
    const int qt = blockIdx.y;
    const int h = blockIdx.z;
    const int t = threadIdx.x;
    const int w = t >> 6, lane = t & 63;
    const int quad = lane >> 4, l16 = lane & 15;

    __shared__ union {
        struct { ushort Vt[64][40]; ushort Ps[128][40]; } s;
        float Os[128][68];
    } L;

    s8b aq[2][2];
    const ushort* qbase = qlb + ((long)h * 256 + qt * 128 + w * 32) * 64;
#pragma unroll
    for (int mi = 0; mi < 2; mi++)
#pragma unroll
        for (int kf = 0; kf < 2; kf++)
            aq[mi][kf] = *(const s8b*)(qbase + (mi * 16 + l16) * 64 + kf * 32 + quad * 8);

    f4 oacc[2][4] = {};
    float mrow[2][4], lrow[2][4];
#pragma unroll
    for (int mi = 0; mi < 2; mi++)
#pragma unroll
        for (int r = 0; r < 4; r++) { mrow[mi][r] = -INFINITY; lrow[mi][r] = 0.f; }

    const ushort* kh = kg + (long)h * NPQ * 64;
    const ushort* vh = vg + (long)h * NPQ * 64;
    const int key0c = c * 256;

    for (int sub = 0; sub < 8; sub++) {
        int key0 = key0c + sub * 32;
        __syncthreads();
        {   // swizzled V^T stage: col' = (key + ((d>>3)&3)*8) & 31  -> 4-way max
            int kk = t >> 3 & 31;
            int dc = (t & 7) * 8;
            s8b vv = *(const s8b*)(vh + (long)(key0 + kk) * 64 + dc);
            int rot = (dc >> 3) & 3;
            int colp = (kk + rot * 8) & 31;
#pragma unroll
            for (int j = 0; j < 8; j++) L.s.Vt[dc + j][colp] = ((ushort*)&vv)[j];
        }
        s8b bq[2][2];
#pragma unroll
        for (int nj = 0; nj < 2; nj++)
#pragma unroll
            for (int kf = 0; kf < 2; kf++)
                bq[nj][kf] = *(const s8b*)(kh + (long)(key0 + nj * 16 + l16) * 64 + kf * 32 + quad * 8);
        f4 sacc[2][2] = {};
#pragma unroll
        for (int mi = 0; mi < 2; mi++)
#pragma unroll
            for (int nj = 0; nj < 2; nj++) {
                sacc[mi][nj] = __builtin_amdgcn_mfma_f32_16x16x32_bf16(aq[mi][0], bq[nj][0], sacc[mi][nj], 0, 0, 0);
                sacc[mi][nj] = __builtin_amdgcn_mfma_f32_16x16x32_bf16(aq[mi][1], bq[nj][1], sacc[mi][nj], 0, 0, 0);
            }
#pragma unroll
        for (int mi = 0; mi < 2; mi++)
#pragma unroll
            for (int r = 0; r < 4; r++) {
                float mx = fmaxf(sacc[mi][0][r], sacc[mi][1][r]);
#pragma unroll
                for (int d = 1; d < 16; d <<= 1) mx = fmaxf(mx, __shfl_xor(mx, d));
                float mn = fmaxf(mrow[mi][r], mx);
                float f = __expf(mrow[mi][r] - mn);
                float p0 = __expf(sacc[mi][0][r] - mn);
                float p1 = __expf(sacc[mi][1][r] - mn);
                float ps = p0 + p1;
#pragma unroll
                for (int d = 1; d < 16; d <<= 1) ps += __shfl_xor(ps, d);
                lrow[mi][r] = lrow[mi][r] * f + ps;
                mrow[mi][r] = mn;
#pragma unroll
                for (int dj = 0; dj < 4; dj++) oacc[mi][dj][r] *= f;
                int row = w * 32 + mi * 16 + quad * 4 + r;
                L.s.Ps[row][l16]      = f2bf(p0);
                L.s.Ps[row][16 + l16] = f2bf(p1);
            }
        __syncthreads();
        s8b ap[2], bv[4];
#pragma unroll
        for (int mi = 0; mi < 2; mi++)
            ap[mi] = *(const s8b*)(&L.s.Ps[w * 32 + mi * 16 + l16][quad * 8]);
#pragma unroll
        for (int dj = 0; dj < 4; dj++) {
            int d = dj * 16 + l16;
            int rot = (d >> 3) & 3;
            int cb = ((quad + rot) & 3) * 8;
            bv[dj] = *(const s8b*)(&L.s.Vt[d][cb]);
        }
#pragma unroll
        for (int mi = 0; mi < 2; mi++)
#pragma unroll
            for (int dj = 0; dj < 4; dj++)
                oacc[mi][dj] = __builtin_amdgcn_mfma_f32_16x16x32_bf16(ap[mi], bv[dj], oacc[mi][dj], 0, 0, 0);
    }
    __syncthreads();
#pragma unroll
    for (int mi = 0; mi < 2; mi++)
#pragma unroll
        for (int dj = 0; dj < 4; dj++)
#pragma unroll
            for (int r = 0; r < 4; r++)
                L.Os[w * 32 + mi * 16 + quad * 4 + r][dj * 16 + l16] = oacc[mi][dj][r];
    long pbase = (long)(h * 60 + c);
    if (l16 == 0) {
#pragma unroll
        for (int mi = 0; mi < 2; mi++)
#pragma unroll
            for (int r = 0; r < 4; r++) {
                int i = qt * 128 + w * 32 + mi * 16 + quad * 4 + r;
                pml[pbase * 512 + i] = mrow[mi][r];
                pml[pbase * 512 + 256 + i] = lrow[mi][r];
            }
    }
    __syncthreads();
    float* pc = pacc + pbase * 16384 + qt * 128;
    int d = t >> 2, ig = t & 3;
#pragma unroll
    for (int u = 0; u < 8; u++) {
        int i0 = ig * 32 + u * 4;
        float4 v4 = make_float4(L.Os[i0][d], L.Os[i0 + 1][d], L.Os[i0 + 2][d], L.Os[i0 + 3][d]);
        *(float4*)(pc + (long)d * 256 + i0) = v4;
    }
}

// ---------------- fused sim1+softmax+@BmT attention + depthwise res-conv; writes bf16 ohb
// V-fragments from global BmT (L2-hot, no LDS staging); Os round-trip in bf16 stride-68 (conflict-free)
__global__ __launch_bounds__(256)
void k_attn1(const ushort* __restrict__ qg, const ushort* __restrict__ klb,
             const ushort* __restrict__ BmT, const ushort* __restrict__ vg,
             const float* __restrict__ rw, ushort* __restrict__ ohb)
{
    const int m0 = blockIdx.x * 128;
    const int h = blockIdx.y;
    const int t = threadIdx.x;
    const int w = t >> 6, lane = t & 63;
    const int quad = lane >> 4, l16 = lane & 15;

    __shared__ union {
        ushort Ps[128][40];
        ushort Os[128][68];
    } L;

    s8b aq[2][2];
    const ushort* qbase = qg + ((long)h * NPQ + 230 + m0 + w * 32) * 64;
#pragma unroll
    for (int mi = 0; mi < 2; mi++)
#pragma unroll
        for (int kf = 0; kf < 2; kf++)
            aq[mi][kf] = *(const s8b*)(qbase + (mi * 16 + l16) * 64 + kf * 32 + quad * 8);

    f4 oacc[2][4] = {};
    float mrow[2][4], lrow[2][4];
#pragma unroll
    for (int mi = 0; mi < 2; mi++)
#pragma unroll
        for (int r = 0; r < 4; r++) { mrow[mi][r] = -INFINITY; lrow[mi][r] = 0.f; }

    const ushort* kh = klb + (long)h * 16384;
    const ushort* bmt = BmT + (long)h * 16384;

    for (int sub = 0; sub < 8; sub++) {
        int key0 = sub * 32;
        // K fragments + V fragments straight from global (32KB/head, L2-hot)
        s8b bq[2][2], bv[4];
#pragma unroll
        for (int nj = 0; nj < 2; nj++)
#pragma unroll
            for (int kf = 0; kf < 2; kf++)
                bq[nj][kf] = *(const s8b*)(kh + (long)(key0 + nj * 16 + l16) * 64 + kf * 32 + quad * 8);
#pragma unroll
        for (int dj = 0; dj < 4; dj++)
            bv[dj] = *(const s8b*)(bmt + (long)(dj * 16 + l16) * 256 + key0 + quad * 8);
        f4 sacc[2][2] = {};
#pragma unroll
        for (int mi = 0; mi < 2; mi++)
#pragma unroll
            for (int nj = 0; nj < 2; nj++) {
                sacc[mi][nj] = __builtin_amdgcn_mfma_f32_16x16x32_bf16(aq[mi][0], bq[nj][0], sacc[mi][nj], 0, 0, 0);
                sacc[mi][nj] = __builtin_amdgcn_mfma_f32_16x16x32_bf16(aq[mi][1], bq[nj][1], sacc[mi][nj], 0, 0, 0);
            }
        float p0s[2][4], p1s[2][4];
#pragma unroll
        for (int mi = 0; mi < 2; mi++)
#pragma unroll
            for (int r = 0; r < 4; r++) {
                float mx = fmaxf(sacc[mi][0][r], sacc[mi][1][r]);
#pragma unroll
                for (int d = 1; d < 16; d <<= 1) mx = fmaxf(mx, __shfl_xor(mx, d));
                float mn = fmaxf(mrow[mi][r], mx);
                float f = __expf(mrow[mi][r] - mn);
                float p0 = __expf(sacc[mi][0][r] - mn);
                float p1 = __expf(sacc[mi][1][r] - mn);
                float ps = p0 + p1;
#pragma unroll
                for (int d = 1; d < 16; d <<= 1) ps += __shfl_xor(ps, d);
                lrow[mi][r] = lrow[mi][r] * f + ps;
                mrow[mi][r] = mn;
#pragma unroll
                for (int dj = 0; dj < 4; dj++) oacc[mi][dj][r] *= f;
                p0s[mi][r] = p0; p1s[mi][r] = p1;
            }
        __syncthreads();   // previous subtile's ap reads done
#pragma unroll
        for (int mi = 0; mi < 2; mi++)
#pragma unroll
            for (int r = 0; r < 4; r++) {
                int row = w * 32 + mi * 16 + quad * 4 + r;
                L.Ps[row][l16]      = f2bf(p0s[mi][r]);
                L.Ps[row][16 + l16] = f2bf(p1s[mi][r]);
            }
        __syncthreads();
        s8b ap[2];
#pragma unroll
        for (int mi = 0; mi < 2; mi++)
            ap[mi] = *(const s8b*)(&L.Ps[w * 32 + mi * 16 + l16][quad * 8]);
#pragma unroll
        for (int mi = 0; mi < 2; mi++)
#pragma unroll
            for (int dj = 0; dj < 4; dj++)
                oacc[mi][dj] = __builtin_amdgcn_mfma_f32_16x16x32_bf16(ap[mi], bv[dj], oacc[mi][dj], 0, 0, 0);
    }
    __syncthreads();   // all ap reads done -> Os may overwrite Ps
    // normalized attn tile -> LDS bf16, stride 68 (conflict-free writes: quad offset 8 banks)
#pragma unroll
    for (int mi = 0; mi < 2; mi++)
#pragma unroll
        for (int r = 0; r < 4; r++) {
            float inv = 1.f / lrow[mi][r];
            int row = w * 32 + mi * 16 + quad * 4 + r;
#pragma unroll
            for (int dj = 0; dj < 4; dj++)
                L.Os[row][dj * 16 + l16] = f2bf(oacc[mi][dj][r] * inv);
        }
    __syncthreads();
    // conv phase: wave w owns tokens [m0+w*32, +32), lane = d; two 16-token halves (reg cap)
    const ushort* vh = vg + (long)h * NPQ * 64;
    int tk0 = m0 + w * 32;
#pragma unroll
    for (int half = 0; half < 2; half++) {
        int t0 = tk0 + half * 16;
        int base = 214 + t0;
        float vr[48];
#pragma unroll
        for (int i = 0; i < 48; i++) {
            int src = base + i;
            vr[i] = (src < NP) ? bf2f(vh[(long)src * 64 + lane]) : 0.f;
        }
        float conv[16];
#pragma unroll
        for (int i = 0; i < 16; i++) conv[i] = 0.f;
#pragma unroll
        for (int kk = 0; kk < 33; kk++) {
            float wk = rw[h * 33 + kk];
#pragma unroll
            for (int i = 0; i < 16; i++) conv[i] = fmaf(wk, vr[i + kk], conv[i]);
        }
#pragma unroll
        for (int i = 0; i < 16; i++) {
            int tk = t0 + i;
            if (tk < NTOK) {
                float val = bf2f(L.Os[w * 32 + half * 16 + i][lane]) + conv[i];
                ohb[(long)tk * 512 + h * 64 + lane] = f2bf(val);
            }
        }
    }
}

// ---------------- layernorm over 512, writes bf16 xln (first `pad` rows zero)
__global__ __launch_bounds__(256)
void k_layernorm(const float* __restrict__ h, ushort* __restrict__ xln,
                 const float* __restrict__ g, const float* __restrict__ b, int pad)
{
    int row = blockIdx.x, t = threadIdx.x;
    if (row < pad) {
        xln[(long)row * 512 + t] = 0;
        xln[(long)row * 512 + t + 256] = 0;
        return;
    }
    const float* src = h + (long)(row - pad) * 512;
    float x1 = src[t], x2 = src[t + 256];
    float s = x1 + x2, q = x1 * x1 + x2 * x2;
    __shared__ float rs[4], rq[4], st[2];
    int wid = t >> 6, lane = t & 63;
#pragma unroll
    for (int o = 32; o > 0; o >>= 1) { s += __shfl_down(s, o); q += __shfl_down(q, o); }
    if (lane == 0) { rs[wid] = s; rq[wid] = q; }
    __syncthreads();
    if (t == 0) {
        float S = rs[0] + rs[1] + rs[2] + rs[3];
        float Q = rq[0] + rq[1] + rq[2] + rq[3];
        float mean = S / 512.f;
        float var = Q / 512.f - mean * mean;
        st[0] = mean; st[1] = rsqrtf(var + 1e-5f);
    }
    __syncthreads();
    float mean = st[0], rstd = st[1];
    xln[(long)row * 512 + t] = f2bf((x1 - mean) * rstd * g[t] + b[t]);
    xln[(long)row * 512 + t + 256] = f2bf((x2 - mean) * rstd * g[t + 256] + b[t + 256]);
}

__global__ __launch_bounds__(256)
void k_padcls(float* __restrict__ hbuf, const float* __restrict__ cls)
{
    int i = blockIdx.x, t = threadIdx.x;
    if (i == 0) { hbuf[t] = cls[t]; hbuf[t + 256] = cls[t + 256]; }
    else {
        hbuf[(long)(15000 + i) * 512 + t] = hbuf[(long)i * 512 + t];
        hbuf[(long)(15000 + i) * 512 + t + 256] = hbuf[(long)i * 512 + t + 256];
    }
}

__global__ __launch_bounds__(256)
void k_wT(const float* __restrict__ Wm, ushort* __restrict__ Wt, int K, int N, long sW, long sWt)
{
    Wm += (long)blockIdx.z * sW; Wt += (long)blockIdx.z * sWt;
    __shared__ float tile[32][33];
    int tx = threadIdx.x & 31, ty = threadIdx.x >> 5;
    int n0 = blockIdx.x * 32, k0 = blockIdx.y * 32;
#pragma unroll
    for (int u = 0; u < 4; u++) tile[ty + u * 8][tx] = Wm[(long)(k0 + ty + u * 8) * N + n0 + tx];
    __syncthreads();
#pragma unroll
    for (int u = 0; u < 4; u++) Wt[(long)(n0 + ty + u * 8) * K + k0 + tx] = f2bf(tile[tx][ty + u * 8]);
}

__global__ __launch_bounds__(256)
void k_cvt(const float4* __restrict__ src, ushort4* __restrict__ dst, long n4)
{
    long i = (long)blockIdx.x * 256 + threadIdx.x;
    if (i < n4) {
        float4 v = src[i];
        ushort4 o;
        o.x = f2bf(v.x); o.y = f2bf(v.y); o.z = f2bf(v.z); o.w = f2bf(v.w);
        dst[i] = o;
    }
}

__global__ __launch_bounds__(256)
void k_b2f(const ushort4* __restrict__ src, float4* __restrict__ dst, long n4)
{
    long i = (long)blockIdx.x * 256 + threadIdx.x;
    if (i < n4) {
        ushort4 v = src[i];
        dst[i] = make_float4(bf2f(v.x), bf2f(v.y), bf2f(v.z), bf2f(v.w));
    }
}

__global__ __launch_bounds__(64)
void k_landmarks(const ushort* __restrict__ q, const ushort* __restrict__ k,
                 float* __restrict__ ql, ushort* __restrict__ qlb,
                 float* __restrict__ klT, ushort* __restrict__ klb,
                 unsigned* __restrict__ scal)
{
    int i = blockIdx.x, h = blockIdx.y, d = threadIdx.x;
    if (i == 0 && h == 0 && d == 0) { scal[0] = 0u; scal[1] = 0u; }
    long base = ((long)h * NPQ + (long)i * 60) * 64 + d;
    float sq = 0.f, sk = 0.f;
    for (int j = 0; j < 60; j++) { sq += bf2f(q[base + j * 64]); sk += bf2f(k[base + j * 64]); }
    float qv = sq / 60.f, kv = sk / 60.f;
    ql[((long)h * 256 + i) * 64 + d] = qv;
    qlb[((long)h * 256 + i) * 64 + d] = f2bf(qv);
    klT[((long)h * 64 + d) * 256 + i] = kv;
    klb[((long)h * 256 + i) * 64 + d] = f2bf(kv);
}

__global__ __launch_bounds__(256)
void k_softmax256(float* __restrict__ X, ushort* __restrict__ X16, long headStride)
{
    float* row = X + (long)blockIdx.y * headStride + (long)blockIdx.x * 256;
    int t = threadIdx.x, wid = t >> 6, lane = t & 63;
    float x = row[t];
    __shared__ float rm[4], rsum[4], fin[2];
    float m = x;
#pragma unroll
    for (int o = 32; o > 0; o >>= 1) m = fmaxf(m, __shfl_down(m, o));
    if (lane == 0) rm[wid] = m;
    __syncthreads();
    if (t == 0) fin[0] = fmaxf(fmaxf(rm[0], rm[1]), fmaxf(rm[2], rm[3]));
    __syncthreads();
    float e = __expf(x - fin[0]);
    float s = e;
#pragma unroll
    for (int o = 32; o > 0; o >>= 1) s += __shfl_down(s, o);
    if (lane == 0) rsum[wid] = s;
    __syncthreads();
    if (t == 0) fin[1] = rsum[0] + rsum[1] + rsum[2] + rsum[3];
    __syncthreads();
    float v = e / fin[1];
    row[t] = v;
    if (X16) X16[(long)blockIdx.y * headStride + (long)blockIdx.x * 256 + t] = f2bf(v);
}

__global__ __launch_bounds__(256)
void k_colmax(const float* __restrict__ a2, unsigned* __restrict__ scal)
{
    int h = blockIdx.x, t = threadIdx.x, wid = t >> 6, lane = t & 63;
    const float* A = a2 + (long)h * 65536;
    float cs = 0.f, rs = 0.f;
    for (int i = 0; i < 256; i++) cs += A[(long)i * 256 + t];
    for (int j = 0; j < 256; j++) rs += A[(long)t * 256 + j];
    __shared__ float r1[4], r2[4];
    float m1v = cs, m2v = rs;
#pragma unroll
    for (int o = 32; o > 0; o >>= 1) {
        m1v = fmaxf(m1v, __shfl_down(m1v, o));
        m2v = fmaxf(m2v, __shfl_down(m2v, o));
    }
    if (lane == 0) { r1[wid] = m1v; r2[wid] = m2v; }
    __syncthreads();
    if (t == 0) {
        float a = fmaxf(fmaxf(r1[0], r1[1]), fmaxf(r1[2], r1[3]));
        float b = fmaxf(fmaxf(r2[0], r2[1]), fmaxf(r2[2], r2[3]));
        atomicMax(scal + 0, __float_as_uint(a));
        atomicMax(scal + 1, __float_as_uint(b));
    }
}

__global__ __launch_bounds__(256)
void k_zinit(const float* __restrict__ a2, ushort* __restrict__ zb, const unsigned* __restrict__ scal)
{
    float s = 1.f / (__uint_as_float(scal[0]) * __uint_as_float(scal[1]));
    const float* A = a2 + (long)blockIdx.z * 65536;
    ushort* Z = zb + (long)blockIdx.z * 65536;
    __shared__ float tile[32][33];
    int tx = threadIdx.x & 31, ty = threadIdx.x >> 5;
    int i0 = blockIdx.x * 32, j0 = blockIdx.y * 32;
#pragma unroll
    for (int u = 0; u < 4; u++) tile[ty + u * 8][tx] = A[(long)(j0 + ty + u * 8) * 256 + i0 + tx];
    __syncthreads();
#pragma unroll
    for (int u = 0; u < 4; u++) Z[(long)(i0 + ty + u * 8) * 256 + j0 + tx] = f2bf(tile[tx][ty + u * 8] * s);
}

__global__ __launch_bounds__(256)
void k_a3v_merge(const float* __restrict__ pacc, const float* __restrict__ pml,
                 float* __restrict__ t1)
{
    int d = blockIdx.x, h = blockIdx.y, i = threadIdx.x;
    float M = -INFINITY, L = 0.f, num = 0.f;
    for (int c = 0; c < 60; c++) {
        float mc = pml[(long)(h * 60 + c) * 2 * 256 + i];
        float lc = pml[((long)(h * 60 + c) * 2 + 1) * 256 + i];
        float ac = pacc[((long)(h * 60 + c) * 64 + d) * 256 + i];
        if (mc > M) {
            float f = __expf(M - mc);
            num = num * f + ac; L = L * f + lc; M = mc;
        } else {
            float p = __expf(mc - M);
            num = fmaf(p, ac, num); L = fmaf(p, lc, L);
        }
    }
    t1[((long)h * 256 + i) * 64 + d] = num / L;
}

__global__ __launch_bounds__(256)
void k_cls(const ushort* __restrict__ qb, const float* __restrict__ klT,
           const float* __restrict__ Bm, const ushort* __restrict__ vb,
           const float* __restrict__ rw, float* __restrict__ oh)
{
    int h = blockIdx.x, t = threadIdx.x, wid = t >> 6, lane = t & 63;
    __shared__ float qs[64], p[256], red[256];
    __shared__ float rm[4], rsum[4], fin[2];
    if (t < 64) qs[t] = bf2f(qb[((long)h * NPQ + 230) * 64 + t]);
    __syncthreads();
    float s = 0.f;
    for (int d = 0; d < 64; d++) s = fmaf(qs[d], klT[((long)h * 64 + d) * 256 + t], s);
    float m = s;
#pragma unroll
    for (int o = 32; o > 0; o >>= 1) m = fmaxf(m, __shfl_down(m, o));
    if (lane == 0) rm[wid] = m;
    __syncthreads();
    if (t == 0) fin[0] = fmaxf(fmaxf(rm[0], rm[1]), fmaxf(rm[2], rm[3]));
    __syncthreads();
    float e = __expf(s - fin[0]);
    float ss = e;
#pragma unroll
    for (int o = 32; o > 0; o >>= 1) ss += __shfl_down(ss, o);
    if (lane == 0) rsum[wid] = ss;
    __syncthreads();
    if (t == 0) fin[1] = rsum[0] + rsum[1] + rsum[2] + rsum[3];
    __syncthreads();
    p[t] = e / fin[1];
    __syncthreads();
    int d = t & 63, grp = t >> 6;
    float o = 0.f;
    for (int j = grp * 64; j < grp * 64 + 64; j++) o = fmaf(p[j], Bm[((long)h * 256 + j) * 64 + d], o);
    red[t] = o;
    __syncthreads();
    if (t < 64) {
        float val = red[t] + red[t + 64] + red[t + 128] + red[t + 192];
#pragma unroll
        for (int kk = 0; kk < 33; kk++)
            val = fmaf(rw[h * 33 + kk], bf2f(vb[((long)h * NPQ + 214 + kk) * 64 + t]), val);
        oh[h * 64 + t] = val;
    }
}

__global__ __launch_bounds__(256)
void k_copy4(const float4* __restrict__ src, float4* __restrict__ dst, long n4)
{
    long i = (long)blockIdx.x * 256 + threadIdx.x;
    if (i < n4) dst[i] = src[i];
}

// ---------------- combine w7+w5+w3+identity into wc[49][512], bc = b7+b5+b3
__global__ __launch_bounds__(512)
void k_wcomb(const float* __restrict__ w7, const float* __restrict__ b7,
             const float* __restrict__ w5, const float* __restrict__ b5,
             const float* __restrict__ w3, const float* __restrict__ b3,
             float* __restrict__ wc, float* __restrict__ bc)
{
    int k = blockIdx.x, c = threadIdx.x;
    int kr = k / 7, kc = k % 7;
    float v = w7[c * 49 + k];
    if (kr >= 1 && kr <= 5 && kc >= 1 && kc <= 5) v += w5[c * 25 + (kr - 1) * 5 + (kc - 1)];
    if (kr >= 2 && kr <= 4 && kc >= 2 && kc <= 4) v += w3[c * 9 + (kr - 2) * 3 + (kc - 2)];
    if (k == 24) v += 1.f;
    wc[k * 512 + c] = v;
    if (k == 0) bc[c] = b7[c] + b5[c] + b3[c];
}

// ---------------- PPEG v2: single 7x7 combined depthwise; bf16 LDS tile
__global__ __launch_bounds__(256)
void k_ppeg2(const float* __restrict__ cnn, float* __restrict__ hbuf,
             const float* __restrict__ wc, const float* __restrict__ bc)
{
    __shared__ ushort tile[140][64];
    int t = threadIdx.x;
    int cp = t & 31;
    int g = t >> 5;
    int c0 = blockIdx.x * 8, r0 = blockIdx.y * 4, cb = blockIdx.z * 64;
    for (int idx = t; idx < 140 * 32; idx += 256) {
        int pos = idx >> 5, pp = idx & 31;
        int pr = pos / 14, pc = pos % 14;
        int gr = r0 + pr - 3, gc = c0 + pc - 3;
        float v0 = 0.f, v1 = 0.f;
        if (gr >= 0 && gr < HG && gc >= 0 && gc < HG) {
            const float* src = cnn + (long)(gr * HG + gc) * 512 + cb + pp * 2;
            v0 = src[0]; v1 = src[1];
        }
        tile[pos][pp * 2] = f2bf(v0);
        tile[pos][pp * 2 + 1] = f2bf(v1);
    }
    __syncthreads();
    float acc[4][2] = {};
    for (int kr = 0; kr < 7; kr++)
#pragma unroll
        for (int kc = 0; kc < 7; kc++) {
            float w0 = wc[(kr * 7 + kc) * 512 + cb + cp * 2];
            float w1 = wc[(kr * 7 + kc) * 512 + cb + cp * 2 + 1];
#pragma unroll
            for (int u = 0; u < 4; u++) {
                int p = g * 4 + u;
                int orow = p >> 3, ocol = p & 7;
                unsigned pk = *(const unsigned*)&tile[(orow + kr) * 14 + (ocol + kc)][cp * 2];
                acc[u][0] = fmaf(w0, bf2f((ushort)pk), acc[u][0]);
                acc[u][1] = fmaf(w1, bf2f((ushort)(pk >> 16)), acc[u][1]);
            }
        }
    float b0 = bc[cb + cp * 2], b1 = bc[cb + cp * 2 + 1];
#pragma unroll
    for (int u = 0; u < 4; u++) {
        int p = g * 4 + u;
        int orow = p >> 3, ocol = p & 7;
        int gr = r0 + orow, gc = c0 + ocol;
        if (gr < HG && gc < HG) {
            float* dst = hbuf + (long)(1 + gr * HG + gc) * 512 + cb + cp * 2;
            dst[0] = acc[u][0] + b0;
            dst[1] = acc[u][1] + b1;
        }
    }
}

__global__ __launch_bounds__(256)
void k_final(const float* __restrict__ hbuf, const float* __restrict__ g,
             const float* __restrict__ b, const float* __restrict__ W2,
             const float* __restrict__ b2, float* __restrict__ out)
{
    __shared__ float y[512];
    __shared__ float rs[4], rq[4], st[2], lg[8];
    int t = threadIdx.x, wid = t >> 6, lane = t & 63;
    float x1 = hbuf[t], x2 = hbuf[t + 256];
    float s = x1 + x2, q = x1 * x1 + x2 * x2;
#pragma unroll
    for (int o = 32; o > 0; o >>= 1) { s += __shfl_down(s, o); q += __shfl_down(q, o); }
    if (lane == 0) { rs[wid] = s; rq[wid] = q; }
    __syncthreads();
    if (t == 0) {
        float S = rs[0] + rs[1] + rs[2] + rs[3];
        float Q = rq[0] + rq[1] + rq[2] + rq[3];
        float mean = S / 512.f;
        float var = Q / 512.f - mean * mean;
        st[0] = mean; st[1] = rsqrtf(var + 1e-5f);
    }
    __syncthreads();
    float mean = st[0], rstd = st[1];
    y[t] = (x1 - mean) * rstd * g[t] + b[t];
    y[t + 256] = (x2 - mean) * rstd * g[t + 256] + b[t + 256];
    __syncthreads();
    if (t < 5) {
        float acc = b2[t];
        for (int kx = 0; kx < 512; kx++) acc = fmaf(y[kx], W2[kx * 5 + t], acc);
        lg[t] = acc;
    }
    __syncthreads();
    if (t == 0) {
        float mx = lg[0]; int am = 0;
        for (int j = 1; j < 5; j++) if (lg[j] > mx) { mx = lg[j]; am = j; }
        float e[5], se = 0.f;
        for (int j = 0; j < 5; j++) { e[j] = __expf(lg[j] - mx); se += e[j]; }
        for (int j = 0; j < 5; j++) { out[j] = lg[j]; out[5 + j] = e[j] / se; }
        out[10] = (float)am;
    }
}

extern "C" void kernel_launch(void* const* d_in, const int* in_sizes, int n_in,
                              void* d_out, int out_size, void* d_ws, size_t ws_size,
                              hipStream_t stream)
{
    const float* data  = (const float*)d_in[0];
    const float* Wfc1  = (const float*)d_in[1];
    const float* bfc1  = (const float*)d_in[2];
    const float* cls   = (const float*)d_in[3];
    const float* ln1g  = (const float*)d_in[4];
    const float* ln1b  = (const float*)d_in[5];
    const float* qkv1  = (const float*)d_in[6];
    const float* out1w = (const float*)d_in[7];
    const float* out1b = (const float*)d_in[8];
    const float* res1  = (const float*)d_in[9];
    const float* w7    = (const float*)d_in[10];
    const float* b7    = (const float*)d_in[11];
    const float* w5    = (const float*)d_in[12];
    const float* b5    = (const float*)d_in[13];
    const float* w3    = (const float*)d_in[14];
    const float* b3    = (const float*)d_in[15];
    const float* ln2g  = (const float*)d_in[16];
    const float* ln2b  = (const float*)d_in[17];
    const float* qkv2  = (const float*)d_in[18];
    const float* out2w = (const float*)d_in[19];
    const float* out2b = (const float*)d_in[20];
    const float* res2  = (const float*)d_in[21];
    const float* normg = (const float*)d_in[22];
    const float* normb = (const float*)d_in[23];
    const float* Wfc2  = (const float*)d_in[24];
    const float* bfc2  = (const float*)d_in[25];
    float* out = (float*)d_out;

    float* W = (float*)d_ws;
    size_t off = 0;
    auto alloc = [&](size_t n) { size_t o = off; off += (n + 255) & ~(size_t)255; return o; };
    float*  hbuf   = W + alloc((size_t)NTOK * 512);
    float*  ohreg  = W + alloc((size_t)15232 * 512);
    float*  oh     = ohreg;
    ushort* xln    = (ushort*)ohreg;
    ushort* qb16   = (ushort*)(W + alloc((size_t)8 * NPQ * 32));
    ushort* kb16   = (ushort*)(W + alloc((size_t)8 * NPQ * 32));
    ushort* vb16   = (ushort*)(W + alloc((size_t)8 * NPQ * 32));
    float*  ql     = W + alloc(8 * 256 * 64);
    ushort* qlb    = (ushort*)(W + alloc(8 * 256 * 32));
    float*  klT    = W + alloc(8 * 64 * 256);
    ushort* klb    = (ushort*)(W + alloc(8 * 256 * 32));
    float*  a2     = W + alloc(8 * 65536);
    ushort* a2b    = (ushort*)(W + alloc(8 * 32768));
    ushort* zb0    = (ushort*)(W + alloc(8 * 32768));
    ushort* zb1    = (ushort*)(W + alloc(8 * 32768));
    ushort* m1b    = (ushort*)(W + alloc(8 * 32768));
    ushort* mab    = (ushort*)(W + alloc(8 * 32768));
    ushort* mbb    = (ushort*)(W + alloc(8 * 32768));
    float*  z0     = W + alloc(8 * 65536);
    float*  z1     = W + alloc(8 * 65536);
    float*  m1     = W + alloc(8 * 65536);
    float*  ma     = W + alloc(8 * 65536);
    float*  mb     = W + alloc(8 * 65536);
    float*  t1     = W + alloc(8 * 256 * 64);
    float*  Bm     = W + alloc(8 * 256 * 64);
    ushort* BmbT   = (ushort*)(W + alloc(8 * 256 * 32));   // bf16 BmT [h][64][256]
    float*  scal   = W + alloc(64);
    ushort* ohb16  = (ushort*)(W + alloc((size_t)15232 * 256));
    ushort* WfcT   = (ushort*)(W + alloc(1024 * 256));
    ushort* qkv1T  = (ushort*)(W + alloc(1536 * 256));
    ushort* qkv2T  = (ushort*)(W + alloc(1536 * 256));
    ushort* out1T  = (ushort*)(W + alloc(512 * 256));
    ushort* out2T  = (ushort*)(W + alloc(512 * 256));
    float*  wc     = W + alloc(49 * 512);
    float*  bc     = W + alloc(512);
    float*  big    = W + alloc(8110080);   // datab | pacc+pml | ppeg cnn
    ushort* datab  = (ushort*)big;
    float*  pacc   = big;
    float*  pml    = big + 7864320;
    float*  cnn    = big;
    if (ws_size < off * sizeof(float)) return;

    k_wT<<<dim3(16, 32, 1), 256, 0, stream>>>(Wfc1, WfcT, 1024, 512, 0, 0);
    k_wT<<<dim3(48, 16, 1), 256, 0, stream>>>(qkv1, qkv1T, 512, 1536, 0, 0);
    k_wT<<<dim3(48, 16, 1), 256, 0, stream>>>(qkv2, qkv2T, 512, 1536, 0, 0);
    k_wT<<<dim3(16, 16, 1), 256, 0, stream>>>(out1w, out1T, 512, 512, 0, 0);
    k_wT<<<dim3(16, 16, 1), 256, 0, stream>>>(out2w, out2T, 512, 512, 0, 0);
    k_wcomb<<<49, 512, 0, stream>>>(w7, b7, w5, b5, w3, b3, wc, bc);
    k_cvt<<<15000, 256, 0, stream>>>((const float4*)data, (ushort4*)datab, 3840000);
    gemm_mfma<4, 4, 2, 2><<<dim3(4, 118, 1), 256, 0, stream>>>(
        datab, 1024, 0, WfcT, 1024, 0, hbuf + 512, 512, 0, 15000, 1024, bfc1, 1, 0);
    k_padcls<<<130, 256, 0, stream>>>(hbuf, cls);

    auto layer = [&](const float* lng, const float* lnb, const ushort* qkvT,
                     const float* outW, const ushort* outT, const float* outB,
                     const float* resW, bool full) {
        k_layernorm<<<NP, 256, 0, stream>>>(hbuf, xln, lng, lnb, 230);
        gemm_qkv_mfma<<<dim3(12, 120, 1), 256, 0, stream>>>(xln, qkvT, qb16, kb16, vb16);
        k_landmarks<<<dim3(256, 8), 64, 0, stream>>>(qb16, kb16, ql, qlb, klT, klb, (unsigned*)scal);
        gemm_f32<<<dim3(4, 4, 8), 256, 0, stream>>>(ql, 64, 16384, klT, 256, 16384,
            a2, 256, 65536, 256, 256, 64, nullptr, nullptr, 0, 0, 0.f, 1.f, 0, 0);
        k_softmax256<<<dim3(256, 8), 256, 0, stream>>>(a2, a2b, 65536);
        k_colmax<<<8, 256, 0, stream>>>(a2, (unsigned*)scal);
        k_zinit<<<dim3(8, 8, 8), 256, 0, stream>>>(a2, zb0, (const unsigned*)scal);
        // pinv iters 0-4 in bf16 MFMA
        ushort* zbi = zb0; ushort* zbo = zb1;
        for (int it = 0; it < 5; ++it) {
            gemm_nn16<<<dim3(4, 4, 8), 256, 0, stream>>>(a2b, zbi, nullptr, m1b, 256, 256, 1.f, 0.f, 65536);
            gemm_nn16<<<dim3(4, 4, 8), 256, 0, stream>>>(m1b, m1b, m1b, mab, 256, 256, -1.f, 7.f, 65536);
            gemm_nn16<<<dim3(4, 4, 8), 256, 0, stream>>>(m1b, mab, m1b, mbb, 256, 256, -1.f, 15.f, 65536);
            gemm_nn16<<<dim3(4, 4, 8), 256, 0, stream>>>(zbi, mbb, zbi, zbo, 256, 256, -0.25f, 3.25f, 65536);
            ushort* tmp = zbi; zbi = zbo; zbo = tmp;
        }
        k_b2f<<<512, 256, 0, stream>>>((const ushort4*)zbi, (float4*)z0, 131072);
        // final pinv iter in fp32
        float* zi = z0; float* zo = z1;
        {
            gemm_f32<<<dim3(4, 4, 8), 256, 0, stream>>>(a2, 256, 65536, zi, 256, 65536,
                m1, 256, 65536, 256, 256, 256, nullptr, nullptr, 0, 0, 0.f, 1.f, 0, 0);
            gemm_f32<<<dim3(4, 4, 8), 256, 0, stream>>>(m1, 256, 65536, m1, 256, 65536,
                ma, 256, 65536, 256, 256, 256, nullptr, m1, 256, 65536, 7.f, -1.f, 0, 0);
            gemm_f32<<<dim3(4, 4, 8), 256, 0, stream>>>(m1, 256, 65536, ma, 256, 65536,
                mb, 256, 65536, 256, 256, 256, nullptr, m1, 256, 65536, 15.f, -1.f, 0, 0);
            gemm_f32<<<dim3(4, 4, 8), 256, 0, stream>>>(zi, 256, 65536, mb, 256, 65536,
                zo, 256, 65536, 256, 256, 256, nullptr, zi, 256, 65536, 3.25f, -0.25f, 0, 0);
            float* tmp = zi; zi = zo; zo = tmp;
        }
        k_flash_a3v<<<dim3(60, 2, 8), 256, 0, stream>>>(qlb, kb16, vb16, pacc, pml);
        k_a3v_merge<<<dim3(64, 8), 256, 0, stream>>>(pacc, pml, t1);
        gemm_f32<<<dim3(1, 4, 8), 256, 0, stream>>>(zi, 256, 65536, t1, 64, 16384,
            Bm, 64, 16384, 256, 64, 256, nullptr, nullptr, 0, 0, 0.f, 1.f, 0, 0);
        if (full) {
            k_wT<<<dim3(2, 8, 8), 256, 0, stream>>>(Bm, BmbT, 256, 64, 16384, 16384);
            k_attn1<<<dim3(119, 8), 256, 0, stream>>>(qb16, klb, BmbT, vb16, resW, ohb16);
            gemm_mfma<4, 4, 2, 2><<<dim3(4, 119, 1), 256, 0, stream>>>(
                ohb16, 512, 0, outT, 512, 0, hbuf, 512, 0, NTOK, 512, outB, 0, 1);
        } else {
            k_cls<<<8, 256, 0, stream>>>(qb16, klT, Bm, vb16, resW, oh);
            gemm_f32<<<dim3(8, 1, 1), 256, 0, stream>>>(oh, 512, 0, outW, 512, 0,
                hbuf, 512, 0, 1, 512, 512, outB, nullptr, 0, 0, 0.f, 1.f, 0, 1);
        }
    };

    layer(ln1g, ln1b, qkv1T, out1w, out1T, out1b, res1, true);
    k_copy4<<<(1936512 + 255) / 256, 256, 0, stream>>>((const float4*)(hbuf + 512), (float4*)cnn, 1936512);
    k_ppeg2<<<dim3(16, 31, 8), 256, 0, stream>>>(cnn, hbuf, wc, bc);
    layer(ln2g, ln2b, qkv2T, out2w, out2T, out2b, res2, false);
    k_final<<<1, 256, 0, stream>>>(hbuf, normg, normb, Wfc2, bfc2, out);
}

// Round 7
// 1397.955 us; speedup vs baseline: 2.4243x; 1.0403x over previous
//
#include <hip/hip_runtime.h>
#include <math.h>

#define NP 15360
#define NPQ 15488
#define NTOK 15130
#define HG 123

typedef __attribute__((ext_vector_type(8))) short s8b;
typedef __attribute__((ext_vector_type(4))) float f4;

__device__ inline float bf2f(ushort u) { return __uint_as_float(((unsigned)u) << 16); }
__device__ inline ushort f2bf(float f) {
    unsigned u = __float_as_uint(f);
    unsigned r = (u + 0x7fffu + ((u >> 16) & 1u)) >> 16;
    return (ushort)r;
}

// ---------------- generic fp32 GEMM (small/sensitive ops): C = cS*(A@B) + eS*E + bias
__global__ __launch_bounds__(256)
void gemm_f32(const float* __restrict__ A, int lda, long sA,
              const float* __restrict__ B, int ldb, long sB,
              float* __restrict__ C, int ldc, long sC,
              int M, int N, int K,
              const float* __restrict__ bias,
              const float* __restrict__ E, int ldE, long sE, float eS,
              float cS, int relu, int accum)
{
    A += (long)blockIdx.z * sA;
    B += (long)blockIdx.z * sB;
    C += (long)blockIdx.z * sC;
    if (E) E += (long)blockIdx.z * sE;
    const int m0 = blockIdx.y * 64, n0 = blockIdx.x * 64;
    const int t = threadIdx.x;
    const int tx = t & 15, ty = t >> 4;
    __shared__ float As[16][64];
    __shared__ float Bs[16][64];
    float acc[4][4] = {};
    const int arow = t >> 2, akc = (t & 3) * 4;
    const int brow = t >> 4, bnc = (t & 15) * 4;
    for (int k0 = 0; k0 < K; k0 += 16) {
        float4 av = make_float4(0.f, 0.f, 0.f, 0.f);
        if (m0 + arow < M) av = *(const float4*)(A + (long)(m0 + arow) * lda + k0 + akc);
        As[akc + 0][arow] = av.x; As[akc + 1][arow] = av.y;
        As[akc + 2][arow] = av.z; As[akc + 3][arow] = av.w;
        float4 bv = *(const float4*)(B + (long)(k0 + brow) * ldb + n0 + bnc);
        *(float4*)&Bs[brow][bnc] = bv;
        __syncthreads();
#pragma unroll
        for (int kk = 0; kk < 16; ++kk) {
            float4 a4 = *(const float4*)&As[kk][ty * 4];
            float4 b4 = *(const float4*)&Bs[kk][tx * 4];
            float a[4] = {a4.x, a4.y, a4.z, a4.w};
            float b[4] = {b4.x, b4.y, b4.z, b4.w};
#pragma unroll
            for (int i = 0; i < 4; i++)
#pragma unroll
                for (int j = 0; j < 4; j++) acc[i][j] = fmaf(a[i], b[j], acc[i][j]);
        }
        __syncthreads();
    }
#pragma unroll
    for (int i = 0; i < 4; i++) {
        int m = m0 + ty * 4 + i;
        if (m < M) {
#pragma unroll
            for (int j = 0; j < 4; j++) {
                int n = n0 + tx * 4 + j;
                float v = cS * acc[i][j];
                if (E) v = fmaf(eS, E[(long)m * ldE + n], v);
                if (bias) v += bias[n];
                if (relu) v = fmaxf(v, 0.f);
                if (accum) C[(long)m * ldc + n] += v;
                else C[(long)m * ldc + n] = v;
            }
        }
    }
}

// ---------------- bf16 MFMA GEMM: C(fp32) = A(bf16,[M][K]) @ Bt(bf16,[N][K])^T
template<int MT, int NT, int WROWS, int WCOLS>
__global__ __launch_bounds__(256)
void gemm_mfma(const ushort* __restrict__ A, int lda, long sA,
               const ushort* __restrict__ Bt, int ldb, long sB,
               float* __restrict__ C, int ldc, long sC,
               int M, int K,
               const float* __restrict__ bias, int relu, int accum)
{
    constexpr int TM = MT * 16 * WROWS;
    constexpr int TN = NT * 16 * WCOLS;
    constexpr int BKP = 40;
    __shared__ ushort As[TM * BKP];
    __shared__ ushort Bs[TN * BKP];
    A  += (long)blockIdx.z * sA;
    Bt += (long)blockIdx.z * sB;
    C  += (long)blockIdx.z * sC;
    const int t = threadIdx.x;
    const int m0 = blockIdx.y * TM, n0 = blockIdx.x * TN;
    const int w = t >> 6, l = t & 63;
    const int wm = (w / WCOLS) * (MT * 16), wn = (w % WCOLS) * (NT * 16);
    const int lr = l & 15;
    const int lk = (l >> 4) * 8;
    f4 acc[MT][NT] = {};
    for (int k0 = 0; k0 < K; k0 += 32) {
        for (int c = t; c < TM * 4; c += 256) {
            int row = c >> 2, kc = (c & 3) * 8;
            s8b v = *(const s8b*)(A + (long)(m0 + row) * lda + k0 + kc);
            *(s8b*)(&As[row * BKP + kc]) = v;
        }
        for (int c = t; c < TN * 4; c += 256) {
            int row = c >> 2, kc = (c & 3) * 8;
            s8b v = *(const s8b*)(Bt + (long)(n0 + row) * ldb + k0 + kc);
            *(s8b*)(&Bs[row * BKP + kc]) = v;
        }
        __syncthreads();
        s8b af[MT], bf[NT];
#pragma unroll
        for (int i = 0; i < MT; i++) af[i] = *(const s8b*)(&As[(wm + i * 16 + lr) * BKP + lk]);
#pragma unroll
        for (int j = 0; j < NT; j++) bf[j] = *(const s8b*)(&Bs[(wn + j * 16 + lr) * BKP + lk]);
#pragma unroll
        for (int i = 0; i < MT; i++)
#pragma unroll
            for (int j = 0; j < NT; j++)
                acc[i][j] = __builtin_amdgcn_mfma_f32_16x16x32_bf16(af[i], bf[j], acc[i][j], 0, 0, 0);
        __syncthreads();
    }
    const int orow = (l >> 4) * 4;
#pragma unroll
    for (int i = 0; i < MT; i++) {
#pragma unroll
        for (int r = 0; r < 4; r++) {
            int m = m0 + wm + i * 16 + orow + r;
            if (m < M) {
#pragma unroll
                for (int j = 0; j < NT; j++) {
                    int n = n0 + wn + j * 16 + lr;
                    float vv = acc[i][j][r];
                    if (bias) vv += bias[n];
                    if (relu) vv = fmaxf(vv, 0.f);
                    if (accum) C[(long)m * ldc + n] += vv;
                    else C[(long)m * ldc + n] = vv;
                }
            }
        }
    }
}

// ---------------- bf16-in/bf16-out MFMA GEMM, B row-major [K][N]: C16 = bf16(cS*(A@B) + eS*E16)
__global__ __launch_bounds__(256)
void gemm_nn16(const ushort* __restrict__ A, const ushort* __restrict__ B,
               const ushort* __restrict__ E, ushort* __restrict__ C,
               int N, int K, float cS, float eS, long sAB)
{
    __shared__ ushort As[64 * 40];
    __shared__ ushort Bs[64 * 40];
    A += (long)blockIdx.z * sAB;
    B += (long)blockIdx.z * sAB;
    if (E) E += (long)blockIdx.z * sAB;
    C += (long)blockIdx.z * sAB;
    const int t = threadIdx.x;
    const int m0 = blockIdx.y * 64, n0 = blockIdx.x * 64;
    const int w = t >> 6, l = t & 63;
    const int wm = (w >> 1) * 32, wn = (w & 1) * 32;
    const int lr = l & 15, lk = (l >> 4) * 8;
    f4 acc[2][2] = {};
    for (int k0 = 0; k0 < K; k0 += 32) {
        {
            int row = t >> 2, kc = (t & 3) * 8;
            s8b v = *(const s8b*)(A + (long)(m0 + row) * K + k0 + kc);
            *(s8b*)(&As[row * 40 + kc]) = v;
            int kk = t >> 3, nc = (t & 7) * 8;
            s8b vb = *(const s8b*)(B + (long)(k0 + kk) * N + n0 + nc);
#pragma unroll
            for (int j = 0; j < 8; j++) Bs[(nc + j) * 40 + kk] = ((ushort*)&vb)[j];
        }
        __syncthreads();
        s8b af[2], bf[2];
#pragma unroll
        for (int i = 0; i < 2; i++) af[i] = *(const s8b*)(&As[(wm + i * 16 + lr) * 40 + lk]);
#pragma unroll
        for (int j = 0; j < 2; j++) bf[j] = *(const s8b*)(&Bs[(wn + j * 16 + lr) * 40 + lk]);
#pragma unroll
        for (int i = 0; i < 2; i++)
#pragma unroll
            for (int j = 0; j < 2; j++)
                acc[i][j] = __builtin_amdgcn_mfma_f32_16x16x32_bf16(af[i], bf[j], acc[i][j], 0, 0, 0);
        __syncthreads();
    }
    const int orow = (l >> 4) * 4;
#pragma unroll
    for (int i = 0; i < 2; i++)
#pragma unroll
        for (int r = 0; r < 4; r++) {
            int m = m0 + wm + i * 16 + orow + r;
#pragma unroll
            for (int j = 0; j < 2; j++) {
                int n = n0 + wn + j * 16 + lr;
                float vv = cS * acc[i][j][r];
                if (E) vv = fmaf(eS, bf2f(E[(long)m * N + n]), vv);
                C[(long)m * N + n] = f2bf(vv);
            }
        }
}

// ---------------- qkv MFMA GEMM, scatter into bf16 q/k/v [head][NPQ][64], q scaled 1/8
__global__ __launch_bounds__(256)
void gemm_qkv_mfma(const ushort* __restrict__ A, const ushort* __restrict__ Bt,
                   ushort* __restrict__ qo, ushort* __restrict__ ko, ushort* __restrict__ vo)
{
    constexpr int BKP = 40;
    __shared__ ushort As[128 * BKP];
    __shared__ ushort Bs[128 * BKP];
    const int t = threadIdx.x;
    const int m0 = blockIdx.y * 128, n0 = blockIdx.x * 128;
    const int w = t >> 6, l = t & 63;
    const int wm = (w >> 1) * 64, wn = (w & 1) * 64;
    const int lr = l & 15;
    const int lk = (l >> 4) * 8;
    f4 acc[4][4] = {};
    for (int k0 = 0; k0 < 512; k0 += 32) {
        for (int c = t; c < 512; c += 256) {
            int row = c >> 2, kc = (c & 3) * 8;
            s8b va = *(const s8b*)(A + (long)(m0 + row) * 512 + k0 + kc);
            *(s8b*)(&As[row * BKP + kc]) = va;
            s8b vb = *(const s8b*)(Bt + (long)(n0 + row) * 512 + k0 + kc);
            *(s8b*)(&Bs[row * BKP + kc]) = vb;
        }
        __syncthreads();
        s8b af[4], bf[4];
#pragma unroll
        for (int i = 0; i < 4; i++) af[i] = *(const s8b*)(&As[(wm + i * 16 + lr) * BKP + lk]);
#pragma unroll
        for (int j = 0; j < 4; j++) bf[j] = *(const s8b*)(&Bs[(wn + j * 16 + lr) * BKP + lk]);
#pragma unroll
        for (int i = 0; i < 4; i++)
#pragma unroll
            for (int j = 0; j < 4; j++)
                acc[i][j] = __builtin_amdgcn_mfma_f32_16x16x32_bf16(af[i], bf[j], acc[i][j], 0, 0, 0);
        __syncthreads();
    }
    const int orow = (l >> 4) * 4;
#pragma unroll
    for (int i = 0; i < 4; i++) {
#pragma unroll
        for (int r = 0; r < 4; r++) {
            int m = m0 + wm + i * 16 + orow + r;
#pragma unroll
            for (int j = 0; j < 4; j++) {
                int col = n0 + wn + j * 16 + lr;
                int which = col >> 9, h = (col >> 6) & 7, d = col & 63;
                float vv = acc[i][j][r];
                if (which == 0) vv *= 0.125f;
                ushort* dst = which == 0 ? qo : (which == 1 ? ko : vo);
                dst[((long)h * NPQ + m) * 64 + d] = f2bf(vv);
            }
        }
    }
}

// ---------------- flash a3@v with rotation-swizzled Vt
__global__ __launch_bounds__(256)
void k_flash_a3v(const ushort* __restrict__ qlb, const ushort* __restrict__ kg,
                 const ushort* __restrict__ vg,
                 float* __restrict__ pacc, float* __restrict__ pml)
{
    const int c = blockIdx.x;
    const int qt = blockIdx.y;
    const int h = blockIdx.z;
    const int t = threadIdx.x;
    const int w = t >> 6, lane = t & 63;
    const int quad = lane >> 4, l16 = lane & 15;

    __shared__ union {
        struct { ushort Vt[64][40]; ushort Ps[128][40]; } s;
        float Os[128][68];
    } L;

    s8b aq[2][2];
    const ushort* qbase = qlb + ((long)h * 256 + qt * 128 + w * 32) * 64;
#pragma unroll
    for (int mi = 0; mi < 2; mi++)
#pragma unroll
        for (int kf = 0; kf < 2; kf++)
            aq[mi][kf] = *(const s8b*)(qbase + (mi * 16 + l16) * 64 + kf * 32 + quad * 8);

    f4 oacc[2][4] = {};
    float mrow[2][4], lrow[2][4];
#pragma unroll
    for (int mi = 0; mi < 2; mi++)
#pragma unroll
        for (int r = 0; r < 4; r++) { mrow[mi][r] = -INFINITY; lrow[mi][r] = 0.f; }

    const ushort* kh = kg + (long)h * NPQ * 64;
    const ushort* vh = vg + (long)h * NPQ * 64;
    const int key0c = c * 256;

    for (int sub = 0; sub < 8; sub++) {
        int key0 = key0c + sub * 32;
        __syncthreads();
        {
            int kk = t >> 3 & 31;
            int dc = (t & 7) * 8;
            s8b vv = *(const s8b*)(vh + (long)(key0 + kk) * 64 + dc);
            int rot = (dc >> 3) & 3;
            int colp = (kk + rot * 8) & 31;
#pragma unroll
            for (int j = 0; j < 8; j++) L.s.Vt[dc + j][colp] = ((ushort*)&vv)[j];
        }
        s8b bq[2][2];
#pragma unroll
        for (int nj = 0; nj < 2; nj++)
#pragma unroll
            for (int kf = 0; kf < 2; kf++)
                bq[nj][kf] = *(const s8b*)(kh + (long)(key0 + nj * 16 + l16) * 64 + kf * 32 + quad * 8);
        f4 sacc[2][2] = {};
#pragma unroll
        for (int mi = 0; mi < 2; mi++)
#pragma unroll
            for (int nj = 0; nj < 2; nj++) {
                sacc[mi][nj] = __builtin_amdgcn_mfma_f32_16x16x32_bf16(aq[mi][0], bq[nj][0], sacc[mi][nj], 0, 0, 0);
                sacc[mi][nj] = __builtin_amdgcn_mfma_f32_16x16x32_bf16(aq[mi][1], bq[nj][1], sacc[mi][nj], 0, 0, 0);
            }
#pragma unroll
        for (int mi = 0; mi < 2; mi++)
#pragma unroll
            for (int r = 0; r < 4; r++) {
                float mx = fmaxf(sacc[mi][0][r], sacc[mi][1][r]);
#pragma unroll
                for (int d = 1; d < 16; d <<= 1) mx = fmaxf(mx, __shfl_xor(mx, d));
                float mn = fmaxf(mrow[mi][r], mx);
                float f = __expf(mrow[mi][r] - mn);
                float p0 = __expf(sacc[mi][0][r] - mn);
                float p1 = __expf(sacc[mi][1][r] - mn);
                float ps = p0 + p1;
#pragma unroll
                for (int d = 1; d < 16; d <<= 1) ps += __shfl_xor(ps, d);
                lrow[mi][r] = lrow[mi][r] * f + ps;
                mrow[mi][r] = mn;
#pragma unroll
                for (int dj = 0; dj < 4; dj++) oacc[mi][dj][r] *= f;
                int row = w * 32 + mi * 16 + quad * 4 + r;
                L.s.Ps[row][l16]      = f2bf(p0);
                L.s.Ps[row][16 + l16] = f2bf(p1);
            }
        __syncthreads();
        s8b ap[2], bv[4];
#pragma unroll
        for (int mi = 0; mi < 2; mi++)
            ap[mi] = *(const s8b*)(&L.s.Ps[w * 32 + mi * 16 + l16][quad * 8]);
#pragma unroll
        for (int dj = 0; dj < 4; dj++) {
            int d = dj * 16 + l16;
            int rot = (d >> 3) & 3;
            int cb = ((quad + rot) & 3) * 8;
            bv[dj] = *(const s8b*)(&L.s.Vt[d][cb]);
        }
#pragma unroll
        for (int mi = 0; mi < 2; mi++)
#pragma unroll
            for (int dj = 0; dj < 4; dj++)
                oacc[mi][dj] = __builtin_amdgcn_mfma_f32_16x16x32_bf16(ap[mi], bv[dj], oacc[mi][dj], 0, 0, 0);
    }
    __syncthreads();
#pragma unroll
    for (int mi = 0; mi < 2; mi++)
#pragma unroll
        for (int dj = 0; dj < 4; dj++)
#pragma unroll
            for (int r = 0; r < 4; r++)
                L.Os[w * 32 + mi * 16 + quad * 4 + r][dj * 16 + l16] = oacc[mi][dj][r];
    long pbase = (long)(h * 60 + c);
    if (l16 == 0) {
#pragma unroll
        for (int mi = 0; mi < 2; mi++)
#pragma unroll
            for (int r = 0; r < 4; r++) {
                int i = qt * 128 + w * 32 + mi * 16 + quad * 4 + r;
                pml[pbase * 512 + i] = mrow[mi][r];
                pml[pbase * 512 + 256 + i] = lrow[mi][r];
            }
    }
    __syncthreads();
    float* pc = pacc + pbase * 16384 + qt * 128;
    int d = t >> 2, ig = t & 3;
#pragma unroll
    for (int u = 0; u < 8; u++) {
        int i0 = ig * 32 + u * 4;
        float4 v4 = make_float4(L.Os[i0][d], L.Os[i0 + 1][d], L.Os[i0 + 2][d], L.Os[i0 + 3][d]);
        *(float4*)(pc + (long)d * 256 + i0) = v4;
    }
}

// ---------------- fused sim1+softmax+@BmT attention + res-conv; 2-pass softmax (no online chain)
__global__ __launch_bounds__(256)
void k_attn1(const ushort* __restrict__ qg, const ushort* __restrict__ klb,
             const ushort* __restrict__ BmT, const ushort* __restrict__ vg,
             const float* __restrict__ rw, ushort* __restrict__ ohb)
{
    const int m0 = blockIdx.x * 128;
    const int h = blockIdx.y;
    const int t = threadIdx.x;
    const int w = t >> 6, lane = t & 63;
    const int quad = lane >> 4, l16 = lane & 15;

    __shared__ union {
        ushort Ps[2][128][40];
        ushort Os[128][68];
    } L;

    s8b aq[2][2];
    const ushort* qbase = qg + ((long)h * NPQ + 230 + m0 + w * 32) * 64;
#pragma unroll
    for (int mi = 0; mi < 2; mi++)
#pragma unroll
        for (int kf = 0; kf < 2; kf++)
            aq[mi][kf] = *(const s8b*)(qbase + (mi * 16 + l16) * 64 + kf * 32 + quad * 8);

    const ushort* kh = klb + (long)h * 16384;
    const ushort* bmt = BmT + (long)h * 16384;

    // ---- pass 1: per-lane running max over all 256 keys (no cross-lane work inside loop)
    float mx[2][4];
#pragma unroll
    for (int mi = 0; mi < 2; mi++)
#pragma unroll
        for (int r = 0; r < 4; r++) mx[mi][r] = -INFINITY;
    for (int sub = 0; sub < 8; sub++) {
        int key0 = sub * 32;
        s8b bq[2][2];
#pragma unroll
        for (int nj = 0; nj < 2; nj++)
#pragma unroll
            for (int kf = 0; kf < 2; kf++)
                bq[nj][kf] = *(const s8b*)(kh + (long)(key0 + nj * 16 + l16) * 64 + kf * 32 + quad * 8);
        f4 sacc[2][2] = {};
#pragma unroll
        for (int mi = 0; mi < 2; mi++)
#pragma unroll
            for (int nj = 0; nj < 2; nj++) {
                sacc[mi][nj] = __builtin_amdgcn_mfma_f32_16x16x32_bf16(aq[mi][0], bq[nj][0], sacc[mi][nj], 0, 0, 0);
                sacc[mi][nj] = __builtin_amdgcn_mfma_f32_16x16x32_bf16(aq[mi][1], bq[nj][1], sacc[mi][nj], 0, 0, 0);
            }
#pragma unroll
        for (int mi = 0; mi < 2; mi++)
#pragma unroll
            for (int r = 0; r < 4; r++)
                mx[mi][r] = fmaxf(mx[mi][r], fmaxf(sacc[mi][0][r], sacc[mi][1][r]));
    }
    // one max-reduce per row
#pragma unroll
    for (int mi = 0; mi < 2; mi++)
#pragma unroll
        for (int r = 0; r < 4; r++) {
#pragma unroll
            for (int d = 1; d < 16; d <<= 1) mx[mi][r] = fmaxf(mx[mi][r], __shfl_xor(mx[mi][r], d));
        }

    // ---- pass 2: exp with fixed max, per-lane sum, PV MFMA (double-buffered Ps, 1 barrier/subtile)
    f4 oacc[2][4] = {};
    float lsum[2][4] = {};
    for (int sub = 0; sub < 8; sub++) {
        int key0 = sub * 32;
        s8b bq[2][2], bv[4];
#pragma unroll
        for (int nj = 0; nj < 2; nj++)
#pragma unroll
            for (int kf = 0; kf < 2; kf++)
                bq[nj][kf] = *(const s8b*)(kh + (long)(key0 + nj * 16 + l16) * 64 + kf * 32 + quad * 8);
#pragma unroll
        for (int dj = 0; dj < 4; dj++)
            bv[dj] = *(const s8b*)(bmt + (long)(dj * 16 + l16) * 256 + key0 + quad * 8);
        f4 sacc[2][2] = {};
#pragma unroll
        for (int mi = 0; mi < 2; mi++)
#pragma unroll
            for (int nj = 0; nj < 2; nj++) {
                sacc[mi][nj] = __builtin_amdgcn_mfma_f32_16x16x32_bf16(aq[mi][0], bq[nj][0], sacc[mi][nj], 0, 0, 0);
                sacc[mi][nj] = __builtin_amdgcn_mfma_f32_16x16x32_bf16(aq[mi][1], bq[nj][1], sacc[mi][nj], 0, 0, 0);
            }
        int par = sub & 1;
#pragma unroll
        for (int mi = 0; mi < 2; mi++)
#pragma unroll
            for (int r = 0; r < 4; r++) {
                float p0 = __expf(sacc[mi][0][r] - mx[mi][r]);
                float p1 = __expf(sacc[mi][1][r] - mx[mi][r]);
                lsum[mi][r] += p0 + p1;
                int row = w * 32 + mi * 16 + quad * 4 + r;
                L.Ps[par][row][l16]      = f2bf(p0);
                L.Ps[par][row][16 + l16] = f2bf(p1);
            }
        __syncthreads();
        s8b ap[2];
#pragma unroll
        for (int mi = 0; mi < 2; mi++)
            ap[mi] = *(const s8b*)(&L.Ps[par][w * 32 + mi * 16 + l16][quad * 8]);
#pragma unroll
        for (int mi = 0; mi < 2; mi++)
#pragma unroll
            for (int dj = 0; dj < 4; dj++)
                oacc[mi][dj] = __builtin_amdgcn_mfma_f32_16x16x32_bf16(ap[mi], bv[dj], oacc[mi][dj], 0, 0, 0);
    }
    // one sum-reduce per row
#pragma unroll
    for (int mi = 0; mi < 2; mi++)
#pragma unroll
        for (int r = 0; r < 4; r++) {
#pragma unroll
            for (int d = 1; d < 16; d <<= 1) lsum[mi][r] += __shfl_xor(lsum[mi][r], d);
        }
    __syncthreads();   // all Ps reads done -> Os may overwrite
    // normalized attn tile -> LDS bf16, stride 68
#pragma unroll
    for (int mi = 0; mi < 2; mi++)
#pragma unroll
        for (int r = 0; r < 4; r++) {
            float inv = 1.f / lsum[mi][r];
            int row = w * 32 + mi * 16 + quad * 4 + r;
#pragma unroll
            for (int dj = 0; dj < 4; dj++)
                L.Os[row][dj * 16 + l16] = f2bf(oacc[mi][dj][r] * inv);
        }
    __syncthreads();
    // conv phase: wave w owns tokens [m0+w*32, +32), lane = d; two 16-token halves
    const ushort* vh = vg + (long)h * NPQ * 64;
    int tk0 = m0 + w * 32;
#pragma unroll
    for (int half = 0; half < 2; half++) {
        int t0 = tk0 + half * 16;
        int base = 214 + t0;
        float vr[48];
#pragma unroll
        for (int i = 0; i < 48; i++) {
            int src = base + i;
            vr[i] = (src < NP) ? bf2f(vh[(long)src * 64 + lane]) : 0.f;
        }
        float conv[16];
#pragma unroll
        for (int i = 0; i < 16; i++) conv[i] = 0.f;
#pragma unroll
        for (int kk = 0; kk < 33; kk++) {
            float wk = rw[h * 33 + kk];
#pragma unroll
            for (int i = 0; i < 16; i++) conv[i] = fmaf(wk, vr[i + kk], conv[i]);
        }
#pragma unroll
        for (int i = 0; i < 16; i++) {
            int tk = t0 + i;
            if (tk < NTOK) {
                float val = bf2f(L.Os[w * 32 + half * 16 + i][lane]) + conv[i];
                ohb[(long)tk * 512 + h * 64 + lane] = f2bf(val);
            }
        }
    }
}

// ---------------- layernorm over 512, writes bf16 xln (first `pad` rows zero)
__global__ __launch_bounds__(256)
void k_layernorm(const float* __restrict__ h, ushort* __restrict__ xln,
                 const float* __restrict__ g, const float* __restrict__ b, int pad)
{
    int row = blockIdx.x, t = threadIdx.x;
    if (row < pad) {
        xln[(long)row * 512 + t] = 0;
        xln[(long)row * 512 + t + 256] = 0;
        return;
    }
    const float* src = h + (long)(row - pad) * 512;
    float x1 = src[t], x2 = src[t + 256];
    float s = x1 + x2, q = x1 * x1 + x2 * x2;
    __shared__ float rs[4], rq[4], st[2];
    int wid = t >> 6, lane = t & 63;
#pragma unroll
    for (int o = 32; o > 0; o >>= 1) { s += __shfl_down(s, o); q += __shfl_down(q, o); }
    if (lane == 0) { rs[wid] = s; rq[wid] = q; }
    __syncthreads();
    if (t == 0) {
        float S = rs[0] + rs[1] + rs[2] + rs[3];
        float Q = rq[0] + rq[1] + rq[2] + rq[3];
        float mean = S / 512.f;
        float var = Q / 512.f - mean * mean;
        st[0] = mean; st[1] = rsqrtf(var + 1e-5f);
    }
    __syncthreads();
    float mean = st[0], rstd = st[1];
    xln[(long)row * 512 + t] = f2bf((x1 - mean) * rstd * g[t] + b[t]);
    xln[(long)row * 512 + t + 256] = f2bf((x2 - mean) * rstd * g[t + 256] + b[t + 256]);
}

__global__ __launch_bounds__(256)
void k_padcls(float* __restrict__ hbuf, const float* __restrict__ cls)
{
    int i = blockIdx.x, t = threadIdx.x;
    if (i == 0) { hbuf[t] = cls[t]; hbuf[t + 256] = cls[t + 256]; }
    else {
        hbuf[(long)(15000 + i) * 512 + t] = hbuf[(long)i * 512 + t];
        hbuf[(long)(15000 + i) * 512 + t + 256] = hbuf[(long)i * 512 + t + 256];
    }
}

__global__ __launch_bounds__(256)
void k_wT(const float* __restrict__ Wm, ushort* __restrict__ Wt, int K, int N, long sW, long sWt)
{
    Wm += (long)blockIdx.z * sW; Wt += (long)blockIdx.z * sWt;
    __shared__ float tile[32][33];
    int tx = threadIdx.x & 31, ty = threadIdx.x >> 5;
    int n0 = blockIdx.x * 32, k0 = blockIdx.y * 32;
#pragma unroll
    for (int u = 0; u < 4; u++) tile[ty + u * 8][tx] = Wm[(long)(k0 + ty + u * 8) * N + n0 + tx];
    __syncthreads();
#pragma unroll
    for (int u = 0; u < 4; u++) Wt[(long)(n0 + ty + u * 8) * K + k0 + tx] = f2bf(tile[tx][ty + u * 8]);
}

__global__ __launch_bounds__(256)
void k_cvt(const float4* __restrict__ src, ushort4* __restrict__ dst, long n4)
{
    long i = (long)blockIdx.x * 256 + threadIdx.x;
    if (i < n4) {
        float4 v = src[i];
        ushort4 o;
        o.x = f2bf(v.x); o.y = f2bf(v.y); o.z = f2bf(v.z); o.w = f2bf(v.w);
        dst[i] = o;
    }
}

__global__ __launch_bounds__(256)
void k_b2f(const ushort4* __restrict__ src, float4* __restrict__ dst, long n4)
{
    long i = (long)blockIdx.x * 256 + threadIdx.x;
    if (i < n4) {
        ushort4 v = src[i];
        dst[i] = make_float4(bf2f(v.x), bf2f(v.y), bf2f(v.z), bf2f(v.w));
    }
}

__global__ __launch_bounds__(64)
void k_landmarks(const ushort* __restrict__ q, const ushort* __restrict__ k,
                 float* __restrict__ ql, ushort* __restrict__ qlb,
                 float* __restrict__ klT, ushort* __restrict__ klb,
                 unsigned* __restrict__ scal)
{
    int i = blockIdx.x, h = blockIdx.y, d = threadIdx.x;
    if (i == 0 && h == 0 && d == 0) { scal[0] = 0u; scal[1] = 0u; }
    long base = ((long)h * NPQ + (long)i * 60) * 64 + d;
    float sq = 0.f, sk = 0.f;
    for (int j = 0; j < 60; j++) { sq += bf2f(q[base + j * 64]); sk += bf2f(k[base + j * 64]); }
    float qv = sq / 60.f, kv = sk / 60.f;
    ql[((long)h * 256 + i) * 64 + d] = qv;
    qlb[((long)h * 256 + i) * 64 + d] = f2bf(qv);
    klT[((long)h * 64 + d) * 256 + i] = kv;
    klb[((long)h * 256 + i) * 64 + d] = f2bf(kv);
}

__global__ __launch_bounds__(256)
void k_softmax256(float* __restrict__ X, ushort* __restrict__ X16, long headStride)
{
    float* row = X + (long)blockIdx.y * headStride + (long)blockIdx.x * 256;
    int t = threadIdx.x, wid = t >> 6, lane = t & 63;
    float x = row[t];
    __shared__ float rm[4], rsum[4], fin[2];
    float m = x;
#pragma unroll
    for (int o = 32; o > 0; o >>= 1) m = fmaxf(m, __shfl_down(m, o));
    if (lane == 0) rm[wid] = m;
    __syncthreads();
    if (t == 0) fin[0] = fmaxf(fmaxf(rm[0], rm[1]), fmaxf(rm[2], rm[3]));
    __syncthreads();
    float e = __expf(x - fin[0]);
    float s = e;
#pragma unroll
    for (int o = 32; o > 0; o >>= 1) s += __shfl_down(s, o);
    if (lane == 0) rsum[wid] = s;
    __syncthreads();
    if (t == 0) fin[1] = rsum[0] + rsum[1] + rsum[2] + rsum[3];
    __syncthreads();
    float v = e / fin[1];
    row[t] = v;
    if (X16) X16[(long)blockIdx.y * headStride + (long)blockIdx.x * 256 + t] = f2bf(v);
}

__global__ __launch_bounds__(256)
void k_colmax(const float* __restrict__ a2, unsigned* __restrict__ scal)
{
    int h = blockIdx.x, t = threadIdx.x, wid = t >> 6, lane = t & 63;
    const float* A = a2 + (long)h * 65536;
    float cs = 0.f, rs = 0.f;
    for (int i = 0; i < 256; i++) cs += A[(long)i * 256 + t];
    for (int j = 0; j < 256; j++) rs += A[(long)t * 256 + j];
    __shared__ float r1[4], r2[4];
    float m1v = cs, m2v = rs;
#pragma unroll
    for (int o = 32; o > 0; o >>= 1) {
        m1v = fmaxf(m1v, __shfl_down(m1v, o));
        m2v = fmaxf(m2v, __shfl_down(m2v, o));
    }
    if (lane == 0) { r1[wid] = m1v; r2[wid] = m2v; }
    __syncthreads();
    if (t == 0) {
        float a = fmaxf(fmaxf(r1[0], r1[1]), fmaxf(r1[2], r1[3]));
        float b = fmaxf(fmaxf(r2[0], r2[1]), fmaxf(r2[2], r2[3]));
        atomicMax(scal + 0, __float_as_uint(a));
        atomicMax(scal + 1, __float_as_uint(b));
    }
}

__global__ __launch_bounds__(256)
void k_zinit(const float* __restrict__ a2, ushort* __restrict__ zb, const unsigned* __restrict__ scal)
{
    float s = 1.f / (__uint_as_float(scal[0]) * __uint_as_float(scal[1]));
    const float* A = a2 + (long)blockIdx.z * 65536;
    ushort* Z = zb + (long)blockIdx.z * 65536;
    __shared__ float tile[32][33];
    int tx = threadIdx.x & 31, ty = threadIdx.x >> 5;
    int i0 = blockIdx.x * 32, j0 = blockIdx.y * 32;
#pragma unroll
    for (int u = 0; u < 4; u++) tile[ty + u * 8][tx] = A[(long)(j0 + ty + u * 8) * 256 + i0 + tx];
    __syncthreads();
#pragma unroll
    for (int u = 0; u < 4; u++) Z[(long)(i0 + ty + u * 8) * 256 + j0 + tx] = f2bf(tile[tx][ty + u * 8] * s);
}

__global__ __launch_bounds__(256)
void k_a3v_merge(const float* __restrict__ pacc, const float* __restrict__ pml,
                 float* __restrict__ t1)
{
    int d = blockIdx.x, h = blockIdx.y, i = threadIdx.x;
    float M = -INFINITY, L = 0.f, num = 0.f;
    for (int c = 0; c < 60; c++) {
        float mc = pml[(long)(h * 60 + c) * 2 * 256 + i];
        float lc = pml[((long)(h * 60 + c) * 2 + 1) * 256 + i];
        float ac = pacc[((long)(h * 60 + c) * 64 + d) * 256 + i];
        if (mc > M) {
            float f = __expf(M - mc);
            num = num * f + ac; L = L * f + lc; M = mc;
        } else {
            float p = __expf(mc - M);
            num = fmaf(p, ac, num); L = fmaf(p, lc, L);
        }
    }
    t1[((long)h * 256 + i) * 64 + d] = num / L;
}

__global__ __launch_bounds__(256)
void k_cls(const ushort* __restrict__ qb, const float* __restrict__ klT,
           const float* __restrict__ Bm, const ushort* __restrict__ vb,
           const float* __restrict__ rw, float* __restrict__ oh)
{
    int h = blockIdx.x, t = threadIdx.x, wid = t >> 6, lane = t & 63;
    __shared__ float qs[64], p[256], red[256];
    __shared__ float rm[4], rsum[4], fin[2];
    if (t < 64) qs[t] = bf2f(qb[((long)h * NPQ + 230) * 64 + t]);
    __syncthreads();
    float s = 0.f;
    for (int d = 0; d < 64; d++) s = fmaf(qs[d], klT[((long)h * 64 + d) * 256 + t], s);
    float m = s;
#pragma unroll
    for (int o = 32; o > 0; o >>= 1) m = fmaxf(m, __shfl_down(m, o));
    if (lane == 0) rm[wid] = m;
    __syncthreads();
    if (t == 0) fin[0] = fmaxf(fmaxf(rm[0], rm[1]), fmaxf(rm[2], rm[3]));
    __syncthreads();
    float e = __expf(s - fin[0]);
    float ss = e;
#pragma unroll
    for (int o = 32; o > 0; o >>= 1) ss += __shfl_down(ss, o);
    if (lane == 0) rsum[wid] = ss;
    __syncthreads();
    if (t == 0) fin[1] = rsum[0] + rsum[1] + rsum[2] + rsum[3];
    __syncthreads();
    p[t] = e / fin[1];
    __syncthreads();
    int d = t & 63, grp = t >> 6;
    float o = 0.f;
    for (int j = grp * 64; j < grp * 64 + 64; j++) o = fmaf(p[j], Bm[((long)h * 256 + j) * 64 + d], o);
    red[t] = o;
    __syncthreads();
    if (t < 64) {
        float val = red[t] + red[t + 64] + red[t + 128] + red[t + 192];
#pragma unroll
        for (int kk = 0; kk < 33; kk++)
            val = fmaf(rw[h * 33 + kk], bf2f(vb[((long)h * NPQ + 214 + kk) * 64 + t]), val);
        oh[h * 64 + t] = val;
    }
}

__global__ __launch_bounds__(256)
void k_copy4(const float4* __restrict__ src, float4* __restrict__ dst, long n4)
{
    long i = (long)blockIdx.x * 256 + threadIdx.x;
    if (i < n4) dst[i] = src[i];
}

// ---------------- combine w7+w5+w3+identity into wc[49][512], bc = b7+b5+b3
__global__ __launch_bounds__(512)
void k_wcomb(const float* __restrict__ w7, const float* __restrict__ b7,
             const float* __restrict__ w5, const float* __restrict__ b5,
             const float* __restrict__ w3, const float* __restrict__ b3,
             float* __restrict__ wc, float* __restrict__ bc)
{
    int k = blockIdx.x, c = threadIdx.x;
    int kr = k / 7, kc = k % 7;
    float v = w7[c * 49 + k];
    if (kr >= 1 && kr <= 5 && kc >= 1 && kc <= 5) v += w5[c * 25 + (kr - 1) * 5 + (kc - 1)];
    if (kr >= 2 && kr <= 4 && kc >= 2 && kc <= 4) v += w3[c * 9 + (kr - 2) * 3 + (kc - 2)];
    if (k == 24) v += 1.f;
    wc[k * 512 + c] = v;
    if (k == 0) bc[c] = b7[c] + b5[c] + b3[c];
}

// ---------------- PPEG v2: single 7x7 combined depthwise; bf16 LDS tile
__global__ __launch_bounds__(256)
void k_ppeg2(const float* __restrict__ cnn, float* __restrict__ hbuf,
             const float* __restrict__ wc, const float* __restrict__ bc)
{
    __shared__ ushort tile[140][64];
    int t = threadIdx.x;
    int cp = t & 31;
    int g = t >> 5;
    int c0 = blockIdx.x * 8, r0 = blockIdx.y * 4, cb = blockIdx.z * 64;
    for (int idx = t; idx < 140 * 32; idx += 256) {
        int pos = idx >> 5, pp = idx & 31;
        int pr = pos / 14, pc = pos % 14;
        int gr = r0 + pr - 3, gc = c0 + pc - 3;
        float v0 = 0.f, v1 = 0.f;
        if (gr >= 0 && gr < HG && gc >= 0 && gc < HG) {
            const float* src = cnn + (long)(gr * HG + gc) * 512 + cb + pp * 2;
            v0 = src[0]; v1 = src[1];
        }
        tile[pos][pp * 2] = f2bf(v0);
        tile[pos][pp * 2 + 1] = f2bf(v1);
    }
    __syncthreads();
    float acc[4][2] = {};
    for (int kr = 0; kr < 7; kr++)
#pragma unroll
        for (int kc = 0; kc < 7; kc++) {
            float w0 = wc[(kr * 7 + kc) * 512 + cb + cp * 2];
            float w1 = wc[(kr * 7 + kc) * 512 + cb + cp * 2 + 1];
#pragma unroll
            for (int u = 0; u < 4; u++) {
                int p = g * 4 + u;
                int orow = p >> 3, ocol = p & 7;
                unsigned pk = *(const unsigned*)&tile[(orow + kr) * 14 + (ocol + kc)][cp * 2];
                acc[u][0] = fmaf(w0, bf2f((ushort)pk), acc[u][0]);
                acc[u][1] = fmaf(w1, bf2f((ushort)(pk >> 16)), acc[u][1]);
            }
        }
    float b0 = bc[cb + cp * 2], b1 = bc[cb + cp * 2 + 1];
#pragma unroll
    for (int u = 0; u < 4; u++) {
        int p = g * 4 + u;
        int orow = p >> 3, ocol = p & 7;
        int gr = r0 + orow, gc = c0 + ocol;
        if (gr < HG && gc < HG) {
            float* dst = hbuf + (long)(1 + gr * HG + gc) * 512 + cb + cp * 2;
            dst[0] = acc[u][0] + b0;
            dst[1] = acc[u][1] + b1;
        }
    }
}

__global__ __launch_bounds__(256)
void k_final(const float* __restrict__ hbuf, const float* __restrict__ g,
             const float* __restrict__ b, const float* __restrict__ W2,
             const float* __restrict__ b2, float* __restrict__ out)
{
    __shared__ float y[512];
    __shared__ float rs[4], rq[4], st[2], lg[8];
    int t = threadIdx.x, wid = t >> 6, lane = t & 63;
    float x1 = hbuf[t], x2 = hbuf[t + 256];
    float s = x1 + x2, q = x1 * x1 + x2 * x2;
#pragma unroll
    for (int o = 32; o > 0; o >>= 1) { s += __shfl_down(s, o); q += __shfl_down(q, o); }
    if (lane == 0) { rs[wid] = s; rq[wid] = q; }
    __syncthreads();
    if (t == 0) {
        float S = rs[0] + rs[1] + rs[2] + rs[3];
        float Q = rq[0] + rq[1] + rq[2] + rq[3];
        float mean = S / 512.f;
        float var = Q / 512.f - mean * mean;
        st[0] = mean; st[1] = rsqrtf(var + 1e-5f);
    }
    __syncthreads();
    float mean = st[0], rstd = st[1];
    y[t] = (x1 - mean) * rstd * g[t] + b[t];
    y[t + 256] = (x2 - mean) * rstd * g[t + 256] + b[t + 256];
    __syncthreads();
    if (t < 5) {
        float acc = b2[t];
        for (int kx = 0; kx < 512; kx++) acc = fmaf(y[kx], W2[kx * 5 + t], acc);
        lg[t] = acc;
    }
    __syncthreads();
    if (t == 0) {
        float mx = lg[0]; int am = 0;
        for (int j = 1; j < 5; j++) if (lg[j] > mx) { mx = lg[j]; am = j; }
        float e[5], se = 0.f;
        for (int j = 0; j < 5; j++) { e[j] = __expf(lg[j] - mx); se += e[j]; }
        for (int j = 0; j < 5; j++) { out[j] = lg[j]; out[5 + j] = e[j] / se; }
        out[10] = (float)am;
    }
}

extern "C" void kernel_launch(void* const* d_in, const int* in_sizes, int n_in,
                              void* d_out, int out_size, void* d_ws, size_t ws_size,
                              hipStream_t stream)
{
    const float* data  = (const float*)d_in[0];
    const float* Wfc1  = (const float*)d_in[1];
    const float* bfc1  = (const float*)d_in[2];
    const float* cls   = (const float*)d_in[3];
    const float* ln1g  = (const float*)d_in[4];
    const float* ln1b  = (const float*)d_in[5];
    const float* qkv1  = (const float*)d_in[6];
    const float* out1w = (const float*)d_in[7];
    const float* out1b = (const float*)d_in[8];
    const float* res1  = (const float*)d_in[9];
    const float* w7    = (const float*)d_in[10];
    const float* b7    = (const float*)d_in[11];
    const float* w5    = (const float*)d_in[12];
    const float* b5    = (const float*)d_in[13];
    const float* w3    = (const float*)d_in[14];
    const float* b3    = (const float*)d_in[15];
    const float* ln2g  = (const float*)d_in[16];
    const float* ln2b  = (const float*)d_in[17];
    const float* qkv2  = (const float*)d_in[18];
    const float* out2w = (const float*)d_in[19];
    const float* out2b = (const float*)d_in[20];
    const float* res2  = (const float*)d_in[21];
    const float* normg = (const float*)d_in[22];
    const float* normb = (const float*)d_in[23];
    const float* Wfc2  = (const float*)d_in[24];
    const float* bfc2  = (const float*)d_in[25];
    float* out = (float*)d_out;

    float* W = (float*)d_ws;
    size_t off = 0;
    auto alloc = [&](size_t n) { size_t o = off; off += (n + 255) & ~(size_t)255; return o; };
    float*  hbuf   = W + alloc((size_t)NTOK * 512);
    float*  ohreg  = W + alloc((size_t)15232 * 512);
    float*  oh     = ohreg;
    ushort* xln    = (ushort*)ohreg;
    ushort* qb16   = (ushort*)(W + alloc((size_t)8 * NPQ * 32));
    ushort* kb16   = (ushort*)(W + alloc((size_t)8 * NPQ * 32));
    ushort* vb16   = (ushort*)(W + alloc((size_t)8 * NPQ * 32));
    float*  ql     = W + alloc(8 * 256 * 64);
    ushort* qlb    = (ushort*)(W + alloc(8 * 256 * 32));
    float*  klT    = W + alloc(8 * 64 * 256);
    ushort* klb    = (ushort*)(W + alloc(8 * 256 * 32));
    float*  a2     = W + alloc(8 * 65536);
    ushort* a2b    = (ushort*)(W + alloc(8 * 32768));
    ushort* zb0    = (ushort*)(W + alloc(8 * 32768));
    ushort* zb1    = (ushort*)(W + alloc(8 * 32768));
    ushort* m1b    = (ushort*)(W + alloc(8 * 32768));
    ushort* mab    = (ushort*)(W + alloc(8 * 32768));
    ushort* mbb    = (ushort*)(W + alloc(8 * 32768));
    float*  z0     = W + alloc(8 * 65536);
    float*  t1     = W + alloc(8 * 256 * 64);
    float*  Bm     = W + alloc(8 * 256 * 64);
    ushort* BmbT   = (ushort*)(W + alloc(8 * 256 * 32));   // bf16 BmT [h][64][256]
    float*  scal   = W + alloc(64);
    ushort* ohb16  = (ushort*)(W + alloc((size_t)15232 * 256));
    ushort* WfcT   = (ushort*)(W + alloc(1024 * 256));
    ushort* qkv1T  = (ushort*)(W + alloc(1536 * 256));
    ushort* qkv2T  = (ushort*)(W + alloc(1536 * 256));
    ushort* out1T  = (ushort*)(W + alloc(512 * 256));
    ushort* out2T  = (ushort*)(W + alloc(512 * 256));
    float*  wc     = W + alloc(49 * 512);
    float*  bc     = W + alloc(512);
    float*  big    = W + alloc(8110080);   // datab | pacc+pml | ppeg cnn
    ushort* datab  = (ushort*)big;
    float*  pacc   = big;
    float*  pml    = big + 7864320;
    float*  cnn    = big;
    if (ws_size < off * sizeof(float)) return;

    k_wT<<<dim3(16, 32, 1), 256, 0, stream>>>(Wfc1, WfcT, 1024, 512, 0, 0);
    k_wT<<<dim3(48, 16, 1), 256, 0, stream>>>(qkv1, qkv1T, 512, 1536, 0, 0);
    k_wT<<<dim3(48, 16, 1), 256, 0, stream>>>(qkv2, qkv2T, 512, 1536, 0, 0);
    k_wT<<<dim3(16, 16, 1), 256, 0, stream>>>(out1w, out1T, 512, 512, 0, 0);
    k_wT<<<dim3(16, 16, 1), 256, 0, stream>>>(out2w, out2T, 512, 512, 0, 0);
    k_wcomb<<<49, 512, 0, stream>>>(w7, b7, w5, b5, w3, b3, wc, bc);
    k_cvt<<<15000, 256, 0, stream>>>((const float4*)data, (ushort4*)datab, 3840000);
    gemm_mfma<4, 4, 2, 2><<<dim3(4, 118, 1), 256, 0, stream>>>(
        datab, 1024, 0, WfcT, 1024, 0, hbuf + 512, 512, 0, 15000, 1024, bfc1, 1, 0);
    k_padcls<<<130, 256, 0, stream>>>(hbuf, cls);

    auto layer = [&](const float* lng, const float* lnb, const ushort* qkvT,
                     const float* outW, const ushort* outT, const float* outB,
                     const float* resW, bool full) {
        k_layernorm<<<NP, 256, 0, stream>>>(hbuf, xln, lng, lnb, 230);
        gemm_qkv_mfma<<<dim3(12, 120, 1), 256, 0, stream>>>(xln, qkvT, qb16, kb16, vb16);
        k_landmarks<<<dim3(256, 8), 64, 0, stream>>>(qb16, kb16, ql, qlb, klT, klb, (unsigned*)scal);
        gemm_f32<<<dim3(4, 4, 8), 256, 0, stream>>>(ql, 64, 16384, klT, 256, 16384,
            a2, 256, 65536, 256, 256, 64, nullptr, nullptr, 0, 0, 0.f, 1.f, 0, 0);
        k_softmax256<<<dim3(256, 8), 256, 0, stream>>>(a2, a2b, 65536);
        k_colmax<<<8, 256, 0, stream>>>(a2, (unsigned*)scal);
        k_zinit<<<dim3(8, 8, 8), 256, 0, stream>>>(a2, zb0, (const unsigned*)scal);
        // pinv: all 6 iterations bf16 MFMA
        ushort* zbi = zb0; ushort* zbo = zb1;
        for (int it = 0; it < 6; ++it) {
            gemm_nn16<<<dim3(4, 4, 8), 256, 0, stream>>>(a2b, zbi, nullptr, m1b, 256, 256, 1.f, 0.f, 65536);
            gemm_nn16<<<dim3(4, 4, 8), 256, 0, stream>>>(m1b, m1b, m1b, mab, 256, 256, -1.f, 7.f, 65536);
            gemm_nn16<<<dim3(4, 4, 8), 256, 0, stream>>>(m1b, mab, m1b, mbb, 256, 256, -1.f, 15.f, 65536);
            gemm_nn16<<<dim3(4, 4, 8), 256, 0, stream>>>(zbi, mbb, zbi, zbo, 256, 256, -0.25f, 3.25f, 65536);
            ushort* tmp = zbi; zbi = zbo; zbo = tmp;
        }
        k_b2f<<<512, 256, 0, stream>>>((const ushort4*)zbi, (float4*)z0, 131072);
        k_flash_a3v<<<dim3(60, 2, 8), 256, 0, stream>>>(qlb, kb16, vb16, pacc, pml);
        k_a3v_merge<<<dim3(64, 8), 256, 0, stream>>>(pacc, pml, t1);
        gemm_f32<<<dim3(1, 4, 8), 256, 0, stream>>>(z0, 256, 65536, t1, 64, 16384,
            Bm, 64, 16384, 256, 64, 256, nullptr, nullptr, 0, 0, 0.f, 1.f, 0, 0);
        if (full) {
            k_wT<<<dim3(2, 8, 8), 256, 0, stream>>>(Bm, BmbT, 256, 64, 16384, 16384);
            k_attn1<<<dim3(119, 8), 256, 0, stream>>>(qb16, klb, BmbT, vb16, resW, ohb16);
            gemm_mfma<4, 4, 2, 2><<<dim3(4, 119, 1), 256, 0, stream>>>(
                ohb16, 512, 0, outT, 512, 0, hbuf, 512, 0, NTOK, 512, outB, 0, 1);
        } else {
            k_cls<<<8, 256, 0, stream>>>(qb16, klT, Bm, vb16, resW, oh);
            gemm_f32<<<dim3(8, 1, 1), 256, 0, stream>>>(oh, 512, 0, outW, 512, 0,
                hbuf, 512, 0, 1, 512, 512, outB, nullptr, 0, 0, 0.f, 1.f, 0, 1);
        }
    };

    layer(ln1g, ln1b, qkv1T, out1w, out1T, out1b, res1, true);
    k_copy4<<<(1936512 + 255) / 256, 256, 0, stream>>>((const float4*)(hbuf + 512), (float4*)cnn, 1936512);
    k_ppeg2<<<dim3(16, 31, 8), 256, 0, stream>>>(cnn, hbuf, wc, bc);
    layer(ln2g, ln2b, qkv2T, out2w, out2T, out2b, res2, false);
    k_final<<<1, 256, 0, stream>>>(hbuf, normg, normb, Wfc2, bfc2, out);
}

// Round 8
// 1317.062 us; speedup vs baseline: 2.5732x; 1.0614x over previous
//
#include <hip/hip_runtime.h>
#include <math.h>

#define NP 15360
#define NPQ 15488
#define NTOK 15130
#define HG 123

typedef __attribute__((ext_vector_type(8))) short s8b;
typedef __attribute__((ext_vector_type(4))) float f4;

__device__ inline float bf2f(ushort u) { return __uint_as_float(((unsigned)u) << 16); }
__device__ inline ushort f2bf(float f) {
    unsigned u = __float_as_uint(f);
    unsigned r = (u + 0x7fffu + ((u >> 16) & 1u)) >> 16;
    return (ushort)r;
}

// ---------------- generic fp32 GEMM (small/sensitive ops): C = cS*(A@B) + eS*E + bias
__global__ __launch_bounds__(256)
void gemm_f32(const float* __restrict__ A, int lda, long sA,
              const float* __restrict__ B, int ldb, long sB,
              float* __restrict__ C, int ldc, long sC,
              int M, int N, int K,
              const float* __restrict__ bias,
              const float* __restrict__ E, int ldE, long sE, float eS,
              float cS, int relu, int accum)
{
    A += (long)blockIdx.z * sA;
    B += (long)blockIdx.z * sB;
    C += (long)blockIdx.z * sC;
    if (E) E += (long)blockIdx.z * sE;
    const int m0 = blockIdx.y * 64, n0 = blockIdx.x * 64;
    const int t = threadIdx.x;
    const int tx = t & 15, ty = t >> 4;
    __shared__ float As[16][64];
    __shared__ float Bs[16][64];
    float acc[4][4] = {};
    const int arow = t >> 2, akc = (t & 3) * 4;
    const int brow = t >> 4, bnc = (t & 15) * 4;
    for (int k0 = 0; k0 < K; k0 += 16) {
        float4 av = make_float4(0.f, 0.f, 0.f, 0.f);
        if (m0 + arow < M) av = *(const float4*)(A + (long)(m0 + arow) * lda + k0 + akc);
        As[akc + 0][arow] = av.x; As[akc + 1][arow] = av.y;
        As[akc + 2][arow] = av.z; As[akc + 3][arow] = av.w;
        float4 bv = *(const float4*)(B + (long)(k0 + brow) * ldb + n0 + bnc);
        *(float4*)&Bs[brow][bnc] = bv;
        __syncthreads();
#pragma unroll
        for (int kk = 0; kk < 16; ++kk) {
            float4 a4 = *(const float4*)&As[kk][ty * 4];
            float4 b4 = *(const float4*)&Bs[kk][tx * 4];
            float a[4] = {a4.x, a4.y, a4.z, a4.w};
            float b[4] = {b4.x, b4.y, b4.z, b4.w};
#pragma unroll
            for (int i = 0; i < 4; i++)
#pragma unroll
                for (int j = 0; j < 4; j++) acc[i][j] = fmaf(a[i], b[j], acc[i][j]);
        }
        __syncthreads();
    }
#pragma unroll
    for (int i = 0; i < 4; i++) {
        int m = m0 + ty * 4 + i;
        if (m < M) {
#pragma unroll
            for (int j = 0; j < 4; j++) {
                int n = n0 + tx * 4 + j;
                float v = cS * acc[i][j];
                if (E) v = fmaf(eS, E[(long)m * ldE + n], v);
                if (bias) v += bias[n];
                if (relu) v = fmaxf(v, 0.f);
                if (accum) C[(long)m * ldc + n] += v;
                else C[(long)m * ldc + n] = v;
            }
        }
    }
}

// ---------------- bf16 MFMA GEMM: C(fp32) = A(bf16,[M][K]) @ Bt(bf16,[N][K])^T
template<int MT, int NT, int WROWS, int WCOLS>
__global__ __launch_bounds__(256)
void gemm_mfma(const ushort* __restrict__ A, int lda, long sA,
               const ushort* __restrict__ Bt, int ldb, long sB,
               float* __restrict__ C, int ldc, long sC,
               int M, int K,
               const float* __restrict__ bias, int relu, int accum)
{
    constexpr int TM = MT * 16 * WROWS;
    constexpr int TN = NT * 16 * WCOLS;
    constexpr int BKP = 40;
    __shared__ ushort As[TM * BKP];
    __shared__ ushort Bs[TN * BKP];
    A  += (long)blockIdx.z * sA;
    Bt += (long)blockIdx.z * sB;
    C  += (long)blockIdx.z * sC;
    const int t = threadIdx.x;
    const int m0 = blockIdx.y * TM, n0 = blockIdx.x * TN;
    const int w = t >> 6, l = t & 63;
    const int wm = (w / WCOLS) * (MT * 16), wn = (w % WCOLS) * (NT * 16);
    const int lr = l & 15;
    const int lk = (l >> 4) * 8;
    f4 acc[MT][NT] = {};
    for (int k0 = 0; k0 < K; k0 += 32) {
        for (int c = t; c < TM * 4; c += 256) {
            int row = c >> 2, kc = (c & 3) * 8;
            s8b v = *(const s8b*)(A + (long)(m0 + row) * lda + k0 + kc);
            *(s8b*)(&As[row * BKP + kc]) = v;
        }
        for (int c = t; c < TN * 4; c += 256) {
            int row = c >> 2, kc = (c & 3) * 8;
            s8b v = *(const s8b*)(Bt + (long)(n0 + row) * ldb + k0 + kc);
            *(s8b*)(&Bs[row * BKP + kc]) = v;
        }
        __syncthreads();
        s8b af[MT], bf[NT];
#pragma unroll
        for (int i = 0; i < MT; i++) af[i] = *(const s8b*)(&As[(wm + i * 16 + lr) * BKP + lk]);
#pragma unroll
        for (int j = 0; j < NT; j++) bf[j] = *(const s8b*)(&Bs[(wn + j * 16 + lr) * BKP + lk]);
#pragma unroll
        for (int i = 0; i < MT; i++)
#pragma unroll
            for (int j = 0; j < NT; j++)
                acc[i][j] = __builtin_amdgcn_mfma_f32_16x16x32_bf16(af[i], bf[j], acc[i][j], 0, 0, 0);
        __syncthreads();
    }
    const int orow = (l >> 4) * 4;
#pragma unroll
    for (int i = 0; i < MT; i++) {
#pragma unroll
        for (int r = 0; r < 4; r++) {
            int m = m0 + wm + i * 16 + orow + r;
            if (m < M) {
#pragma unroll
                for (int j = 0; j < NT; j++) {
                    int n = n0 + wn + j * 16 + lr;
                    float vv = acc[i][j][r];
                    if (bias) vv += bias[n];
                    if (relu) vv = fmaxf(vv, 0.f);
                    if (accum) C[(long)m * ldc + n] += vv;
                    else C[(long)m * ldc + n] = vv;
                }
            }
        }
    }
}

// ---------------- bf16-in/bf16-out MFMA GEMM, B row-major [K][N]: C16 = bf16(cS*(A@B) + eS*E16)
__global__ __launch_bounds__(256)
void gemm_nn16(const ushort* __restrict__ A, const ushort* __restrict__ B,
               const ushort* __restrict__ E, ushort* __restrict__ C,
               int N, int K, float cS, float eS, long sAB)
{
    __shared__ ushort As[64 * 40];
    __shared__ ushort Bs[64 * 40];
    A += (long)blockIdx.z * sAB;
    B += (long)blockIdx.z * sAB;
    if (E) E += (long)blockIdx.z * sAB;
    C += (long)blockIdx.z * sAB;
    const int t = threadIdx.x;
    const int m0 = blockIdx.y * 64, n0 = blockIdx.x * 64;
    const int w = t >> 6, l = t & 63;
    const int wm = (w >> 1) * 32, wn = (w & 1) * 32;
    const int lr = l & 15, lk = (l >> 4) * 8;
    f4 acc[2][2] = {};
    for (int k0 = 0; k0 < K; k0 += 32) {
        {
            int row = t >> 2, kc = (t & 3) * 8;
            s8b v = *(const s8b*)(A + (long)(m0 + row) * K + k0 + kc);
            *(s8b*)(&As[row * 40 + kc]) = v;
            int kk = t >> 3, nc = (t & 7) * 8;
            s8b vb = *(const s8b*)(B + (long)(k0 + kk) * N + n0 + nc);
#pragma unroll
            for (int j = 0; j < 8; j++) Bs[(nc + j) * 40 + kk] = ((ushort*)&vb)[j];
        }
        __syncthreads();
        s8b af[2], bf[2];
#pragma unroll
        for (int i = 0; i < 2; i++) af[i] = *(const s8b*)(&As[(wm + i * 16 + lr) * 40 + lk]);
#pragma unroll
        for (int j = 0; j < 2; j++) bf[j] = *(const s8b*)(&Bs[(wn + j * 16 + lr) * 40 + lk]);
#pragma unroll
        for (int i = 0; i < 2; i++)
#pragma unroll
            for (int j = 0; j < 2; j++)
                acc[i][j] = __builtin_amdgcn_mfma_f32_16x16x32_bf16(af[i], bf[j], acc[i][j], 0, 0, 0);
        __syncthreads();
    }
    const int orow = (l >> 4) * 4;
#pragma unroll
    for (int i = 0; i < 2; i++)
#pragma unroll
        for (int r = 0; r < 4; r++) {
            int m = m0 + wm + i * 16 + orow + r;
#pragma unroll
            for (int j = 0; j < 2; j++) {
                int n = n0 + wn + j * 16 + lr;
                float vv = cS * acc[i][j][r];
                if (E) vv = fmaf(eS, bf2f(E[(long)m * N + n]), vv);
                C[(long)m * N + n] = f2bf(vv);
            }
        }
}

// ---------------- qkv MFMA GEMM, scatter into bf16 q/k/v [head][NPQ][64], q scaled 1/8
__global__ __launch_bounds__(256)
void gemm_qkv_mfma(const ushort* __restrict__ A, const ushort* __restrict__ Bt,
                   ushort* __restrict__ qo, ushort* __restrict__ ko, ushort* __restrict__ vo)
{
    constexpr int BKP = 40;
    __shared__ ushort As[128 * BKP];
    __shared__ ushort Bs[128 * BKP];
    const int t = threadIdx.x;
    const int m0 = blockIdx.y * 128, n0 = blockIdx.x * 128;
    const int w = t >> 6, l = t & 63;
    const int wm = (w >> 1) * 64, wn = (w & 1) * 64;
    const int lr = l & 15;
    const int lk = (l >> 4) * 8;
    f4 acc[4][4] = {};
    for (int k0 = 0; k0 < 512; k0 += 32) {
        for (int c = t; c < 512; c += 256) {
            int row = c >> 2, kc = (c & 3) * 8;
            s8b va = *(const s8b*)(A + (long)(m0 + row) * 512 + k0 + kc);
            *(s8b*)(&As[row * BKP + kc]) = va;
            s8b vb = *(const s8b*)(Bt + (long)(n0 + row) * 512 + k0 + kc);
            *(s8b*)(&Bs[row * BKP + kc]) = vb;
        }
        __syncthreads();
        s8b af[4], bf[4];
#pragma unroll
        for (int i = 0; i < 4; i++) af[i] = *(const s8b*)(&As[(wm + i * 16 + lr) * BKP + lk]);
#pragma unroll
        for (int j = 0; j < 4; j++) bf[j] = *(const s8b*)(&Bs[(wn + j * 16 + lr) * BKP + lk]);
#pragma unroll
        for (int i = 0; i < 4; i++)
#pragma unroll
            for (int j = 0; j < 4; j++)
                acc[i][j] = __builtin_amdgcn_mfma_f32_16x16x32_bf16(af[i], bf[j], acc[i][j], 0, 0, 0);
        __syncthreads();
    }
    const int orow = (l >> 4) * 4;
#pragma unroll
    for (int i = 0; i < 4; i++) {
#pragma unroll
        for (int r = 0; r < 4; r++) {
            int m = m0 + wm + i * 16 + orow + r;
#pragma unroll
            for (int j = 0; j < 4; j++) {
                int col = n0 + wn + j * 16 + lr;
                int which = col >> 9, h = (col >> 6) & 7, d = col & 63;
                float vv = acc[i][j][r];
                if (which == 0) vv *= 0.125f;
                ushort* dst = which == 0 ? qo : (which == 1 ? ko : vo);
                dst[((long)h * NPQ + m) * 64 + d] = f2bf(vv);
            }
        }
    }
}

// ---------------- flash a3@v, MAX-FREE (scores |s|<~1): p=exp(s), lsum via ones-MFMA, no shuffles
__global__ __launch_bounds__(256)
void k_flash_a3v(const ushort* __restrict__ qlb, const ushort* __restrict__ kg,
                 const ushort* __restrict__ vg,
                 float* __restrict__ pacc, float* __restrict__ pml)
{
    const int c = blockIdx.x;
    const int qt = blockIdx.y;
    const int h = blockIdx.z;
    const int t = threadIdx.x;
    const int w = t >> 6, lane = t & 63;
    const int quad = lane >> 4, l16 = lane & 15;
    const s8b vones = {0x3F80, 0x3F80, 0x3F80, 0x3F80, 0x3F80, 0x3F80, 0x3F80, 0x3F80};

    __shared__ union {
        struct { ushort Vt[64][40]; ushort Ps[128][40]; } s;
        float Os[128][68];
    } L;

    s8b aq[2][2];
    const ushort* qbase = qlb + ((long)h * 256 + qt * 128 + w * 32) * 64;
#pragma unroll
    for (int mi = 0; mi < 2; mi++)
#pragma unroll
        for (int kf = 0; kf < 2; kf++)
            aq[mi][kf] = *(const s8b*)(qbase + (mi * 16 + l16) * 64 + kf * 32 + quad * 8);

    f4 oacc[2][4] = {};
    f4 lacc[2] = {};

    const ushort* kh = kg + (long)h * NPQ * 64;
    const ushort* vh = vg + (long)h * NPQ * 64;
    const int key0c = c * 256;

    for (int sub = 0; sub < 8; sub++) {
        int key0 = key0c + sub * 32;
        __syncthreads();
        {   // swizzled V^T stage
            int kk = t >> 3 & 31;
            int dc = (t & 7) * 8;
            s8b vv = *(const s8b*)(vh + (long)(key0 + kk) * 64 + dc);
            int rot = (dc >> 3) & 3;
            int colp = (kk + rot * 8) & 31;
#pragma unroll
            for (int j = 0; j < 8; j++) L.s.Vt[dc + j][colp] = ((ushort*)&vv)[j];
        }
        s8b bq[2][2];
#pragma unroll
        for (int nj = 0; nj < 2; nj++)
#pragma unroll
            for (int kf = 0; kf < 2; kf++)
                bq[nj][kf] = *(const s8b*)(kh + (long)(key0 + nj * 16 + l16) * 64 + kf * 32 + quad * 8);
        f4 sacc[2][2] = {};
#pragma unroll
        for (int mi = 0; mi < 2; mi++)
#pragma unroll
            for (int nj = 0; nj < 2; nj++) {
                sacc[mi][nj] = __builtin_amdgcn_mfma_f32_16x16x32_bf16(aq[mi][0], bq[nj][0], sacc[mi][nj], 0, 0, 0);
                sacc[mi][nj] = __builtin_amdgcn_mfma_f32_16x16x32_bf16(aq[mi][1], bq[nj][1], sacc[mi][nj], 0, 0, 0);
            }
#pragma unroll
        for (int mi = 0; mi < 2; mi++)
#pragma unroll
            for (int r = 0; r < 4; r++) {
                int row = w * 32 + mi * 16 + quad * 4 + r;
                L.s.Ps[row][l16]      = f2bf(__expf(sacc[mi][0][r]));
                L.s.Ps[row][16 + l16] = f2bf(__expf(sacc[mi][1][r]));
            }
        __syncthreads();
        s8b ap[2], bv[4];
#pragma unroll
        for (int mi = 0; mi < 2; mi++)
            ap[mi] = *(const s8b*)(&L.s.Ps[w * 32 + mi * 16 + l16][quad * 8]);
#pragma unroll
        for (int dj = 0; dj < 4; dj++) {
            int d = dj * 16 + l16;
            int rot = (d >> 3) & 3;
            int cb = ((quad + rot) & 3) * 8;
            bv[dj] = *(const s8b*)(&L.s.Vt[d][cb]);
        }
#pragma unroll
        for (int mi = 0; mi < 2; mi++) {
#pragma unroll
            for (int dj = 0; dj < 4; dj++)
                oacc[mi][dj] = __builtin_amdgcn_mfma_f32_16x16x32_bf16(ap[mi], bv[dj], oacc[mi][dj], 0, 0, 0);
            lacc[mi] = __builtin_amdgcn_mfma_f32_16x16x32_bf16(ap[mi], vones, lacc[mi], 0, 0, 0);
        }
    }
    __syncthreads();
#pragma unroll
    for (int mi = 0; mi < 2; mi++)
#pragma unroll
        for (int dj = 0; dj < 4; dj++)
#pragma unroll
            for (int r = 0; r < 4; r++)
                L.Os[w * 32 + mi * 16 + quad * 4 + r][dj * 16 + l16] = oacc[mi][dj][r];
    long pbase = (long)(h * 60 + c);
    if (l16 == 0) {
#pragma unroll
        for (int mi = 0; mi < 2; mi++)
#pragma unroll
            for (int r = 0; r < 4; r++) {
                int i = qt * 128 + w * 32 + mi * 16 + quad * 4 + r;
                pml[pbase * 512 + i] = 0.f;
                pml[pbase * 512 + 256 + i] = lacc[mi][r];
            }
    }
    __syncthreads();
    float* pc = pacc + pbase * 16384 + qt * 128;
    int d = t >> 2, ig = t & 3;
#pragma unroll
    for (int u = 0; u < 8; u++) {
        int i0 = ig * 32 + u * 4;
        float4 v4 = make_float4(L.Os[i0][d], L.Os[i0 + 1][d], L.Os[i0 + 2][d], L.Os[i0 + 3][d]);
        *(float4*)(pc + (long)d * 256 + i0) = v4;
    }
}

// ---------------- fused sim1+softmax+@BmT attention + res-conv; MAX-FREE single pass,
// wave-local Ps (no barriers in K-loop), lsum via ones-MFMA (no shuffles)
__global__ __launch_bounds__(256)
void k_attn1(const ushort* __restrict__ qg, const ushort* __restrict__ klb,
             const ushort* __restrict__ BmT, const ushort* __restrict__ vg,
             const float* __restrict__ rw, ushort* __restrict__ ohb)
{
    const int m0 = blockIdx.x * 128;
    const int h = blockIdx.y;
    const int t = threadIdx.x;
    const int w = t >> 6, lane = t & 63;
    const int quad = lane >> 4, l16 = lane & 15;
    const s8b vones = {0x3F80, 0x3F80, 0x3F80, 0x3F80, 0x3F80, 0x3F80, 0x3F80, 0x3F80};

    __shared__ union {
        ushort Ps[2][128][40];
        ushort Os[128][68];
    } L;

    s8b aq[2][2];
    const ushort* qbase = qg + ((long)h * NPQ + 230 + m0 + w * 32) * 64;
#pragma unroll
    for (int mi = 0; mi < 2; mi++)
#pragma unroll
        for (int kf = 0; kf < 2; kf++)
            aq[mi][kf] = *(const s8b*)(qbase + (mi * 16 + l16) * 64 + kf * 32 + quad * 8);

    const ushort* kh = klb + (long)h * 16384;
    const ushort* bmt = BmT + (long)h * 16384;

    f4 oacc[2][4] = {};
    f4 lacc[2] = {};
#pragma unroll
    for (int sub = 0; sub < 8; sub++) {
        int key0 = sub * 32;
        s8b bq[2][2], bv[4];
#pragma unroll
        for (int nj = 0; nj < 2; nj++)
#pragma unroll
            for (int kf = 0; kf < 2; kf++)
                bq[nj][kf] = *(const s8b*)(kh + (long)(key0 + nj * 16 + l16) * 64 + kf * 32 + quad * 8);
#pragma unroll
        for (int dj = 0; dj < 4; dj++)
            bv[dj] = *(const s8b*)(bmt + (long)(dj * 16 + l16) * 256 + key0 + quad * 8);
        f4 sacc[2][2] = {};
#pragma unroll
        for (int mi = 0; mi < 2; mi++)
#pragma unroll
            for (int nj = 0; nj < 2; nj++) {
                sacc[mi][nj] = __builtin_amdgcn_mfma_f32_16x16x32_bf16(aq[mi][0], bq[nj][0], sacc[mi][nj], 0, 0, 0);
                sacc[mi][nj] = __builtin_amdgcn_mfma_f32_16x16x32_bf16(aq[mi][1], bq[nj][1], sacc[mi][nj], 0, 0, 0);
            }
        int par = sub & 1;
        // wave-local Ps: each wave writes & reads only rows [w*32, w*32+32) -> no barrier
#pragma unroll
        for (int mi = 0; mi < 2; mi++)
#pragma unroll
            for (int r = 0; r < 4; r++) {
                int row = w * 32 + mi * 16 + quad * 4 + r;
                L.Ps[par][row][l16]      = f2bf(__expf(sacc[mi][0][r]));
                L.Ps[par][row][16 + l16] = f2bf(__expf(sacc[mi][1][r]));
            }
        s8b ap[2];
#pragma unroll
        for (int mi = 0; mi < 2; mi++)
            ap[mi] = *(const s8b*)(&L.Ps[par][w * 32 + mi * 16 + l16][quad * 8]);
#pragma unroll
        for (int mi = 0; mi < 2; mi++) {
#pragma unroll
            for (int dj = 0; dj < 4; dj++)
                oacc[mi][dj] = __builtin_amdgcn_mfma_f32_16x16x32_bf16(ap[mi], bv[dj], oacc[mi][dj], 0, 0, 0);
            lacc[mi] = __builtin_amdgcn_mfma_f32_16x16x32_bf16(ap[mi], vones, lacc[mi], 0, 0, 0);
        }
    }
    __syncthreads();   // all waves' Ps reads done -> Os may overwrite other waves' Ps space
    // normalized attn tile -> LDS bf16, stride 68
#pragma unroll
    for (int mi = 0; mi < 2; mi++)
#pragma unroll
        for (int r = 0; r < 4; r++) {
            float inv = 1.f / lacc[mi][r];
            int row = w * 32 + mi * 16 + quad * 4 + r;
#pragma unroll
            for (int dj = 0; dj < 4; dj++)
                L.Os[row][dj * 16 + l16] = f2bf(oacc[mi][dj][r] * inv);
        }
    // conv phase reads only own-wave rows (same-wave LDS ordering) -> no barrier
    const ushort* vh = vg + (long)h * NPQ * 64;
    int tk0 = m0 + w * 32;
#pragma unroll
    for (int half = 0; half < 2; half++) {
        int t0 = tk0 + half * 16;
        int base = 214 + t0;
        float vr[48];
#pragma unroll
        for (int i = 0; i < 48; i++) {
            int src = base + i;
            vr[i] = (src < NP) ? bf2f(vh[(long)src * 64 + lane]) : 0.f;
        }
        float conv[16];
#pragma unroll
        for (int i = 0; i < 16; i++) conv[i] = 0.f;
#pragma unroll
        for (int kk = 0; kk < 33; kk++) {
            float wk = rw[h * 33 + kk];
#pragma unroll
            for (int i = 0; i < 16; i++) conv[i] = fmaf(wk, vr[i + kk], conv[i]);
        }
#pragma unroll
        for (int i = 0; i < 16; i++) {
            int tk = t0 + i;
            if (tk < NTOK) {
                float val = bf2f(L.Os[w * 32 + half * 16 + i][lane]) + conv[i];
                ohb[(long)tk * 512 + h * 64 + lane] = f2bf(val);
            }
        }
    }
}

// ---------------- layernorm over 512, writes bf16 xln (first `pad` rows zero)
__global__ __launch_bounds__(256)
void k_layernorm(const float* __restrict__ h, ushort* __restrict__ xln,
                 const float* __restrict__ g, const float* __restrict__ b, int pad)
{
    int row = blockIdx.x, t = threadIdx.x;
    if (row < pad) {
        xln[(long)row * 512 + t] = 0;
        xln[(long)row * 512 + t + 256] = 0;
        return;
    }
    const float* src = h + (long)(row - pad) * 512;
    float x1 = src[t], x2 = src[t + 256];
    float s = x1 + x2, q = x1 * x1 + x2 * x2;
    __shared__ float rs[4], rq[4], st[2];
    int wid = t >> 6, lane = t & 63;
#pragma unroll
    for (int o = 32; o > 0; o >>= 1) { s += __shfl_down(s, o); q += __shfl_down(q, o); }
    if (lane == 0) { rs[wid] = s; rq[wid] = q; }
    __syncthreads();
    if (t == 0) {
        float S = rs[0] + rs[1] + rs[2] + rs[3];
        float Q = rq[0] + rq[1] + rq[2] + rq[3];
        float mean = S / 512.f;
        float var = Q / 512.f - mean * mean;
        st[0] = mean; st[1] = rsqrtf(var + 1e-5f);
    }
    __syncthreads();
    float mean = st[0], rstd = st[1];
    xln[(long)row * 512 + t] = f2bf((x1 - mean) * rstd * g[t] + b[t]);
    xln[(long)row * 512 + t + 256] = f2bf((x2 - mean) * rstd * g[t + 256] + b[t + 256]);
}

__global__ __launch_bounds__(256)
void k_padcls(float* __restrict__ hbuf, const float* __restrict__ cls)
{
    int i = blockIdx.x, t = threadIdx.x;
    if (i == 0) { hbuf[t] = cls[t]; hbuf[t + 256] = cls[t + 256]; }
    else {
        hbuf[(long)(15000 + i) * 512 + t] = hbuf[(long)i * 512 + t];
        hbuf[(long)(15000 + i) * 512 + t + 256] = hbuf[(long)i * 512 + t + 256];
    }
}

__global__ __launch_bounds__(256)
void k_wT(const float* __restrict__ Wm, ushort* __restrict__ Wt, int K, int N, long sW, long sWt)
{
    Wm += (long)blockIdx.z * sW; Wt += (long)blockIdx.z * sWt;
    __shared__ float tile[32][33];
    int tx = threadIdx.x & 31, ty = threadIdx.x >> 5;
    int n0 = blockIdx.x * 32, k0 = blockIdx.y * 32;
#pragma unroll
    for (int u = 0; u < 4; u++) tile[ty + u * 8][tx] = Wm[(long)(k0 + ty + u * 8) * N + n0 + tx];
    __syncthreads();
#pragma unroll
    for (int u = 0; u < 4; u++) Wt[(long)(n0 + ty + u * 8) * K + k0 + tx] = f2bf(tile[tx][ty + u * 8]);
}

__global__ __launch_bounds__(256)
void k_cvt(const float4* __restrict__ src, ushort4* __restrict__ dst, long n4)
{
    long i = (long)blockIdx.x * 256 + threadIdx.x;
    if (i < n4) {
        float4 v = src[i];
        ushort4 o;
        o.x = f2bf(v.x); o.y = f2bf(v.y); o.z = f2bf(v.z); o.w = f2bf(v.w);
        dst[i] = o;
    }
}

__global__ __launch_bounds__(256)
void k_b2f(const ushort4* __restrict__ src, float4* __restrict__ dst, long n4)
{
    long i = (long)blockIdx.x * 256 + threadIdx.x;
    if (i < n4) {
        ushort4 v = src[i];
        dst[i] = make_float4(bf2f(v.x), bf2f(v.y), bf2f(v.z), bf2f(v.w));
    }
}

__global__ __launch_bounds__(64)
void k_landmarks(const ushort* __restrict__ q, const ushort* __restrict__ k,
                 float* __restrict__ ql, ushort* __restrict__ qlb,
                 float* __restrict__ klT, ushort* __restrict__ klb,
                 unsigned* __restrict__ scal)
{
    int i = blockIdx.x, h = blockIdx.y, d = threadIdx.x;
    if (i == 0 && h == 0 && d == 0) { scal[0] = 0u; scal[1] = 0u; }
    long base = ((long)h * NPQ + (long)i * 60) * 64 + d;
    float sq = 0.f, sk = 0.f;
    for (int j = 0; j < 60; j++) { sq += bf2f(q[base + j * 64]); sk += bf2f(k[base + j * 64]); }
    float qv = sq / 60.f, kv = sk / 60.f;
    ql[((long)h * 256 + i) * 64 + d] = qv;
    qlb[((long)h * 256 + i) * 64 + d] = f2bf(qv);
    klT[((long)h * 64 + d) * 256 + i] = kv;
    klb[((long)h * 256 + i) * 64 + d] = f2bf(kv);
}

__global__ __launch_bounds__(256)
void k_softmax256(float* __restrict__ X, ushort* __restrict__ X16, long headStride)
{
    float* row = X + (long)blockIdx.y * headStride + (long)blockIdx.x * 256;
    int t = threadIdx.x, wid = t >> 6, lane = t & 63;
    float x = row[t];
    __shared__ float rm[4], rsum[4], fin[2];
    float m = x;
#pragma unroll
    for (int o = 32; o > 0; o >>= 1) m = fmaxf(m, __shfl_down(m, o));
    if (lane == 0) rm[wid] = m;
    __syncthreads();
    if (t == 0) fin[0] = fmaxf(fmaxf(rm[0], rm[1]), fmaxf(rm[2], rm[3]));
    __syncthreads();
    float e = __expf(x - fin[0]);
    float s = e;
#pragma unroll
    for (int o = 32; o > 0; o >>= 1) s += __shfl_down(s, o);
    if (lane == 0) rsum[wid] = s;
    __syncthreads();
    if (t == 0) fin[1] = rsum[0] + rsum[1] + rsum[2] + rsum[3];
    __syncthreads();
    float v = e / fin[1];
    row[t] = v;
    if (X16) X16[(long)blockIdx.y * headStride + (long)blockIdx.x * 256 + t] = f2bf(v);
}

__global__ __launch_bounds__(256)
void k_colmax(const float* __restrict__ a2, unsigned* __restrict__ scal)
{
    int h = blockIdx.x, t = threadIdx.x, wid = t >> 6, lane = t & 63;
    const float* A = a2 + (long)h * 65536;
    float cs = 0.f, rs = 0.f;
    for (int i = 0; i < 256; i++) cs += A[(long)i * 256 + t];
    for (int j = 0; j < 256; j++) rs += A[(long)t * 256 + j];
    __shared__ float r1[4], r2[4];
    float m1v = cs, m2v = rs;
#pragma unroll
    for (int o = 32; o > 0; o >>= 1) {
        m1v = fmaxf(m1v, __shfl_down(m1v, o));
        m2v = fmaxf(m2v, __shfl_down(m2v, o));
    }
    if (lane == 0) { r1[wid] = m1v; r2[wid] = m2v; }
    __syncthreads();
    if (t == 0) {
        float a = fmaxf(fmaxf(r1[0], r1[1]), fmaxf(r1[2], r1[3]));
        float b = fmaxf(fmaxf(r2[0], r2[1]), fmaxf(r2[2], r2[3]));
        atomicMax(scal + 0, __float_as_uint(a));
        atomicMax(scal + 1, __float_as_uint(b));
    }
}

__global__ __launch_bounds__(256)
void k_zinit(const float* __restrict__ a2, ushort* __restrict__ zb, const unsigned* __restrict__ scal)
{
    float s = 1.f / (__uint_as_float(scal[0]) * __uint_as_float(scal[1]));
    const float* A = a2 + (long)blockIdx.z * 65536;
    ushort* Z = zb + (long)blockIdx.z * 65536;
    __shared__ float tile[32][33];
    int tx = threadIdx.x & 31, ty = threadIdx.x >> 5;
    int i0 = blockIdx.x * 32, j0 = blockIdx.y * 32;
#pragma unroll
    for (int u = 0; u < 4; u++) tile[ty + u * 8][tx] = A[(long)(j0 + ty + u * 8) * 256 + i0 + tx];
    __syncthreads();
#pragma unroll
    for (int u = 0; u < 4; u++) Z[(long)(i0 + ty + u * 8) * 256 + j0 + tx] = f2bf(tile[tx][ty + u * 8] * s);
}

__global__ __launch_bounds__(256)
void k_a3v_merge(const float* __restrict__ pacc, const float* __restrict__ pml,
                 float* __restrict__ t1)
{
    int d = blockIdx.x, h = blockIdx.y, i = threadIdx.x;
    float M = -INFINITY, L = 0.f, num = 0.f;
    for (int c = 0; c < 60; c++) {
        float mc = pml[(long)(h * 60 + c) * 2 * 256 + i];
        float lc = pml[((long)(h * 60 + c) * 2 + 1) * 256 + i];
        float ac = pacc[((long)(h * 60 + c) * 64 + d) * 256 + i];
        if (mc > M) {
            float f = __expf(M - mc);
            num = num * f + ac; L = L * f + lc; M = mc;
        } else {
            float p = __expf(mc - M);
            num = fmaf(p, ac, num); L = fmaf(p, lc, L);
        }
    }
    t1[((long)h * 256 + i) * 64 + d] = num / L;
}

__global__ __launch_bounds__(256)
void k_cls(const ushort* __restrict__ qb, const float* __restrict__ klT,
           const float* __restrict__ Bm, const ushort* __restrict__ vb,
           const float* __restrict__ rw, float* __restrict__ oh)
{
    int h = blockIdx.x, t = threadIdx.x, wid = t >> 6, lane = t & 63;
    __shared__ float qs[64], p[256], red[256];
    __shared__ float rm[4], rsum[4], fin[2];
    if (t < 64) qs[t] = bf2f(qb[((long)h * NPQ + 230) * 64 + t]);
    __syncthreads();
    float s = 0.f;
    for (int d = 0; d < 64; d++) s = fmaf(qs[d], klT[((long)h * 64 + d) * 256 + t], s);
    float m = s;
#pragma unroll
    for (int o = 32; o > 0; o >>= 1) m = fmaxf(m, __shfl_down(m, o));
    if (lane == 0) rm[wid] = m;
    __syncthreads();
    if (t == 0) fin[0] = fmaxf(fmaxf(rm[0], rm[1]), fmaxf(rm[2], rm[3]));
    __syncthreads();
    float e = __expf(s - fin[0]);
    float ss = e;
#pragma unroll
    for (int o = 32; o > 0; o >>= 1) ss += __shfl_down(ss, o);
    if (lane == 0) rsum[wid] = ss;
    __syncthreads();
    if (t == 0) fin[1] = rsum[0] + rsum[1] + rsum[2] + rsum[3];
    __syncthreads();
    p[t] = e / fin[1];
    __syncthreads();
    int d = t & 63, grp = t >> 6;
    float o = 0.f;
    for (int j = grp * 64; j < grp * 64 + 64; j++) o = fmaf(p[j], Bm[((long)h * 256 + j) * 64 + d], o);
    red[t] = o;
    __syncthreads();
    if (t < 64) {
        float val = red[t] + red[t + 64] + red[t + 128] + red[t + 192];
#pragma unroll
        for (int kk = 0; kk < 33; kk++)
            val = fmaf(rw[h * 33 + kk], bf2f(vb[((long)h * NPQ + 214 + kk) * 64 + t]), val);
        oh[h * 64 + t] = val;
    }
}

__global__ __launch_bounds__(256)
void k_copy4(const float4* __restrict__ src, float4* __restrict__ dst, long n4)
{
    long i = (long)blockIdx.x * 256 + threadIdx.x;
    if (i < n4) dst[i] = src[i];
}

// ---------------- combine w7+w5+w3+identity into wc[49][512], bc = b7+b5+b3
__global__ __launch_bounds__(512)
void k_wcomb(const float* __restrict__ w7, const float* __restrict__ b7,
             const float* __restrict__ w5, const float* __restrict__ b5,
             const float* __restrict__ w3, const float* __restrict__ b3,
             float* __restrict__ wc, float* __restrict__ bc)
{
    int k = blockIdx.x, c = threadIdx.x;
    int kr = k / 7, kc = k % 7;
    float v = w7[c * 49 + k];
    if (kr >= 1 && kr <= 5 && kc >= 1 && kc <= 5) v += w5[c * 25 + (kr - 1) * 5 + (kc - 1)];
    if (kr >= 2 && kr <= 4 && kc >= 2 && kc <= 4) v += w3[c * 9 + (kr - 2) * 3 + (kc - 2)];
    if (k == 24) v += 1.f;
    wc[k * 512 + c] = v;
    if (k == 0) bc[c] = b7[c] + b5[c] + b3[c];
}

// ---------------- PPEG v2: single 7x7 combined depthwise; bf16 LDS tile
__global__ __launch_bounds__(256)
void k_ppeg2(const float* __restrict__ cnn, float* __restrict__ hbuf,
             const float* __restrict__ wc, const float* __restrict__ bc)
{
    __shared__ ushort tile[140][64];
    int t = threadIdx.x;
    int cp = t & 31;
    int g = t >> 5;
    int c0 = blockIdx.x * 8, r0 = blockIdx.y * 4, cb = blockIdx.z * 64;
    for (int idx = t; idx < 140 * 32; idx += 256) {
        int pos = idx >> 5, pp = idx & 31;
        int pr = pos / 14, pc = pos % 14;
        int gr = r0 + pr - 3, gc = c0 + pc - 3;
        float v0 = 0.f, v1 = 0.f;
        if (gr >= 0 && gr < HG && gc >= 0 && gc < HG) {
            const float* src = cnn + (long)(gr * HG + gc) * 512 + cb + pp * 2;
            v0 = src[0]; v1 = src[1];
        }
        tile[pos][pp * 2] = f2bf(v0);
        tile[pos][pp * 2 + 1] = f2bf(v1);
    }
    __syncthreads();
    float acc[4][2] = {};
    for (int kr = 0; kr < 7; kr++)
#pragma unroll
        for (int kc = 0; kc < 7; kc++) {
            float w0 = wc[(kr * 7 + kc) * 512 + cb + cp * 2];
            float w1 = wc[(kr * 7 + kc) * 512 + cb + cp * 2 + 1];
#pragma unroll
            for (int u = 0; u < 4; u++) {
                int p = g * 4 + u;
                int orow = p >> 3, ocol = p & 7;
                unsigned pk = *(const unsigned*)&tile[(orow + kr) * 14 + (ocol + kc)][cp * 2];
                acc[u][0] = fmaf(w0, bf2f((ushort)pk), acc[u][0]);
                acc[u][1] = fmaf(w1, bf2f((ushort)(pk >> 16)), acc[u][1]);
            }
        }
    float b0 = bc[cb + cp * 2], b1 = bc[cb + cp * 2 + 1];
#pragma unroll
    for (int u = 0; u < 4; u++) {
        int p = g * 4 + u;
        int orow = p >> 3, ocol = p & 7;
        int gr = r0 + orow, gc = c0 + ocol;
        if (gr < HG && gc < HG) {
            float* dst = hbuf + (long)(1 + gr * HG + gc) * 512 + cb + cp * 2;
            dst[0] = acc[u][0] + b0;
            dst[1] = acc[u][1] + b1;
        }
    }
}

__global__ __launch_bounds__(256)
void k_final(const float* __restrict__ hbuf, const float* __restrict__ g,
             const float* __restrict__ b, const float* __restrict__ W2,
             const float* __restrict__ b2, float* __restrict__ out)
{
    __shared__ float y[512];
    __shared__ float rs[4], rq[4], st[2], lg[8];
    int t = threadIdx.x, wid = t >> 6, lane = t & 63;
    float x1 = hbuf[t], x2 = hbuf[t + 256];
    float s = x1 + x2, q = x1 * x1 + x2 * x2;
#pragma unroll
    for (int o = 32; o > 0; o >>= 1) { s += __shfl_down(s, o); q += __shfl_down(q, o); }
    if (lane == 0) { rs[wid] = s; rq[wid] = q; }
    __syncthreads();
    if (t == 0) {
        float S = rs[0] + rs[1] + rs[2] + rs[3];
        float Q = rq[0] + rq[1] + rq[2] + rq[3];
        float mean = S / 512.f;
        float var = Q / 512.f - mean * mean;
        st[0] = mean; st[1] = rsqrtf(var + 1e-5f);
    }
    __syncthreads();
    float mean = st[0], rstd = st[1];
    y[t] = (x1 - mean) * rstd * g[t] + b[t];
    y[t + 256] = (x2 - mean) * rstd * g[t + 256] + b[t + 256];
    __syncthreads();
    if (t < 5) {
        float acc = b2[t];
        for (int kx = 0; kx < 512; kx++) acc = fmaf(y[kx], W2[kx * 5 + t], acc);
        lg[t] = acc;
    }
    __syncthreads();
    if (t == 0) {
        float mx = lg[0]; int am = 0;
        for (int j = 1; j < 5; j++) if (lg[j] > mx) { mx = lg[j]; am = j; }
        float e[5], se = 0.f;
        for (int j = 0; j < 5; j++) { e[j] = __expf(lg[j] - mx); se += e[j]; }
        for (int j = 0; j < 5; j++) { out[j] = lg[j]; out[5 + j] = e[j] / se; }
        out[10] = (float)am;
    }
}

extern "C" void kernel_launch(void* const* d_in, const int* in_sizes, int n_in,
                              void* d_out, int out_size, void* d_ws, size_t ws_size,
                              hipStream_t stream)
{
    const float* data  = (const float*)d_in[0];
    const float* Wfc1  = (const float*)d_in[1];
    const float* bfc1  = (const float*)d_in[2];
    const float* cls   = (const float*)d_in[3];
    const float* ln1g  = (const float*)d_in[4];
    const float* ln1b  = (const float*)d_in[5];
    const float* qkv1  = (const float*)d_in[6];
    const float* out1w = (const float*)d_in[7];
    const float* out1b = (const float*)d_in[8];
    const float* res1  = (const float*)d_in[9];
    const float* w7    = (const float*)d_in[10];
    const float* b7    = (const float*)d_in[11];
    const float* w5    = (const float*)d_in[12];
    const float* b5    = (const float*)d_in[13];
    const float* w3    = (const float*)d_in[14];
    const float* b3    = (const float*)d_in[15];
    const float* ln2g  = (const float*)d_in[16];
    const float* ln2b  = (const float*)d_in[17];
    const float* qkv2  = (const float*)d_in[18];
    const float* out2w = (const float*)d_in[19];
    const float* out2b = (const float*)d_in[20];
    const float* res2  = (const float*)d_in[21];
    const float* normg = (const float*)d_in[22];
    const float* normb = (const float*)d_in[23];
    const float* Wfc2  = (const float*)d_in[24];
    const float* bfc2  = (const float*)d_in[25];
    float* out = (float*)d_out;

    float* W = (float*)d_ws;
    size_t off = 0;
    auto alloc = [&](size_t n) { size_t o = off; off += (n + 255) & ~(size_t)255; return o; };
    float*  hbuf   = W + alloc((size_t)NTOK * 512);
    float*  ohreg  = W + alloc((size_t)15232 * 512);
    float*  oh     = ohreg;
    ushort* xln    = (ushort*)ohreg;
    ushort* qb16   = (ushort*)(W + alloc((size_t)8 * NPQ * 32));
    ushort* kb16   = (ushort*)(W + alloc((size_t)8 * NPQ * 32));
    ushort* vb16   = (ushort*)(W + alloc((size_t)8 * NPQ * 32));
    float*  ql     = W + alloc(8 * 256 * 64);
    ushort* qlb    = (ushort*)(W + alloc(8 * 256 * 32));
    float*  klT    = W + alloc(8 * 64 * 256);
    ushort* klb    = (ushort*)(W + alloc(8 * 256 * 32));
    float*  a2     = W + alloc(8 * 65536);
    ushort* a2b    = (ushort*)(W + alloc(8 * 32768));
    ushort* zb0    = (ushort*)(W + alloc(8 * 32768));
    ushort* zb1    = (ushort*)(W + alloc(8 * 32768));
    ushort* m1b    = (ushort*)(W + alloc(8 * 32768));
    ushort* mab    = (ushort*)(W + alloc(8 * 32768));
    ushort* mbb    = (ushort*)(W + alloc(8 * 32768));
    float*  z0     = W + alloc(8 * 65536);
    float*  t1     = W + alloc(8 * 256 * 64);
    float*  Bm     = W + alloc(8 * 256 * 64);
    ushort* BmbT   = (ushort*)(W + alloc(8 * 256 * 32));   // bf16 BmT [h][64][256]
    float*  scal   = W + alloc(64);
    ushort* ohb16  = (ushort*)(W + alloc((size_t)15232 * 256));
    ushort* WfcT   = (ushort*)(W + alloc(1024 * 256));
    ushort* qkv1T  = (ushort*)(W + alloc(1536 * 256));
    ushort* qkv2T  = (ushort*)(W + alloc(1536 * 256));
    ushort* out1T  = (ushort*)(W + alloc(512 * 256));
    ushort* out2T  = (ushort*)(W + alloc(512 * 256));
    float*  wc     = W + alloc(49 * 512);
    float*  bc     = W + alloc(512);
    float*  big    = W + alloc(8110080);   // datab | pacc+pml | ppeg cnn
    ushort* datab  = (ushort*)big;
    float*  pacc   = big;
    float*  pml    = big + 7864320;
    float*  cnn    = big;
    if (ws_size < off * sizeof(float)) return;

    k_wT<<<dim3(16, 32, 1), 256, 0, stream>>>(Wfc1, WfcT, 1024, 512, 0, 0);
    k_wT<<<dim3(48, 16, 1), 256, 0, stream>>>(qkv1, qkv1T, 512, 1536, 0, 0);
    k_wT<<<dim3(48, 16, 1), 256, 0, stream>>>(qkv2, qkv2T, 512, 1536, 0, 0);
    k_wT<<<dim3(16, 16, 1), 256, 0, stream>>>(out1w, out1T, 512, 512, 0, 0);
    k_wT<<<dim3(16, 16, 1), 256, 0, stream>>>(out2w, out2T, 512, 512, 0, 0);
    k_wcomb<<<49, 512, 0, stream>>>(w7, b7, w5, b5, w3, b3, wc, bc);
    k_cvt<<<15000, 256, 0, stream>>>((const float4*)data, (ushort4*)datab, 3840000);
    gemm_mfma<4, 4, 2, 2><<<dim3(4, 118, 1), 256, 0, stream>>>(
        datab, 1024, 0, WfcT, 1024, 0, hbuf + 512, 512, 0, 15000, 1024, bfc1, 1, 0);
    k_padcls<<<130, 256, 0, stream>>>(hbuf, cls);

    auto layer = [&](const float* lng, const float* lnb, const ushort* qkvT,
                     const float* outW, const ushort* outT, const float* outB,
                     const float* resW, bool full) {
        k_layernorm<<<NP, 256, 0, stream>>>(hbuf, xln, lng, lnb, 230);
        gemm_qkv_mfma<<<dim3(12, 120, 1), 256, 0, stream>>>(xln, qkvT, qb16, kb16, vb16);
        k_landmarks<<<dim3(256, 8), 64, 0, stream>>>(qb16, kb16, ql, qlb, klT, klb, (unsigned*)scal);
        gemm_f32<<<dim3(4, 4, 8), 256, 0, stream>>>(ql, 64, 16384, klT, 256, 16384,
            a2, 256, 65536, 256, 256, 64, nullptr, nullptr, 0, 0, 0.f, 1.f, 0, 0);
        k_softmax256<<<dim3(256, 8), 256, 0, stream>>>(a2, a2b, 65536);
        k_colmax<<<8, 256, 0, stream>>>(a2, (unsigned*)scal);
        k_zinit<<<dim3(8, 8, 8), 256, 0, stream>>>(a2, zb0, (const unsigned*)scal);
        // pinv: all 6 iterations bf16 MFMA
        ushort* zbi = zb0; ushort* zbo = zb1;
        for (int it = 0; it < 6; ++it) {
            gemm_nn16<<<dim3(4, 4, 8), 256, 0, stream>>>(a2b, zbi, nullptr, m1b, 256, 256, 1.f, 0.f, 65536);
            gemm_nn16<<<dim3(4, 4, 8), 256, 0, stream>>>(m1b, m1b, m1b, mab, 256, 256, -1.f, 7.f, 65536);
            gemm_nn16<<<dim3(4, 4, 8), 256, 0, stream>>>(m1b, mab, m1b, mbb, 256, 256, -1.f, 15.f, 65536);
            gemm_nn16<<<dim3(4, 4, 8), 256, 0, stream>>>(zbi, mbb, zbi, zbo, 256, 256, -0.25f, 3.25f, 65536);
            ushort* tmp = zbi; zbi = zbo; zbo = tmp;
        }
        k_b2f<<<512, 256, 0, stream>>>((const ushort4*)zbi, (float4*)z0, 131072);
        k_flash_a3v<<<dim3(60, 2, 8), 256, 0, stream>>>(qlb, kb16, vb16, pacc, pml);
        k_a3v_merge<<<dim3(64, 8), 256, 0, stream>>>(pacc, pml, t1);
        gemm_f32<<<dim3(1, 4, 8), 256, 0, stream>>>(z0, 256, 65536, t1, 64, 16384,
            Bm, 64, 16384, 256, 64, 256, nullptr, nullptr, 0, 0, 0.f, 1.f, 0, 0);
        if (full) {
            k_wT<<<dim3(2, 8, 8), 256, 0, stream>>>(Bm, BmbT, 256, 64, 16384, 16384);
            k_attn1<<<dim3(119, 8), 256, 0, stream>>>(qb16, klb, BmbT, vb16, resW, ohb16);
            gemm_mfma<4, 4, 2, 2><<<dim3(4, 119, 1), 256, 0, stream>>>(
                ohb16, 512, 0, outT, 512, 0, hbuf, 512, 0, NTOK, 512, outB, 0, 1);
        } else {
            k_cls<<<8, 256, 0, stream>>>(qb16, klT, Bm, vb16, resW, oh);
            gemm_f32<<<dim3(8, 1, 1), 256, 0, stream>>>(oh, 512, 0, outW, 512, 0,
                hbuf, 512, 0, 1, 512, 512, outB, nullptr, 0, 0, 0.f, 1.f, 0, 1);
        }
    };

    layer(ln1g, ln1b, qkv1T, out1w, out1T, out1b, res1, true);
    k_copy4<<<(1936512 + 255) / 256, 256, 0, stream>>>((const float4*)(hbuf + 512), (float4*)cnn, 1936512);
    k_ppeg2<<<dim3(16, 31, 8), 256, 0, stream>>>(cnn, hbuf, wc, bc);
    layer(ln2g, ln2b, qkv2T, out2w, out2T, out2b, res2, false);
    k_final<<<1, 256, 0, stream>>>(hbuf, normg, normb, Wfc2, bfc2, out);
}